// Round 5
// baseline (12592.328 us; speedup 1.0000x reference)
//
#include <hip/hip_runtime.h>
#include <math.h>

// ---------------- constants ----------------
// B=4 N=1024 V=20000 D=512 H=8 DH=64 W=512 NB=2 NS=512 FF=2048

typedef __attribute__((ext_vector_type(8))) __bf16 bf16x8;
typedef __attribute__((ext_vector_type(8))) _Float16 f16x8;
typedef __attribute__((ext_vector_type(4))) float f32x4;

__device__ __forceinline__ ushort f2b(float f){      // fp32 -> bf16 RNE
  uint u = __float_as_uint(f);
  uint r = (u + 0x7FFFu + ((u >> 16) & 1u)) >> 16;
  return (ushort)r;
}
__device__ __forceinline__ uint pkh2(float a, float b){   // two fp32 -> packed fp16
  _Float16 ha = (_Float16)a, hb = (_Float16)b;
  ushort ua = *reinterpret_cast<ushort*>(&ha);
  ushort ub = *reinterpret_cast<ushort*>(&hb);
  return (uint)ua | ((uint)ub << 16);
}
// split 8 fp32 into bf16 hi + bf16 lo (Dekker-style; residual ~2^-17 rel)
__device__ __forceinline__ void split8(const float* f, uint4& hi, uint4& lo){
  ushort h[8], l[8];
#pragma unroll
  for (int i=0;i<8;i++){
    h[i] = f2b(f[i]);
    float fh = __uint_as_float((uint)h[i] << 16);
    l[i] = f2b(f[i] - fh);
  }
  hi = make_uint4((uint)h[0]|((uint)h[1]<<16), (uint)h[2]|((uint)h[3]<<16),
                  (uint)h[4]|((uint)h[5]<<16), (uint)h[6]|((uint)h[7]<<16));
  lo = make_uint4((uint)l[0]|((uint)l[1]<<16), (uint)l[2]|((uint)l[3]<<16),
                  (uint)l[4]|((uint)l[5]<<16), (uint)l[6]|((uint)l[7]<<16));
}

// ---------------- embed ----------------
__global__ void k_embed(const int* __restrict__ x, const float* __restrict__ emb,
                        float* __restrict__ h, int total4){
  int idx = blockIdx.x*blockDim.x + threadIdx.x;
  if (idx >= total4) return;
  int row = idx >> 7;          // 128 float4 per 512-float row
  int c4  = idx & 127;
  int tok = x[row];
  reinterpret_cast<float4*>(h)[idx] =
      reinterpret_cast<const float4*>(emb)[(size_t)tok*128 + c4];
}

// ---------------- pos-bias MLP table [W,H] ----------------
__global__ void k_postable(const float* __restrict__ w1, const float* __restrict__ b1,
                           const float* __restrict__ w2, const float* __restrict__ b2,
                           const float* __restrict__ w3, const float* __restrict__ b3,
                           float* __restrict__ table){
  __shared__ float h1[128];
  __shared__ float h2[128];
  int d = blockIdx.x, t = threadIdx.x;   // 128 threads
  float a = (float)d * w1[t] + b1[t];
  h1[t] = a / (1.f + __expf(-a));        // silu
  __syncthreads();
  float acc = b2[t];
  for (int p=0;p<128;p++) acc += h1[p]*w2[p*128+t];
  h2[t] = acc / (1.f + __expf(-acc));
  __syncthreads();
  if (t < 8){
    float acc2 = b3[t];
    for (int p=0;p<128;p++) acc2 += h2[p]*w3[p*8+t];
    table[d*8+t] = acc2;
  }
}

// ---------------- layernorm (one 512-col row per block of 256) ----------------
__global__ void k_ln(const float* __restrict__ x, const float* __restrict__ g,
                     float* __restrict__ y){
  int row = blockIdx.x;
  int t = threadIdx.x;
  float2 v = reinterpret_cast<const float2*>(x + (size_t)row*512)[t];
  float s = v.x+v.y, ss = v.x*v.x+v.y*v.y;
  for (int o=32;o;o>>=1){ s += __shfl_down(s,o); ss += __shfl_down(ss,o); }
  __shared__ float ls[4], lss[4];
  __shared__ float smu, srs;
  int wid = t>>6;
  if ((t&63)==0){ ls[wid]=s; lss[wid]=ss; }
  __syncthreads();
  if (t==0){
    float S=ls[0]+ls[1]+ls[2]+ls[3], SS=lss[0]+lss[1]+lss[2]+lss[3];
    float mu = S*(1.f/512.f);
    float var = SS*(1.f/512.f) - mu*mu;
    smu = mu; srs = rsqrtf(var + 1e-5f);
  }
  __syncthreads();
  float mu=smu, rs=srs;
  float2 gg = reinterpret_cast<const float2*>(g)[t];
  reinterpret_cast<float2*>(y + (size_t)row*512)[t] =
      make_float2((v.x-mu)*rs*gg.x, (v.y-mu)*rs*gg.y);
}

// ---------------- qk rmsnorm (in place), block = 512 thr = 8 waves (one head each) ----
__global__ void k_qkrms(float* __restrict__ q, float* __restrict__ k,
                        const float* __restrict__ qs, const float* __restrict__ ks){
  int row = blockIdx.x;
  int h = threadIdx.x >> 6, d = threadIdx.x & 63;
  size_t base = (size_t)row*512 + h*64 + d;
  float qv = q[base];
  float s = qv*qv;
  for (int o=32;o;o>>=1) s += __shfl_xor(s,o);
  q[base] = qv*rsqrtf(s+1e-12f)*qs[d];
  float kv = k[base];
  float s2 = kv*kv;
  for (int o=32;o;o>>=1) s2 += __shfl_xor(s2,o);
  k[base] = kv*rsqrtf(s2+1e-12f)*ks[d];
}

__device__ __forceinline__ float geluf(float x){
  float u = 0.7978845608028654f*(x + 0.044715f*x*x*x);
  return 0.5f*x*(1.f + tanhf(u));
}

// ---------------- MFMA GEMM: C[M,N] (+)= A[M,K]@B[K,N] (+bias)(gelu) ----------
// 128x128 tile, BK=32, 4 waves 2x2, each wave 64x64 = 4x4 frags of 16x16x32.
// PREC=0: fp16 single product (u=2^-11). PREC=1: bf16 hi/lo 3-product split
// (effective fp32 inputs) — used for softmax-amplified q/k-path GEMMs.
// A,B fp32 in global; converted during LDS staging. B staged transposed
// ([n][k]) so both fragments are contiguous-K ds_read_b128.
// Requires M%128==0, K%32==0. N tail guarded.
template<int ACC, int EPI, int PREC>
__global__ __launch_bounds__(256)
void k_gemm_mfma(const float* __restrict__ A, const float* __restrict__ Bm,
                 const float* __restrict__ bias, float* __restrict__ C,
                 int M, int N, int K){
  __shared__ ushort As[PREC?2:1][128][32];
  __shared__ ushort Bs[PREC?2:1][128][32];
  int t = threadIdx.x;
  int m0 = blockIdx.x*128, n0 = blockIdx.y*128;
  int w = t>>6, lane = t&63;
  int wm = (w>>1)*64, wn = (w&1)*64;
  int fr = lane&15, fk = (lane>>4)*8;       // fragment row, k-offset (elems)

  f32x4 acc[4][4];
#pragma unroll
  for (int i=0;i<4;i++)
#pragma unroll
    for (int j=0;j<4;j++){ acc[i][j][0]=0.f; acc[i][j][1]=0.f; acc[i][j][2]=0.f; acc[i][j][3]=0.f; }

  int srow = t>>1, skf = (t&1)*16;          // staging: row 0..127, k-half 0/16
  int bn = n0 + srow;
  bool bok = bn < N;

  for (int k0=0; k0<K; k0+=32){
    // ---- A tile: 16 consecutive k
    const float* ap = A + (size_t)(m0+srow)*K + k0 + skf;
    float4 a0 = *reinterpret_cast<const float4*>(ap);
    float4 a1 = *reinterpret_cast<const float4*>(ap+4);
    float4 a2 = *reinterpret_cast<const float4*>(ap+8);
    float4 a3 = *reinterpret_cast<const float4*>(ap+12);
    float fa[16] = {a0.x,a0.y,a0.z,a0.w, a1.x,a1.y,a1.z,a1.w,
                    a2.x,a2.y,a2.z,a2.w, a3.x,a3.y,a3.z,a3.w};
    // ---- B tile (transposed): 16 strided fp32 loads along k for one n
    float fb[16];
    const float* bp = Bm + (size_t)(k0+skf)*N + bn;
#pragma unroll
    for (int u=0;u<16;u++) fb[u] = bok ? bp[(size_t)u*N] : 0.f;

    if constexpr (PREC==0){
      uint4 w0 = make_uint4(pkh2(fa[0],fa[1]),  pkh2(fa[2],fa[3]),
                            pkh2(fa[4],fa[5]),  pkh2(fa[6],fa[7]));
      uint4 w1 = make_uint4(pkh2(fa[8],fa[9]),  pkh2(fa[10],fa[11]),
                            pkh2(fa[12],fa[13]),pkh2(fa[14],fa[15]));
      *reinterpret_cast<uint4*>(&As[0][srow][skf])   = w0;
      *reinterpret_cast<uint4*>(&As[0][srow][skf+8]) = w1;
      uint4 v0 = make_uint4(pkh2(fb[0],fb[1]),  pkh2(fb[2],fb[3]),
                            pkh2(fb[4],fb[5]),  pkh2(fb[6],fb[7]));
      uint4 v1 = make_uint4(pkh2(fb[8],fb[9]),  pkh2(fb[10],fb[11]),
                            pkh2(fb[12],fb[13]),pkh2(fb[14],fb[15]));
      *reinterpret_cast<uint4*>(&Bs[0][srow][skf])   = v0;
      *reinterpret_cast<uint4*>(&Bs[0][srow][skf+8]) = v1;
    } else {
      uint4 hi, lo;
      split8(fa,   hi, lo);
      *reinterpret_cast<uint4*>(&As[0][srow][skf])   = hi;
      *reinterpret_cast<uint4*>(&As[1][srow][skf])   = lo;
      split8(fa+8, hi, lo);
      *reinterpret_cast<uint4*>(&As[0][srow][skf+8]) = hi;
      *reinterpret_cast<uint4*>(&As[1][srow][skf+8]) = lo;
      split8(fb,   hi, lo);
      *reinterpret_cast<uint4*>(&Bs[0][srow][skf])   = hi;
      *reinterpret_cast<uint4*>(&Bs[1][srow][skf])   = lo;
      split8(fb+8, hi, lo);
      *reinterpret_cast<uint4*>(&Bs[0][srow][skf+8]) = hi;
      *reinterpret_cast<uint4*>(&Bs[1][srow][skf+8]) = lo;
    }
    __syncthreads();

    if constexpr (PREC==0){
      f16x8 af[4], bfr[4];
#pragma unroll
      for (int mi=0;mi<4;mi++)
        af[mi] = *reinterpret_cast<const f16x8*>(&As[0][wm+mi*16+fr][fk]);
#pragma unroll
      for (int nj=0;nj<4;nj++)
        bfr[nj] = *reinterpret_cast<const f16x8*>(&Bs[0][wn+nj*16+fr][fk]);
#pragma unroll
      for (int mi=0;mi<4;mi++)
#pragma unroll
        for (int nj=0;nj<4;nj++)
          acc[mi][nj] = __builtin_amdgcn_mfma_f32_16x16x32_f16(af[mi], bfr[nj], acc[mi][nj], 0,0,0);
    } else {
      bf16x8 ah[4], al[4], bh[4], bl[4];
#pragma unroll
      for (int mi=0;mi<4;mi++){
        ah[mi] = *reinterpret_cast<const bf16x8*>(&As[0][wm+mi*16+fr][fk]);
        al[mi] = *reinterpret_cast<const bf16x8*>(&As[1][wm+mi*16+fr][fk]);
      }
#pragma unroll
      for (int nj=0;nj<4;nj++){
        bh[nj] = *reinterpret_cast<const bf16x8*>(&Bs[0][wn+nj*16+fr][fk]);
        bl[nj] = *reinterpret_cast<const bf16x8*>(&Bs[1][wn+nj*16+fr][fk]);
      }
#pragma unroll
      for (int mi=0;mi<4;mi++)
#pragma unroll
        for (int nj=0;nj<4;nj++){
          acc[mi][nj] = __builtin_amdgcn_mfma_f32_16x16x32_bf16(ah[mi], bh[nj], acc[mi][nj], 0,0,0);
          acc[mi][nj] = __builtin_amdgcn_mfma_f32_16x16x32_bf16(al[mi], bh[nj], acc[mi][nj], 0,0,0);
          acc[mi][nj] = __builtin_amdgcn_mfma_f32_16x16x32_bf16(ah[mi], bl[nj], acc[mi][nj], 0,0,0);
        }
    }
    __syncthreads();
  }
  // ---- epilogue: D row=(lane>>4)*4+reg, col=lane&15 (m89/m91 layout)
#pragma unroll
  for (int mi=0;mi<4;mi++){
#pragma unroll
    for (int r=0;r<4;r++){
      int row = m0 + wm + mi*16 + (lane>>4)*4 + r;
      float* crow = C + (size_t)row*N;
#pragma unroll
      for (int nj=0;nj<4;nj++){
        int col = n0 + wn + nj*16 + fr;
        if (col < N){
          float val = acc[mi][nj][r];
          if (bias) val += bias[col];
          if (EPI==1) val = geluf(val);
          if (ACC) crow[col] += val; else crow[col] = val;
        }
      }
    }
  }
}

// ---------------- generic flash attention (fp32, unchanged this round) --------
__global__ __launch_bounds__(256)
void k_attn(const float* __restrict__ Q, long qB,
            const float* __restrict__ K0, long k0B, int k0R, int k0C, int k0H,
            const float* __restrict__ K1, long k1B, int k1R, int k1C, int k1H,
            const float* __restrict__ V0, long v0B, int v0R, int v0C, int v0H,
            const float* __restrict__ V1, long v1B, int v1R, int v1C, int v1H,
            int n0, int n1,
            float* __restrict__ O, long oB,
            float scale, int winmode, int has_mem,
            const float* __restrict__ table){
  __shared__ float Kt[64][68];
  __shared__ float Vt[64][68];
  __shared__ float qsm[32][68];
  __shared__ float pt[4][8][64];
  __shared__ float tcol[512];
  int b = blockIdx.z, h = blockIdx.y, rt = blockIdx.x;
  int t = threadIdx.x, w = t>>6, lane = t&63;
  int i0 = rt*32 + w*8;
  int qc = h*64;
  if (winmode){
    tcol[t]     = table[t*8 + h];
    tcol[t+256] = table[(t+256)*8 + h];
  }
#pragma unroll
  for (int r=0;r<8;r++)
    qsm[w*8+r][lane] = Q[(size_t)b*qB + (size_t)(i0+r)*512 + qc + lane];
  float o[8] = {0,0,0,0,0,0,0,0};
  float m[8], l[8] = {0,0,0,0,0,0,0,0};
#pragma unroll
  for (int r=0;r<8;r++) m[r] = -1e30f;
  int kc0 = k0H? qc : k0C, kc1 = k1H? qc : k1C;
  int vc0 = v0H? qc : v0C, vc1 = v1H? qc : v1C;
  int nk = n0+n1, nt = nk>>6;
  int sj = t>>2, sc = (t&3)*16;
  for (int jt=0;jt<nt;jt++){
    int jgs = jt*64 + sj;
    const float* kp; const float* vp;
    if (jgs < n0){
      kp = K0 + (size_t)b*k0B + (size_t)jgs*k0R + kc0 + sc;
      vp = V0 + (size_t)b*v0B + (size_t)jgs*v0R + vc0 + sc;
    } else {
      int j1 = jgs - n0;
      kp = K1 + (size_t)b*k1B + (size_t)j1*k1R + kc1 + sc;
      vp = V1 + (size_t)b*v1B + (size_t)j1*v1R + vc1 + sc;
    }
#pragma unroll
    for (int u=0;u<4;u++){
      *reinterpret_cast<float4*>(&Kt[sj][sc+u*4]) = *reinterpret_cast<const float4*>(kp + u*4);
      *reinterpret_cast<float4*>(&Vt[sj][sc+u*4]) = *reinterpret_cast<const float4*>(vp + u*4);
    }
    __syncthreads();
    int jgl = jt*64 + lane;
    float s[8] = {0,0,0,0,0,0,0,0};
#pragma unroll
    for (int d4=0;d4<16;d4++){
      float4 kv = *reinterpret_cast<const float4*>(&Kt[lane][d4*4]);
#pragma unroll
      for (int r=0;r<8;r++){
        float4 qv = *reinterpret_cast<const float4*>(&qsm[w*8+r][d4*4]);
        s[r] += kv.x*qv.x + kv.y*qv.y + kv.z*qv.z + kv.w*qv.w;
      }
    }
#pragma unroll
    for (int r=0;r<8;r++){
      float sv;
      if (winmode){
        int ia = i0 + r;
        bool valid = (jgl > ia) && (jgl <= ia+512) && (has_mem || jgl >= 512);
        sv = valid ? s[r]*scale + tcol[ia+512-jgl] : -1e9f;
      } else {
        sv = s[r]*scale;
      }
      float tm = sv;
      for (int off=32;off;off>>=1) tm = fmaxf(tm, __shfl_xor(tm,off));
      float mn = fmaxf(m[r], tm);
      float corr = __expf(m[r]-mn);
      float p = (sv <= -1e8f) ? 0.f : __expf(sv - mn);
      float ps = p;
      for (int off=32;off;off>>=1) ps += __shfl_xor(ps,off);
      l[r] = l[r]*corr + ps;
      m[r] = mn;
      o[r] *= corr;
      pt[w][r][lane] = p;
    }
    __syncthreads();
    for (int jj=0;jj<64;jj++){
      float vv = Vt[jj][lane];
#pragma unroll
      for (int r=0;r<8;r++) o[r] += pt[w][r][jj]*vv;
    }
    __syncthreads();
  }
#pragma unroll
  for (int r=0;r<8;r++)
    O[(size_t)b*oB + (size_t)(i0+r)*512 + qc + lane] = o[r]/l[r];
}

// ---------------- small utility kernels ----------------
__global__ void k_copy(float* __restrict__ dst, const float* __restrict__ src, int n){
  int idx = blockIdx.x*blockDim.x + threadIdx.x;
  if (idx < n) dst[idx] = src[idx];
}
__global__ void k_gather_xb(float* __restrict__ dst, const float* __restrict__ src, int nb){
  int idx = blockIdx.x*blockDim.x + threadIdx.x;  // 1048576
  if (idx >= 1048576) return;
  int b = idx >> 18, rem = idx & 262143;
  dst[idx] = src[(size_t)b*524288 + (size_t)nb*262144 + rem];
}
__global__ void k_xlout(float* __restrict__ dk, float* __restrict__ dv,
                        const float* __restrict__ k, const float* __restrict__ v){
  int idx = blockIdx.x*blockDim.x + threadIdx.x;  // 1048576
  if (idx >= 1048576) return;
  int b = idx >> 18, rem = idx & 262143;
  size_t s = (size_t)b*524288 + 262144 + rem;     // block 1 rows
  dk[idx] = k[s]; dv[idx] = v[s];
}
__global__ void k_ema(float* __restrict__ st, const float* __restrict__ sp,
                      const float* __restrict__ beta, int n){
  int idx = blockIdx.x*blockDim.x + threadIdx.x;
  if (idx >= n) return;
  int d = idx & 511;
  float dec = 1.f/(1.f+__expf(-beta[d]));
  st[idx] = dec*st[idx] + (1.f-dec)*sp[idx];
}

// ---------------- launcher ----------------
extern "C" void kernel_launch(void* const* d_in, const int* in_sizes, int n_in,
                              void* d_out, int out_size, void* d_ws, size_t ws_size,
                              hipStream_t stream){
  // workspace high-water mark: 24,121,344 floats (~96.5 MB)
  if (ws_size < (size_t)24121344 * sizeof(float)) return;

  const int*   x        = (const int*)  d_in[0];
  const float* tok_emb  = (const float*)d_in[1];
  const float* pw1 = (const float*)d_in[2];
  const float* pb1 = (const float*)d_in[3];
  const float* pw2 = (const float*)d_in[4];
  const float* pb2 = (const float*)d_in[5];
  const float* pw3 = (const float*)d_in[6];
  const float* pb3 = (const float*)d_in[7];
  const float* ln_g = (const float*)d_in[8];
  const float* Wq = (const float*)d_in[9];
  const float* Wk = (const float*)d_in[10];
  const float* Wv = (const float*)d_in[11];
  const float* Wo = (const float*)d_in[12];
  const float* q_scale = (const float*)d_in[13];
  const float* k_scale = (const float*)d_in[14];
  const float* Wo_state = (const float*)d_in[15];
  const float* state_norm_g = (const float*)d_in[16];
  const float* Wq2s = (const float*)d_in[17];
  const float* Ws2q = (const float*)d_in[18];
  const float* Ws2kv = (const float*)d_in[19];
  const float* W_state_out = (const float*)d_in[20];
  const float* ema_beta = (const float*)d_in[21];
  const float* ff_g = (const float*)d_in[22];
  const float* ff_w1 = (const float*)d_in[23];
  const float* ff_b1 = (const float*)d_in[24];
  const float* ff_w2 = (const float*)d_in[25];
  const float* ff_b2 = (const float*)d_in[26];
  const float* final_g = (const float*)d_in[27];
  const float* W_logits = (const float*)d_in[28];
  const float* xl_mem_k = (const float*)d_in[29];
  const float* xl_mem_v = (const float*)d_in[30];
  const float* states_in = (const float*)d_in[31];

  float* out = (float*)d_out;
  float* out_xlk    = out + 81920000;
  float* out_xlv    = out + 84017152;
  float* out_states = out + 86114304;

  float* p = (float*)d_ws;
  float* hstate   = p; p += 2097152;
  float* xn       = p; p += 2097152;
  float* q        = p; p += 2097152;
  float* k        = p; p += 2097152;
  float* v        = p; p += 2097152;
  float* attn_out = p; p += 2097152;
  float* to_state = p; p += 2097152;
  float* ff1      = p; p += 8388608;
  float* states_cur = p; p += 1048576;
  float* table    = p; p += 4096;
  // recurrent-layer scratch aliases inside ff1 (rec runs before FF in layer 3)
  float* sn    = ff1;
  float* skv   = ff1 + 1048576;
  float* xb    = ff1 + 1310720;
  float* q2s   = ff1 + 2359296;
  float* sq    = ff1 + 3407872;
  float* satt  = ff1 + 4456448;
  float* sproj = ff1 + 5505024;

  k_embed<<<2048, 256, 0, stream>>>(x, tok_emb, hstate, 524288);
  k_postable<<<512, 128, 0, stream>>>(pw1,pb1,pw2,pb2,pw3,pb3, table);
  k_copy<<<4096, 256, 0, stream>>>(states_cur, states_in, 1048576);

  for (int l=0;l<6;l++){
    k_ln<<<4096,256,0,stream>>>(hstate, ln_g + l*512, xn);
    // q/k path: split-bf16 (softmax-amplified); v: fp16
    k_gemm_mfma<0,0,1><<<dim3(32,4),256,0,stream>>>(xn, Wq + (size_t)l*262144, nullptr, q, 4096,512,512);
    k_gemm_mfma<0,0,1><<<dim3(32,4),256,0,stream>>>(xn, Wk + (size_t)l*262144, nullptr, k, 4096,512,512);
    k_gemm_mfma<0,0,0><<<dim3(32,4),256,0,stream>>>(xn, Wv + (size_t)l*262144, nullptr, v, 4096,512,512);
    float scale = 0.125f;
    if (l>=3){
      k_qkrms<<<4096,512,0,stream>>>(q, k, q_scale + l*64, k_scale + l*64);
      scale = 8.f;
    }
    bool isxl = (l==4 || l==5);
    int src = (l==4)? 1 : 0;     // roll(-1): xl layer 4 -> mem[1], layer 5 -> mem[0]
    for (int nb=0;nb<2;nb++){
      const float* K0; const float* V0; long k0B;
      int has_mem;
      if (nb==0){
        if (isxl){ K0 = xl_mem_k + (size_t)src*1048576; V0 = xl_mem_v + (size_t)src*1048576;
                   k0B = 262144; has_mem = 1; }
        else     { K0 = k; V0 = v; k0B = 524288; has_mem = 0; }   // dummy (masked)
      } else {
        K0 = k; V0 = v; k0B = 524288; has_mem = 1;                // prev block = block 0
      }
      k_attn<<<dim3(16,8,4),256,0,stream>>>(
        q + nb*262144, 524288L,
        K0, k0B, 512, 0, 1,
        k + nb*262144, 524288L, 512, 0, 1,
        V0, k0B, 512, 0, 1,
        v + nb*262144, 524288L, 512, 0, 1,
        512, 512,
        attn_out + nb*262144, 524288L,
        scale, 1, has_mem, table);
    }
    k_gemm_mfma<1,0,0><<<dim3(32,4),256,0,stream>>>(attn_out, Wo + (size_t)l*262144, nullptr, hstate, 4096,512,512);
    if (l==3){
      for (int nb=0;nb<2;nb++){
        k_ln<<<2048,256,0,stream>>>(states_cur, state_norm_g, sn);
        k_gemm_mfma<0,0,1><<<dim3(16,1),256,0,stream>>>(sn, Ws2kv, nullptr, skv, 2048,128,512);
        k_gather_xb<<<4096,256,0,stream>>>(xb, xn, nb);
        k_gemm_mfma<0,0,1><<<dim3(16,4),256,0,stream>>>(xb, Wq2s, nullptr, q2s, 2048,512,512);
        // block tokens -> states attention (512 keys, no mask/bias)
        k_attn<<<dim3(16,8,4),256,0,stream>>>(
          q2s, 262144L,
          skv, 65536L, 128, 0, 0,
          skv, 65536L, 128, 0, 0,
          skv, 65536L, 128, 64, 0,
          skv, 65536L, 128, 64, 0,
          512, 0,
          to_state + nb*262144, 524288L,
          0.125f, 0, 0, table);
        k_gemm_mfma<0,0,1><<<dim3(16,4),256,0,stream>>>(sn, Ws2q, nullptr, sq, 2048,512,512);
        // states -> [states | block tokens] attention
        k_attn<<<dim3(16,8,4),256,0,stream>>>(
          sq, 262144L,
          skv, 65536L, 128, 0, 0,
          k + nb*262144, 524288L, 512, 0, 1,
          skv, 65536L, 128, 64, 0,
          v + nb*262144, 524288L, 512, 0, 1,
          512, 512,
          satt, 262144L,
          0.125f, 0, 0, table);
        k_gemm_mfma<0,0,0><<<dim3(16,4),256,0,stream>>>(satt, W_state_out, nullptr, sproj, 2048,512,512);
        k_ema<<<4096,256,0,stream>>>(states_cur, sproj, ema_beta, 1048576);
      }
      k_gemm_mfma<1,0,0><<<dim3(32,4),256,0,stream>>>(to_state, Wo_state, nullptr, hstate, 4096,512,512);
    }
    if (isxl){
      int xli = l-4;
      k_xlout<<<4096,256,0,stream>>>(out_xlk + (size_t)xli*1048576,
                                     out_xlv + (size_t)xli*1048576, k, v);
    }
    k_ln<<<4096,256,0,stream>>>(hstate, ff_g + l*512, xn);
    k_gemm_mfma<0,1,0><<<dim3(32,16),256,0,stream>>>(xn, ff_w1 + (size_t)l*1048576, ff_b1 + l*2048, ff1, 4096,2048,512);
    k_gemm_mfma<1,0,0><<<dim3(32,4),256,0,stream>>>(ff1, ff_w2 + (size_t)l*1048576, ff_b2 + l*512, hstate, 4096,512,2048);
  }
  k_ln<<<4096,256,0,stream>>>(hstate, final_g, xn);
  k_gemm_mfma<0,0,0><<<dim3(32,157),256,0,stream>>>(xn, W_logits, nullptr, out, 4096,20000,512);
  k_copy<<<4096, 256, 0, stream>>>(out_states, states_cur, 1048576);
}

// Round 6
// 7748.080 us; speedup vs baseline: 1.6252x; 1.6252x over previous
//
#include <hip/hip_runtime.h>
#include <math.h>

// ---------------- constants ----------------
// B=4 N=1024 V=20000 D=512 H=8 DH=64 W=512 NB=2 NS=512 FF=2048

typedef __attribute__((ext_vector_type(8))) __bf16 bf16x8;
typedef __attribute__((ext_vector_type(8))) _Float16 f16x8;
typedef __attribute__((ext_vector_type(4))) float f32x4;

__device__ __forceinline__ ushort f2b(float f){      // fp32 -> bf16 RNE
  uint u = __float_as_uint(f);
  uint r = (u + 0x7FFFu + ((u >> 16) & 1u)) >> 16;
  return (ushort)r;
}
__device__ __forceinline__ ushort f2h(float f){      // fp32 -> fp16 RNE
  _Float16 h = (_Float16)f;
  return *reinterpret_cast<ushort*>(&h);
}
__device__ __forceinline__ uint pkh2(float a, float b){
  return (uint)f2h(a) | ((uint)f2h(b)<<16);
}
// split 8 fp32 into bf16 hi + bf16 lo (Dekker-style; residual ~2^-17 rel)
__device__ __forceinline__ void split8(const float* f, uint4& hi, uint4& lo){
  ushort h[8], l[8];
#pragma unroll
  for (int i=0;i<8;i++){
    h[i] = f2b(f[i]);
    float fh = __uint_as_float((uint)h[i] << 16);
    l[i] = f2b(f[i] - fh);
  }
  hi = make_uint4((uint)h[0]|((uint)h[1]<<16), (uint)h[2]|((uint)h[3]<<16),
                  (uint)h[4]|((uint)h[5]<<16), (uint)h[6]|((uint)h[7]<<16));
  lo = make_uint4((uint)l[0]|((uint)l[1]<<16), (uint)l[2]|((uint)l[3]<<16),
                  (uint)l[4]|((uint)l[5]<<16), (uint)l[6]|((uint)l[7]<<16));
}

// ---------------- weight prep: transpose [K][N] fp32 -> [Npad][K] fp16/bf16hi+lo
// grid (Npad/32, K/32, slabs); block 256 = 32x8; rows n>=N zero-filled.
template<int MODE>   // 0: fp16 ; 1: bf16 hi + lo
__global__ __launch_bounds__(256)
void k_prep(const float* __restrict__ src, ushort* __restrict__ dh,
            ushort* __restrict__ dl, int K, int N, int Npad){
  __shared__ float tile[32][33];
  int z = blockIdx.z;
  src += (size_t)z*K*N;
  dh  += (size_t)z*Npad*K;
  if (MODE) dl += (size_t)z*Npad*K;
  int n0 = blockIdx.x*32, k0 = blockIdx.y*32;
  int tx = threadIdx.x&31, ty = threadIdx.x>>5;
#pragma unroll
  for (int i=0;i<4;i++){
    int kk = k0 + ty + i*8, nn = n0 + tx;
    tile[ty+i*8][tx] = (nn < N) ? src[(size_t)kk*N + nn] : 0.f;
  }
  __syncthreads();
#pragma unroll
  for (int i=0;i<4;i++){
    int nn = n0 + ty + i*8, kk = k0 + tx;
    float v = tile[tx][ty+i*8];
    if (MODE==0){
      dh[(size_t)nn*K + kk] = f2h(v);
    } else {
      ushort h = f2b(v);
      dh[(size_t)nn*K + kk] = h;
      float fh = __uint_as_float((uint)h<<16);
      dl[(size_t)nn*K + kk] = f2b(v - fh);
    }
  }
}

// ---------------- embed ----------------
__global__ void k_embed(const int* __restrict__ x, const float* __restrict__ emb,
                        float* __restrict__ h, int total4){
  int idx = blockIdx.x*blockDim.x + threadIdx.x;
  if (idx >= total4) return;
  int row = idx >> 7;
  int c4  = idx & 127;
  int tok = x[row];
  reinterpret_cast<float4*>(h)[idx] =
      reinterpret_cast<const float4*>(emb)[(size_t)tok*128 + c4];
}

// ---------------- pos-bias MLP table [W,H] ----------------
__global__ void k_postable(const float* __restrict__ w1, const float* __restrict__ b1,
                           const float* __restrict__ w2, const float* __restrict__ b2,
                           const float* __restrict__ w3, const float* __restrict__ b3,
                           float* __restrict__ table){
  __shared__ float h1[128];
  __shared__ float h2[128];
  int d = blockIdx.x, t = threadIdx.x;
  float a = (float)d * w1[t] + b1[t];
  h1[t] = a / (1.f + __expf(-a));
  __syncthreads();
  float acc = b2[t];
  for (int p=0;p<128;p++) acc += h1[p]*w2[p*128+t];
  h2[t] = acc / (1.f + __expf(-acc));
  __syncthreads();
  if (t < 8){
    float acc2 = b3[t];
    for (int p=0;p<128;p++) acc2 += h2[p]*w3[p*8+t];
    table[d*8+t] = acc2;
  }
}

// ---------------- layernorm ----------------
__global__ void k_ln(const float* __restrict__ x, const float* __restrict__ g,
                     float* __restrict__ y){
  int row = blockIdx.x;
  int t = threadIdx.x;
  float2 v = reinterpret_cast<const float2*>(x + (size_t)row*512)[t];
  float s = v.x+v.y, ss = v.x*v.x+v.y*v.y;
  for (int o=32;o;o>>=1){ s += __shfl_down(s,o); ss += __shfl_down(ss,o); }
  __shared__ float ls[4], lss[4];
  __shared__ float smu, srs;
  int wid = t>>6;
  if ((t&63)==0){ ls[wid]=s; lss[wid]=ss; }
  __syncthreads();
  if (t==0){
    float S=ls[0]+ls[1]+ls[2]+ls[3], SS=lss[0]+lss[1]+lss[2]+lss[3];
    float mu = S*(1.f/512.f);
    float var = SS*(1.f/512.f) - mu*mu;
    smu = mu; srs = rsqrtf(var + 1e-5f);
  }
  __syncthreads();
  float mu=smu, rs=srs;
  float2 gg = reinterpret_cast<const float2*>(g)[t];
  reinterpret_cast<float2*>(y + (size_t)row*512)[t] =
      make_float2((v.x-mu)*rs*gg.x, (v.y-mu)*rs*gg.y);
}

// ---------------- qk rmsnorm (in place) ----------------
__global__ void k_qkrms(float* __restrict__ q, float* __restrict__ k,
                        const float* __restrict__ qs, const float* __restrict__ ks){
  int row = blockIdx.x;
  int h = threadIdx.x >> 6, d = threadIdx.x & 63;
  size_t base = (size_t)row*512 + h*64 + d;
  float qv = q[base];
  float s = qv*qv;
  for (int o=32;o;o>>=1) s += __shfl_xor(s,o);
  q[base] = qv*rsqrtf(s+1e-12f)*qs[d];
  float kv = k[base];
  float s2 = kv*kv;
  for (int o=32;o;o>>=1) s2 += __shfl_xor(s2,o);
  k[base] = kv*rsqrtf(s2+1e-12f)*ks[d];
}

__device__ __forceinline__ float geluf(float x){
  float u = 0.7978845608028654f*(x + 0.044715f*x*x*x);
  return 0.5f*x*(1.f + tanhf(u));
}

// ---------------- MFMA GEMM: C[M,N] (+)= A[M,K]@Bt^T (+bias)(gelu) ----------
// Bt is PRE-TRANSPOSED [Npad][K] fp16 (PREC0) or bf16 hi (+BtLo lo, PREC1),
// Npad = 128-multiple, zero-filled. 128x128 tile, BK=32, 4 waves 2x2, each
// wave 64x64 = 4x4 frags of 16x16x32. A fp32, converted during reg-staging.
// Requires M%128==0, K%32==0. C cols guarded by N.
template<int ACC, int EPI, int PREC>
__global__ __launch_bounds__(256)
void k_gemm_mfma(const float* __restrict__ A, const ushort* __restrict__ Bt,
                 const ushort* __restrict__ BtLo, const float* __restrict__ bias,
                 float* __restrict__ C, int M, int N, int K){
  __shared__ ushort As[PREC?2:1][128][32];
  __shared__ ushort Bs[PREC?2:1][128][32];
  const int t = threadIdx.x;
  const int m0 = blockIdx.x*128, n0 = blockIdx.y*128;
  const int w = t>>6, lane = t&63;
  const int wm = (w>>1)*64, wn = (w&1)*64;
  const int fr = lane&15, fk = (lane>>4)*8;
  const int srow = t>>1, sko = (t&1)*16;     // staging row, ushort k-offset

  f32x4 acc[4][4];
#pragma unroll
  for (int i=0;i<4;i++)
#pragma unroll
    for (int j=0;j<4;j++){ acc[i][j][0]=0.f; acc[i][j][1]=0.f; acc[i][j][2]=0.f; acc[i][j][3]=0.f; }

  const float*  ap  = A  + (size_t)(m0+srow)*K + sko;
  const ushort* bp  = Bt + (size_t)(n0+srow)*K + sko;
  const ushort* bpl = PREC ? (BtLo + (size_t)(n0+srow)*K + sko) : Bt;

  for (int k0=0; k0<K; k0+=32){
    // B: two coalesced 16B loads (pre-converted, pre-transposed)
    uint4 b0 = *reinterpret_cast<const uint4*>(bp + k0);
    uint4 b1 = *reinterpret_cast<const uint4*>(bp + k0 + 8);
    uint4 bl0, bl1;
    if (PREC){
      bl0 = *reinterpret_cast<const uint4*>(bpl + k0);
      bl1 = *reinterpret_cast<const uint4*>(bpl + k0 + 8);
    }
    // A: 16 consecutive fp32
    float4 a0 = *reinterpret_cast<const float4*>(ap + k0);
    float4 a1 = *reinterpret_cast<const float4*>(ap + k0 + 4);
    float4 a2 = *reinterpret_cast<const float4*>(ap + k0 + 8);
    float4 a3 = *reinterpret_cast<const float4*>(ap + k0 + 12);
    if constexpr (PREC==0){
      uint4 wa0 = make_uint4(pkh2(a0.x,a0.y),pkh2(a0.z,a0.w),pkh2(a1.x,a1.y),pkh2(a1.z,a1.w));
      uint4 wa1 = make_uint4(pkh2(a2.x,a2.y),pkh2(a2.z,a2.w),pkh2(a3.x,a3.y),pkh2(a3.z,a3.w));
      *reinterpret_cast<uint4*>(&As[0][srow][sko])   = wa0;
      *reinterpret_cast<uint4*>(&As[0][srow][sko+8]) = wa1;
      *reinterpret_cast<uint4*>(&Bs[0][srow][sko])   = b0;
      *reinterpret_cast<uint4*>(&Bs[0][srow][sko+8]) = b1;
    } else {
      float fa[16] = {a0.x,a0.y,a0.z,a0.w, a1.x,a1.y,a1.z,a1.w,
                      a2.x,a2.y,a2.z,a2.w, a3.x,a3.y,a3.z,a3.w};
      uint4 hi, lo;
      split8(fa,   hi, lo);
      *reinterpret_cast<uint4*>(&As[0][srow][sko])   = hi;
      *reinterpret_cast<uint4*>(&As[1][srow][sko])   = lo;
      split8(fa+8, hi, lo);
      *reinterpret_cast<uint4*>(&As[0][srow][sko+8]) = hi;
      *reinterpret_cast<uint4*>(&As[1][srow][sko+8]) = lo;
      *reinterpret_cast<uint4*>(&Bs[0][srow][sko])   = b0;
      *reinterpret_cast<uint4*>(&Bs[0][srow][sko+8]) = b1;
      *reinterpret_cast<uint4*>(&Bs[1][srow][sko])   = bl0;
      *reinterpret_cast<uint4*>(&Bs[1][srow][sko+8]) = bl1;
    }
    __syncthreads();

    if constexpr (PREC==0){
      f16x8 af[4], bfr[4];
#pragma unroll
      for (int mi=0;mi<4;mi++)
        af[mi] = *reinterpret_cast<const f16x8*>(&As[0][wm+mi*16+fr][fk]);
#pragma unroll
      for (int nj=0;nj<4;nj++)
        bfr[nj] = *reinterpret_cast<const f16x8*>(&Bs[0][wn+nj*16+fr][fk]);
#pragma unroll
      for (int mi=0;mi<4;mi++)
#pragma unroll
        for (int nj=0;nj<4;nj++)
          acc[mi][nj] = __builtin_amdgcn_mfma_f32_16x16x32_f16(af[mi], bfr[nj], acc[mi][nj], 0,0,0);
    } else {
      bf16x8 ah[4], al[4], bh[4], bl[4];
#pragma unroll
      for (int mi=0;mi<4;mi++){
        ah[mi] = *reinterpret_cast<const bf16x8*>(&As[0][wm+mi*16+fr][fk]);
        al[mi] = *reinterpret_cast<const bf16x8*>(&As[1][wm+mi*16+fr][fk]);
      }
#pragma unroll
      for (int nj=0;nj<4;nj++){
        bh[nj] = *reinterpret_cast<const bf16x8*>(&Bs[0][wn+nj*16+fr][fk]);
        bl[nj] = *reinterpret_cast<const bf16x8*>(&Bs[1][wn+nj*16+fr][fk]);
      }
#pragma unroll
      for (int mi=0;mi<4;mi++)
#pragma unroll
        for (int nj=0;nj<4;nj++){
          acc[mi][nj] = __builtin_amdgcn_mfma_f32_16x16x32_bf16(ah[mi], bh[nj], acc[mi][nj], 0,0,0);
          acc[mi][nj] = __builtin_amdgcn_mfma_f32_16x16x32_bf16(al[mi], bh[nj], acc[mi][nj], 0,0,0);
          acc[mi][nj] = __builtin_amdgcn_mfma_f32_16x16x32_bf16(ah[mi], bl[nj], acc[mi][nj], 0,0,0);
        }
    }
    __syncthreads();
  }
  // epilogue: D row=(lane>>4)*4+reg, col=lane&15
#pragma unroll
  for (int mi=0;mi<4;mi++){
#pragma unroll
    for (int r=0;r<4;r++){
      int row = m0 + wm + mi*16 + (lane>>4)*4 + r;
      float* crow = C + (size_t)row*N;
#pragma unroll
      for (int nj=0;nj<4;nj++){
        int col = n0 + wn + nj*16 + fr;
        if (col < N){
          float val = acc[mi][nj][r];
          if (bias) val += bias[col];
          if (EPI==1) val = geluf(val);
          if (ACC) crow[col] += val; else crow[col] = val;
        }
      }
    }
  }
}

// ---------------- generic flash attention (fp32, unchanged this round) --------
__global__ __launch_bounds__(256)
void k_attn(const float* __restrict__ Q, long qB,
            const float* __restrict__ K0, long k0B, int k0R, int k0C, int k0H,
            const float* __restrict__ K1, long k1B, int k1R, int k1C, int k1H,
            const float* __restrict__ V0, long v0B, int v0R, int v0C, int v0H,
            const float* __restrict__ V1, long v1B, int v1R, int v1C, int v1H,
            int n0, int n1,
            float* __restrict__ O, long oB,
            float scale, int winmode, int has_mem,
            const float* __restrict__ table){
  __shared__ float Kt[64][68];
  __shared__ float Vt[64][68];
  __shared__ float qsm[32][68];
  __shared__ float pt[4][8][64];
  __shared__ float tcol[512];
  int b = blockIdx.z, h = blockIdx.y, rt = blockIdx.x;
  int t = threadIdx.x, w = t>>6, lane = t&63;
  int i0 = rt*32 + w*8;
  int qc = h*64;
  if (winmode){
    tcol[t]     = table[t*8 + h];
    tcol[t+256] = table[(t+256)*8 + h];
  }
#pragma unroll
  for (int r=0;r<8;r++)
    qsm[w*8+r][lane] = Q[(size_t)b*qB + (size_t)(i0+r)*512 + qc + lane];
  float o[8] = {0,0,0,0,0,0,0,0};
  float m[8], l[8] = {0,0,0,0,0,0,0,0};
#pragma unroll
  for (int r=0;r<8;r++) m[r] = -1e30f;
  int kc0 = k0H? qc : k0C, kc1 = k1H? qc : k1C;
  int vc0 = v0H? qc : v0C, vc1 = v1H? qc : v1C;
  int nk = n0+n1, nt = nk>>6;
  int sj = t>>2, sc = (t&3)*16;
  for (int jt=0;jt<nt;jt++){
    int jgs = jt*64 + sj;
    const float* kp; const float* vp;
    if (jgs < n0){
      kp = K0 + (size_t)b*k0B + (size_t)jgs*k0R + kc0 + sc;
      vp = V0 + (size_t)b*v0B + (size_t)jgs*v0R + vc0 + sc;
    } else {
      int j1 = jgs - n0;
      kp = K1 + (size_t)b*k1B + (size_t)j1*k1R + kc1 + sc;
      vp = V1 + (size_t)b*v1B + (size_t)j1*v1R + vc1 + sc;
    }
#pragma unroll
    for (int u=0;u<4;u++){
      *reinterpret_cast<float4*>(&Kt[sj][sc+u*4]) = *reinterpret_cast<const float4*>(kp + u*4);
      *reinterpret_cast<float4*>(&Vt[sj][sc+u*4]) = *reinterpret_cast<const float4*>(vp + u*4);
    }
    __syncthreads();
    int jgl = jt*64 + lane;
    float s[8] = {0,0,0,0,0,0,0,0};
#pragma unroll
    for (int d4=0;d4<16;d4++){
      float4 kv = *reinterpret_cast<const float4*>(&Kt[lane][d4*4]);
#pragma unroll
      for (int r=0;r<8;r++){
        float4 qv = *reinterpret_cast<const float4*>(&qsm[w*8+r][d4*4]);
        s[r] += kv.x*qv.x + kv.y*qv.y + kv.z*qv.z + kv.w*qv.w;
      }
    }
#pragma unroll
    for (int r=0;r<8;r++){
      float sv;
      if (winmode){
        int ia = i0 + r;
        bool valid = (jgl > ia) && (jgl <= ia+512) && (has_mem || jgl >= 512);
        sv = valid ? s[r]*scale + tcol[ia+512-jgl] : -1e9f;
      } else {
        sv = s[r]*scale;
      }
      float tm = sv;
      for (int off=32;off;off>>=1) tm = fmaxf(tm, __shfl_xor(tm,off));
      float mn = fmaxf(m[r], tm);
      float corr = __expf(m[r]-mn);
      float p = (sv <= -1e8f) ? 0.f : __expf(sv - mn);
      float ps = p;
      for (int off=32;off;off>>=1) ps += __shfl_xor(ps,off);
      l[r] = l[r]*corr + ps;
      m[r] = mn;
      o[r] *= corr;
      pt[w][r][lane] = p;
    }
    __syncthreads();
    for (int jj=0;jj<64;jj++){
      float vv = Vt[jj][lane];
#pragma unroll
      for (int r=0;r<8;r++) o[r] += pt[w][r][jj]*vv;
    }
    __syncthreads();
  }
#pragma unroll
  for (int r=0;r<8;r++)
    O[(size_t)b*oB + (size_t)(i0+r)*512 + qc + lane] = o[r]/l[r];
}

// ---------------- small utility kernels ----------------
__global__ void k_copy(float* __restrict__ dst, const float* __restrict__ src, int n){
  int idx = blockIdx.x*blockDim.x + threadIdx.x;
  if (idx < n) dst[idx] = src[idx];
}
__global__ void k_gather_xb(float* __restrict__ dst, const float* __restrict__ src, int nb){
  int idx = blockIdx.x*blockDim.x + threadIdx.x;
  if (idx >= 1048576) return;
  int b = idx >> 18, rem = idx & 262143;
  dst[idx] = src[(size_t)b*524288 + (size_t)nb*262144 + rem];
}
__global__ void k_xlout(float* __restrict__ dk, float* __restrict__ dv,
                        const float* __restrict__ k, const float* __restrict__ v){
  int idx = blockIdx.x*blockDim.x + threadIdx.x;
  if (idx >= 1048576) return;
  int b = idx >> 18, rem = idx & 262143;
  size_t s = (size_t)b*524288 + 262144 + rem;
  dk[idx] = k[s]; dv[idx] = v[s];
}
__global__ void k_ema(float* __restrict__ st, const float* __restrict__ sp,
                      const float* __restrict__ beta, int n){
  int idx = blockIdx.x*blockDim.x + threadIdx.x;
  if (idx >= n) return;
  int d = idx & 511;
  float dec = 1.f/(1.f+__expf(-beta[d]));
  st[idx] = dec*st[idx] + (1.f-dec)*sp[idx];
}

// ---------------- launcher ----------------
extern "C" void kernel_launch(void* const* d_in, const int* in_sizes, int n_in,
                              void* d_out, int out_size, void* d_ws, size_t ws_size,
                              hipStream_t stream){
  // floats: 24,121,344 (96.5 MB) + ushorts: 34,013,184 (68 MB) = 164,511,744 B
  if (ws_size < (size_t)164511744) return;

  const int*   x        = (const int*)  d_in[0];
  const float* tok_emb  = (const float*)d_in[1];
  const float* pw1 = (const float*)d_in[2];
  const float* pb1 = (const float*)d_in[3];
  const float* pw2 = (const float*)d_in[4];
  const float* pb2 = (const float*)d_in[5];
  const float* pw3 = (const float*)d_in[6];
  const float* pb3 = (const float*)d_in[7];
  const float* ln_g = (const float*)d_in[8];
  const float* Wq = (const float*)d_in[9];
  const float* Wk = (const float*)d_in[10];
  const float* Wv = (const float*)d_in[11];
  const float* Wo = (const float*)d_in[12];
  const float* q_scale = (const float*)d_in[13];
  const float* k_scale = (const float*)d_in[14];
  const float* Wo_state = (const float*)d_in[15];
  const float* state_norm_g = (const float*)d_in[16];
  const float* Wq2s = (const float*)d_in[17];
  const float* Ws2q = (const float*)d_in[18];
  const float* Ws2kv = (const float*)d_in[19];
  const float* W_state_out = (const float*)d_in[20];
  const float* ema_beta = (const float*)d_in[21];
  const float* ff_g = (const float*)d_in[22];
  const float* ff_w1 = (const float*)d_in[23];
  const float* ff_b1 = (const float*)d_in[24];
  const float* ff_w2 = (const float*)d_in[25];
  const float* ff_b2 = (const float*)d_in[26];
  const float* final_g = (const float*)d_in[27];
  const float* W_logits = (const float*)d_in[28];
  const float* xl_mem_k = (const float*)d_in[29];
  const float* xl_mem_v = (const float*)d_in[30];
  const float* states_in = (const float*)d_in[31];

  float* out = (float*)d_out;
  float* out_xlk    = out + 81920000;
  float* out_xlv    = out + 84017152;
  float* out_states = out + 86114304;

  float* p = (float*)d_ws;
  float* hstate   = p; p += 2097152;
  float* xn       = p; p += 2097152;
  float* q        = p; p += 2097152;
  float* k        = p; p += 2097152;
  float* v        = p; p += 2097152;
  float* attn_out = p; p += 2097152;
  float* to_state = p; p += 2097152;
  float* ff1      = p; p += 8388608;
  float* states_cur = p; p += 1048576;
  float* table    = p; p += 4096;
  // rec scratch aliases inside ff1
  float* sn    = ff1;
  float* skv   = ff1 + 1048576;
  float* xb    = ff1 + 1310720;
  float* q2s   = ff1 + 2359296;
  float* sq    = ff1 + 3407872;
  float* satt  = ff1 + 4456448;
  float* sproj = ff1 + 5505024;

  // fp16/bf16 weight region (ushort units)
  ushort* us = (ushort*)p;
  ushort* wqh   = us; us += 1572864;   // 6 x 512 x 512
  ushort* wql   = us; us += 1572864;
  ushort* wkh   = us; us += 1572864;
  ushort* wkl   = us; us += 1572864;
  ushort* wvT   = us; us += 1572864;
  ushort* woT   = us; us += 1572864;
  ushort* ffw1T = us; us += 6291456;   // 6 x 2048 x 512
  ushort* ffw2T = us; us += 6291456;   // 6 x 512 x 2048
  ushort* wostT = us; us += 262144;
  ushort* wstoutT = us; us += 262144;
  ushort* wq2sh = us; us += 262144;
  ushort* wq2sl = us; us += 262144;
  ushort* ws2qh = us; us += 262144;
  ushort* ws2ql = us; us += 262144;
  ushort* ws2kvh = us; us += 65536;    // 128 x 512
  ushort* ws2kvl = us; us += 65536;
  ushort* wlogT  = us; us += 10289152; // 20096 x 512

  // ---- weight prep (once per launch) ----
  k_prep<1><<<dim3(16,16,6),256,0,stream>>>(Wq, wqh, wql, 512,512,512);
  k_prep<1><<<dim3(16,16,6),256,0,stream>>>(Wk, wkh, wkl, 512,512,512);
  k_prep<0><<<dim3(16,16,6),256,0,stream>>>(Wv, wvT, nullptr, 512,512,512);
  k_prep<0><<<dim3(16,16,6),256,0,stream>>>(Wo, woT, nullptr, 512,512,512);
  k_prep<0><<<dim3(64,16,6),256,0,stream>>>(ff_w1, ffw1T, nullptr, 512,2048,2048);
  k_prep<0><<<dim3(16,64,6),256,0,stream>>>(ff_w2, ffw2T, nullptr, 2048,512,512);
  k_prep<0><<<dim3(16,16,1),256,0,stream>>>(Wo_state, wostT, nullptr, 512,512,512);
  k_prep<0><<<dim3(16,16,1),256,0,stream>>>(W_state_out, wstoutT, nullptr, 512,512,512);
  k_prep<1><<<dim3(16,16,1),256,0,stream>>>(Wq2s, wq2sh, wq2sl, 512,512,512);
  k_prep<1><<<dim3(16,16,1),256,0,stream>>>(Ws2q, ws2qh, ws2ql, 512,512,512);
  k_prep<1><<<dim3(4,16,1),256,0,stream>>>(Ws2kv, ws2kvh, ws2kvl, 512,128,128);
  k_prep<0><<<dim3(628,16,1),256,0,stream>>>(W_logits, wlogT, nullptr, 512,20000,20096);

  k_embed<<<2048, 256, 0, stream>>>(x, tok_emb, hstate, 524288);
  k_postable<<<512, 128, 0, stream>>>(pw1,pb1,pw2,pb2,pw3,pb3, table);
  k_copy<<<4096, 256, 0, stream>>>(states_cur, states_in, 1048576);

  for (int l=0;l<6;l++){
    k_ln<<<4096,256,0,stream>>>(hstate, ln_g + l*512, xn);
    k_gemm_mfma<0,0,1><<<dim3(32,4),256,0,stream>>>(xn, wqh + (size_t)l*262144, wql + (size_t)l*262144, nullptr, q, 4096,512,512);
    k_gemm_mfma<0,0,1><<<dim3(32,4),256,0,stream>>>(xn, wkh + (size_t)l*262144, wkl + (size_t)l*262144, nullptr, k, 4096,512,512);
    k_gemm_mfma<0,0,0><<<dim3(32,4),256,0,stream>>>(xn, wvT + (size_t)l*262144, nullptr, nullptr, v, 4096,512,512);
    float scale = 0.125f;
    if (l>=3){
      k_qkrms<<<4096,512,0,stream>>>(q, k, q_scale + l*64, k_scale + l*64);
      scale = 8.f;
    }
    bool isxl = (l==4 || l==5);
    int src = (l==4)? 1 : 0;     // roll(-1): xl layer 4 -> mem[1], layer 5 -> mem[0]
    for (int nb=0;nb<2;nb++){
      const float* K0; const float* V0; long k0B;
      int has_mem;
      if (nb==0){
        if (isxl){ K0 = xl_mem_k + (size_t)src*1048576; V0 = xl_mem_v + (size_t)src*1048576;
                   k0B = 262144; has_mem = 1; }
        else     { K0 = k; V0 = v; k0B = 524288; has_mem = 0; }   // dummy (masked)
      } else {
        K0 = k; V0 = v; k0B = 524288; has_mem = 1;
      }
      k_attn<<<dim3(16,8,4),256,0,stream>>>(
        q + nb*262144, 524288L,
        K0, k0B, 512, 0, 1,
        k + nb*262144, 524288L, 512, 0, 1,
        V0, k0B, 512, 0, 1,
        v + nb*262144, 524288L, 512, 0, 1,
        512, 512,
        attn_out + nb*262144, 524288L,
        scale, 1, has_mem, table);
    }
    k_gemm_mfma<1,0,0><<<dim3(32,4),256,0,stream>>>(attn_out, woT + (size_t)l*262144, nullptr, nullptr, hstate, 4096,512,512);
    if (l==3){
      for (int nb=0;nb<2;nb++){
        k_ln<<<2048,256,0,stream>>>(states_cur, state_norm_g, sn);
        k_gemm_mfma<0,0,1><<<dim3(16,1),256,0,stream>>>(sn, ws2kvh, ws2kvl, nullptr, skv, 2048,128,512);
        k_gather_xb<<<4096,256,0,stream>>>(xb, xn, nb);
        k_gemm_mfma<0,0,1><<<dim3(16,4),256,0,stream>>>(xb, wq2sh, wq2sl, nullptr, q2s, 2048,512,512);
        k_attn<<<dim3(16,8,4),256,0,stream>>>(
          q2s, 262144L,
          skv, 65536L, 128, 0, 0,
          skv, 65536L, 128, 0, 0,
          skv, 65536L, 128, 64, 0,
          skv, 65536L, 128, 64, 0,
          512, 0,
          to_state + nb*262144, 524288L,
          0.125f, 0, 0, table);
        k_gemm_mfma<0,0,1><<<dim3(16,4),256,0,stream>>>(sn, ws2qh, ws2ql, nullptr, sq, 2048,512,512);
        k_attn<<<dim3(16,8,4),256,0,stream>>>(
          sq, 262144L,
          skv, 65536L, 128, 0, 0,
          k + nb*262144, 524288L, 512, 0, 1,
          skv, 65536L, 128, 64, 0,
          v + nb*262144, 524288L, 512, 0, 1,
          512, 512,
          satt, 262144L,
          0.125f, 0, 0, table);
        k_gemm_mfma<0,0,0><<<dim3(16,4),256,0,stream>>>(satt, wstoutT, nullptr, nullptr, sproj, 2048,512,512);
        k_ema<<<4096,256,0,stream>>>(states_cur, sproj, ema_beta, 1048576);
      }
      k_gemm_mfma<1,0,0><<<dim3(32,4),256,0,stream>>>(to_state, wostT, nullptr, nullptr, hstate, 4096,512,512);
    }
    if (isxl){
      int xli = l-4;
      k_xlout<<<4096,256,0,stream>>>(out_xlk + (size_t)xli*1048576,
                                     out_xlv + (size_t)xli*1048576, k, v);
    }
    k_ln<<<4096,256,0,stream>>>(hstate, ff_g + l*512, xn);
    k_gemm_mfma<0,1,0><<<dim3(32,16),256,0,stream>>>(xn, ffw1T + (size_t)l*1048576, nullptr, ff_b1 + l*2048, ff1, 4096,2048,512);
    k_gemm_mfma<1,0,0><<<dim3(32,4),256,0,stream>>>(ff1, ffw2T + (size_t)l*1048576, nullptr, ff_b2 + l*512, hstate, 4096,512,2048);
  }
  k_ln<<<4096,256,0,stream>>>(hstate, final_g, xn);
  k_gemm_mfma<0,0,0><<<dim3(32,157),256,0,stream>>>(xn, wlogT, nullptr, nullptr, out, 4096,20000,512);
  k_copy<<<4096, 256, 0, stream>>>(out_states, states_cur, 1048576);
}

// Round 7
// 2969.164 us; speedup vs baseline: 4.2410x; 2.6095x over previous
//
#include <hip/hip_runtime.h>
#include <math.h>

// B=4 N=1024 V=20000 D=512 H=8 DH=64 W=512 NB=2 NS=512 FF=2048

typedef __attribute__((ext_vector_type(8))) __bf16 bf16x8;
typedef __attribute__((ext_vector_type(8))) _Float16 f16x8;
typedef __attribute__((ext_vector_type(4))) float f32x4;

__device__ __forceinline__ ushort f2b(float f){
  uint u = __float_as_uint(f);
  uint r = (u + 0x7FFFu + ((u >> 16) & 1u)) >> 16;
  return (ushort)r;
}
__device__ __forceinline__ ushort f2h(float f){
  _Float16 h = (_Float16)f;
  return *reinterpret_cast<ushort*>(&h);
}
__device__ __forceinline__ uint pkh2(float a, float b){
  return (uint)f2h(a) | ((uint)f2h(b)<<16);
}
__device__ __forceinline__ void split8(const float* f, uint4& hi, uint4& lo){
  ushort h[8], l[8];
#pragma unroll
  for (int i=0;i<8;i++){
    h[i] = f2b(f[i]);
    float fh = __uint_as_float((uint)h[i] << 16);
    l[i] = f2b(f[i] - fh);
  }
  hi = make_uint4((uint)h[0]|((uint)h[1]<<16), (uint)h[2]|((uint)h[3]<<16),
                  (uint)h[4]|((uint)h[5]<<16), (uint)h[6]|((uint)h[7]<<16));
  lo = make_uint4((uint)l[0]|((uint)l[1]<<16), (uint)l[2]|((uint)l[3]<<16),
                  (uint)l[4]|((uint)l[5]<<16), (uint)l[6]|((uint)l[7]<<16));
}

// ---------------- weight prep (unchanged) ----------------
template<int MODE>
__global__ __launch_bounds__(256)
void k_prep(const float* __restrict__ src, ushort* __restrict__ dh,
            ushort* __restrict__ dl, int K, int N, int Npad){
  __shared__ float tile[32][33];
  int z = blockIdx.z;
  src += (size_t)z*K*N;
  dh  += (size_t)z*Npad*K;
  if (MODE) dl += (size_t)z*Npad*K;
  int n0 = blockIdx.x*32, k0 = blockIdx.y*32;
  int tx = threadIdx.x&31, ty = threadIdx.x>>5;
#pragma unroll
  for (int i=0;i<4;i++){
    int kk = k0 + ty + i*8, nn = n0 + tx;
    tile[ty+i*8][tx] = (nn < N) ? src[(size_t)kk*N + nn] : 0.f;
  }
  __syncthreads();
#pragma unroll
  for (int i=0;i<4;i++){
    int nn = n0 + ty + i*8, kk = k0 + tx;
    float v = tile[tx][ty+i*8];
    if (MODE==0){
      dh[(size_t)nn*K + kk] = f2h(v);
    } else {
      ushort h = f2b(v);
      dh[(size_t)nn*K + kk] = h;
      float fh = __uint_as_float((uint)h<<16);
      dl[(size_t)nn*K + kk] = f2b(v - fh);
    }
  }
}

// ---------------- V transpose: fp32 [b][key][cols] -> fp16 [b][h][d=64][NK] ----
__global__ __launch_bounds__(256)
void k_vtrans(const float* __restrict__ src, ushort* __restrict__ dst,
              long sB, int sR, int sMH, long dB, long dH, int NK){
  __shared__ float tile[64][65];
  int kc = blockIdx.x, h = blockIdx.y, b = blockIdx.z;
  int t = threadIdx.x;
  int key = t>>2, doff = (t&3)*16;
  const float* sp = src + (size_t)b*sB + (size_t)(kc*64+key)*sR + (sMH? h*64:0) + doff;
#pragma unroll
  for (int u=0;u<4;u++){
    float4 v = *reinterpret_cast<const float4*>(sp + u*4);
    tile[key][doff+u*4+0]=v.x; tile[key][doff+u*4+1]=v.y;
    tile[key][doff+u*4+2]=v.z; tile[key][doff+u*4+3]=v.w;
  }
  __syncthreads();
  int d = t>>2, kf = (t&3)*16;
  ushort* dp = dst + (size_t)b*dB + (size_t)h*dH + (size_t)d*NK + kc*64 + kf;
  ushort tmp[16];
#pragma unroll
  for (int u=0;u<16;u++) tmp[u] = f2h(tile[kf+u][d]);
  uint4 o0 = make_uint4((uint)tmp[0]|((uint)tmp[1]<<16), (uint)tmp[2]|((uint)tmp[3]<<16),
                        (uint)tmp[4]|((uint)tmp[5]<<16), (uint)tmp[6]|((uint)tmp[7]<<16));
  uint4 o1 = make_uint4((uint)tmp[8]|((uint)tmp[9]<<16), (uint)tmp[10]|((uint)tmp[11]<<16),
                        (uint)tmp[12]|((uint)tmp[13]<<16),(uint)tmp[14]|((uint)tmp[15]<<16));
  *reinterpret_cast<uint4*>(dp)   = o0;
  *reinterpret_cast<uint4*>(dp+8) = o1;
}

// ---------------- embed / postable / ln / qkrms (unchanged) ----------------
__global__ void k_embed(const int* __restrict__ x, const float* __restrict__ emb,
                        float* __restrict__ h, int total4){
  int idx = blockIdx.x*blockDim.x + threadIdx.x;
  if (idx >= total4) return;
  int row = idx >> 7;
  int c4  = idx & 127;
  int tok = x[row];
  reinterpret_cast<float4*>(h)[idx] =
      reinterpret_cast<const float4*>(emb)[(size_t)tok*128 + c4];
}

__global__ void k_postable(const float* __restrict__ w1, const float* __restrict__ b1,
                           const float* __restrict__ w2, const float* __restrict__ b2,
                           const float* __restrict__ w3, const float* __restrict__ b3,
                           float* __restrict__ table){
  __shared__ float h1[128];
  __shared__ float h2[128];
  int d = blockIdx.x, t = threadIdx.x;
  float a = (float)d * w1[t] + b1[t];
  h1[t] = a / (1.f + __expf(-a));
  __syncthreads();
  float acc = b2[t];
  for (int p=0;p<128;p++) acc += h1[p]*w2[p*128+t];
  h2[t] = acc / (1.f + __expf(-acc));
  __syncthreads();
  if (t < 8){
    float acc2 = b3[t];
    for (int p=0;p<128;p++) acc2 += h2[p]*w3[p*8+t];
    table[d*8+t] = acc2;
  }
}

__global__ void k_ln(const float* __restrict__ x, const float* __restrict__ g,
                     float* __restrict__ y){
  int row = blockIdx.x;
  int t = threadIdx.x;
  float2 v = reinterpret_cast<const float2*>(x + (size_t)row*512)[t];
  float s = v.x+v.y, ss = v.x*v.x+v.y*v.y;
  for (int o=32;o;o>>=1){ s += __shfl_down(s,o); ss += __shfl_down(ss,o); }
  __shared__ float ls[4], lss[4];
  __shared__ float smu, srs;
  int wid = t>>6;
  if ((t&63)==0){ ls[wid]=s; lss[wid]=ss; }
  __syncthreads();
  if (t==0){
    float S=ls[0]+ls[1]+ls[2]+ls[3], SS=lss[0]+lss[1]+lss[2]+lss[3];
    float mu = S*(1.f/512.f);
    float var = SS*(1.f/512.f) - mu*mu;
    smu = mu; srs = rsqrtf(var + 1e-5f);
  }
  __syncthreads();
  float mu=smu, rs=srs;
  float2 gg = reinterpret_cast<const float2*>(g)[t];
  reinterpret_cast<float2*>(y + (size_t)row*512)[t] =
      make_float2((v.x-mu)*rs*gg.x, (v.y-mu)*rs*gg.y);
}

__global__ void k_qkrms(float* __restrict__ q, float* __restrict__ k,
                        const float* __restrict__ qs, const float* __restrict__ ks){
  int row = blockIdx.x;
  int h = threadIdx.x >> 6, d = threadIdx.x & 63;
  size_t base = (size_t)row*512 + h*64 + d;
  float qv = q[base];
  float s = qv*qv;
  for (int o=32;o;o>>=1) s += __shfl_xor(s,o);
  q[base] = qv*rsqrtf(s+1e-12f)*qs[d];
  float kv = k[base];
  float s2 = kv*kv;
  for (int o=32;o;o>>=1) s2 += __shfl_xor(s2,o);
  k[base] = kv*rsqrtf(s2+1e-12f)*ks[d];
}

__device__ __forceinline__ float geluf(float x){
  float u = 0.7978845608028654f*(x + 0.044715f*x*x*x);
  return 0.5f*x*(1.f + tanhf(u));
}

// ---------------- MFMA GEMM (unchanged from round 6) ----------------
template<int ACC, int EPI, int PREC>
__global__ __launch_bounds__(256)
void k_gemm_mfma(const float* __restrict__ A, const ushort* __restrict__ Bt,
                 const ushort* __restrict__ BtLo, const float* __restrict__ bias,
                 float* __restrict__ C, int M, int N, int K){
  __shared__ ushort As[PREC?2:1][128][32];
  __shared__ ushort Bs[PREC?2:1][128][32];
  const int t = threadIdx.x;
  const int m0 = blockIdx.x*128, n0 = blockIdx.y*128;
  const int w = t>>6, lane = t&63;
  const int wm = (w>>1)*64, wn = (w&1)*64;
  const int fr = lane&15, fk = (lane>>4)*8;
  const int srow = t>>1, sko = (t&1)*16;

  f32x4 acc[4][4];
#pragma unroll
  for (int i=0;i<4;i++)
#pragma unroll
    for (int j=0;j<4;j++){ acc[i][j][0]=0.f; acc[i][j][1]=0.f; acc[i][j][2]=0.f; acc[i][j][3]=0.f; }

  const float*  ap  = A  + (size_t)(m0+srow)*K + sko;
  const ushort* bp  = Bt + (size_t)(n0+srow)*K + sko;
  const ushort* bpl = PREC ? (BtLo + (size_t)(n0+srow)*K + sko) : Bt;

  for (int k0=0; k0<K; k0+=32){
    uint4 b0 = *reinterpret_cast<const uint4*>(bp + k0);
    uint4 b1 = *reinterpret_cast<const uint4*>(bp + k0 + 8);
    uint4 bl0, bl1;
    if (PREC){
      bl0 = *reinterpret_cast<const uint4*>(bpl + k0);
      bl1 = *reinterpret_cast<const uint4*>(bpl + k0 + 8);
    }
    float4 a0 = *reinterpret_cast<const float4*>(ap + k0);
    float4 a1 = *reinterpret_cast<const float4*>(ap + k0 + 4);
    float4 a2 = *reinterpret_cast<const float4*>(ap + k0 + 8);
    float4 a3 = *reinterpret_cast<const float4*>(ap + k0 + 12);
    if constexpr (PREC==0){
      uint4 wa0 = make_uint4(pkh2(a0.x,a0.y),pkh2(a0.z,a0.w),pkh2(a1.x,a1.y),pkh2(a1.z,a1.w));
      uint4 wa1 = make_uint4(pkh2(a2.x,a2.y),pkh2(a2.z,a2.w),pkh2(a3.x,a3.y),pkh2(a3.z,a3.w));
      *reinterpret_cast<uint4*>(&As[0][srow][sko])   = wa0;
      *reinterpret_cast<uint4*>(&As[0][srow][sko+8]) = wa1;
      *reinterpret_cast<uint4*>(&Bs[0][srow][sko])   = b0;
      *reinterpret_cast<uint4*>(&Bs[0][srow][sko+8]) = b1;
    } else {
      float fa[16] = {a0.x,a0.y,a0.z,a0.w, a1.x,a1.y,a1.z,a1.w,
                      a2.x,a2.y,a2.z,a2.w, a3.x,a3.y,a3.z,a3.w};
      uint4 hi, lo;
      split8(fa,   hi, lo);
      *reinterpret_cast<uint4*>(&As[0][srow][sko])   = hi;
      *reinterpret_cast<uint4*>(&As[1][srow][sko])   = lo;
      split8(fa+8, hi, lo);
      *reinterpret_cast<uint4*>(&As[0][srow][sko+8]) = hi;
      *reinterpret_cast<uint4*>(&As[1][srow][sko+8]) = lo;
      *reinterpret_cast<uint4*>(&Bs[0][srow][sko])   = b0;
      *reinterpret_cast<uint4*>(&Bs[0][srow][sko+8]) = b1;
      *reinterpret_cast<uint4*>(&Bs[1][srow][sko])   = bl0;
      *reinterpret_cast<uint4*>(&Bs[1][srow][sko+8]) = bl1;
    }
    __syncthreads();

    if constexpr (PREC==0){
      f16x8 af[4], bfr[4];
#pragma unroll
      for (int mi=0;mi<4;mi++)
        af[mi] = *reinterpret_cast<const f16x8*>(&As[0][wm+mi*16+fr][fk]);
#pragma unroll
      for (int nj=0;nj<4;nj++)
        bfr[nj] = *reinterpret_cast<const f16x8*>(&Bs[0][wn+nj*16+fr][fk]);
#pragma unroll
      for (int mi=0;mi<4;mi++)
#pragma unroll
        for (int nj=0;nj<4;nj++)
          acc[mi][nj] = __builtin_amdgcn_mfma_f32_16x16x32_f16(af[mi], bfr[nj], acc[mi][nj], 0,0,0);
    } else {
      bf16x8 ah[4], al[4], bh[4], bl[4];
#pragma unroll
      for (int mi=0;mi<4;mi++){
        ah[mi] = *reinterpret_cast<const bf16x8*>(&As[0][wm+mi*16+fr][fk]);
        al[mi] = *reinterpret_cast<const bf16x8*>(&As[1][wm+mi*16+fr][fk]);
      }
#pragma unroll
      for (int nj=0;nj<4;nj++){
        bh[nj] = *reinterpret_cast<const bf16x8*>(&Bs[0][wn+nj*16+fr][fk]);
        bl[nj] = *reinterpret_cast<const bf16x8*>(&Bs[1][wn+nj*16+fr][fk]);
      }
#pragma unroll
      for (int mi=0;mi<4;mi++)
#pragma unroll
        for (int nj=0;nj<4;nj++){
          acc[mi][nj] = __builtin_amdgcn_mfma_f32_16x16x32_bf16(ah[mi], bh[nj], acc[mi][nj], 0,0,0);
          acc[mi][nj] = __builtin_amdgcn_mfma_f32_16x16x32_bf16(al[mi], bh[nj], acc[mi][nj], 0,0,0);
          acc[mi][nj] = __builtin_amdgcn_mfma_f32_16x16x32_bf16(ah[mi], bl[nj], acc[mi][nj], 0,0,0);
        }
    }
    __syncthreads();
  }
#pragma unroll
  for (int mi=0;mi<4;mi++){
#pragma unroll
    for (int r=0;r<4;r++){
      int row = m0 + wm + mi*16 + (lane>>4)*4 + r;
      float* crow = C + (size_t)row*N;
#pragma unroll
      for (int nj=0;nj<4;nj++){
        int col = n0 + wn + nj*16 + fr;
        if (col < N){
          float val = acc[mi][nj][r];
          if (bias) val += bias[col];
          if (EPI==1) val = geluf(val);
          if (ACC) crow[col] += val; else crow[col] = val;
        }
      }
    }
  }
}

// ---------------- MFMA flash attention ----------------
// Block: 64 q rows (4 waves x 16), loops over 64-key tiles from two segments.
// Q,K fp32 global (converted to fp16 at staging); V pre-transposed fp16 [d][key].
// WIN=1: sliding-window mask + pos-bias table; WIN=0: plain softmax.
template<int WIN>
__global__ __launch_bounds__(256)
void k_attn_mfma(const float* __restrict__ Q, long qB,
                 const float* __restrict__ K0, long k0B, int k0R, int k0H,
                 const float* __restrict__ K1, long k1B, int k1R, int k1H,
                 const ushort* __restrict__ VT0, long vt0B, long vt0H, int vt0D,
                 const ushort* __restrict__ VT1, long vt1B, long vt1H, int vt1D,
                 int n0, int n1,
                 float* __restrict__ O, long oB,
                 float scale, int has_mem, const float* __restrict__ table){
  __shared__ ushort Qs[64][72];
  __shared__ ushort Ks[64][72];
  __shared__ ushort Vs[64][72];
  __shared__ ushort Pw[4][16][72];
  __shared__ float tcol[512];
  const int b = blockIdx.z, h = blockIdx.y, qt = blockIdx.x;
  const int t = threadIdx.x, w = t>>6, lane = t&63;
  const int fr = lane&15, fg = lane>>4;
  if (WIN){
    tcol[t]     = table[t*8 + h];
    tcol[t+256] = table[(t+256)*8 + h];
  }
  // stage Q once: [64 q][64 dh] fp16
  {
    int qrow = t>>2, doff = (t&3)*16;
    const float* qp = Q + (size_t)b*qB + (size_t)(qt*64+qrow)*512 + h*64 + doff;
    float4 q0 = *reinterpret_cast<const float4*>(qp);
    float4 q1 = *reinterpret_cast<const float4*>(qp+4);
    float4 q2 = *reinterpret_cast<const float4*>(qp+8);
    float4 q3 = *reinterpret_cast<const float4*>(qp+12);
    uint4 w0 = make_uint4(pkh2(q0.x,q0.y),pkh2(q0.z,q0.w),pkh2(q1.x,q1.y),pkh2(q1.z,q1.w));
    uint4 w1 = make_uint4(pkh2(q2.x,q2.y),pkh2(q2.z,q2.w),pkh2(q3.x,q3.y),pkh2(q3.z,q3.w));
    *reinterpret_cast<uint4*>(&Qs[qrow][doff])   = w0;
    *reinterpret_cast<uint4*>(&Qs[qrow][doff+8]) = w1;
  }
  __syncthreads();
  f16x8 aq[2];
  aq[0] = *reinterpret_cast<const f16x8*>(&Qs[w*16+fr][fg*8]);
  aq[1] = *reinterpret_cast<const f16x8*>(&Qs[w*16+fr][32+fg*8]);

  f32x4 so[4];
#pragma unroll
  for (int dt=0;dt<4;dt++){ so[dt][0]=0.f; so[dt][1]=0.f; so[dt][2]=0.f; so[dt][3]=0.f; }
  float m[4] = {-1e30f,-1e30f,-1e30f,-1e30f};
  float lsum[4] = {0.f,0.f,0.f,0.f};

  const int nt = (n0+n1)>>6;
  const int srow = t>>2, sdo = (t&3)*16;    // K staging: key-in-tile, dh offset
  const int vd = t>>2,   vkf = (t&3)*16;    // V staging: d, key offset

  for (int jt=0; jt<nt; jt++){
    // ---- stage K tile [64 key][64 dh] fp16 (fp32 -> fp16)
    {
      int key = jt*64 + srow;
      const float* kp;
      if (key < n0) kp = K0 + (size_t)b*k0B + (size_t)key*k0R + (k0H? h*64:0) + sdo;
      else          kp = K1 + (size_t)b*k1B + (size_t)(key-n0)*k1R + (k1H? h*64:0) + sdo;
      float4 c0 = *reinterpret_cast<const float4*>(kp);
      float4 c1 = *reinterpret_cast<const float4*>(kp+4);
      float4 c2 = *reinterpret_cast<const float4*>(kp+8);
      float4 c3 = *reinterpret_cast<const float4*>(kp+12);
      uint4 w0 = make_uint4(pkh2(c0.x,c0.y),pkh2(c0.z,c0.w),pkh2(c1.x,c1.y),pkh2(c1.z,c1.w));
      uint4 w1 = make_uint4(pkh2(c2.x,c2.y),pkh2(c2.z,c2.w),pkh2(c3.x,c3.y),pkh2(c3.z,c3.w));
      *reinterpret_cast<uint4*>(&Ks[srow][sdo])   = w0;
      *reinterpret_cast<uint4*>(&Ks[srow][sdo+8]) = w1;
    }
    // ---- stage V^T tile [64 d][64 key] fp16 (already fp16 in global)
    {
      const ushort* vp;
      if (jt*64 < n0) vp = VT0 + (size_t)b*vt0B + (size_t)h*vt0H + (size_t)vd*vt0D + jt*64 + vkf;
      else            vp = VT1 + (size_t)b*vt1B + (size_t)h*vt1H + (size_t)vd*vt1D + (jt*64-n0) + vkf;
      uint4 v0 = *reinterpret_cast<const uint4*>(vp);
      uint4 v1 = *reinterpret_cast<const uint4*>(vp+8);
      *reinterpret_cast<uint4*>(&Vs[vd][vkf])   = v0;
      *reinterpret_cast<uint4*>(&Vs[vd][vkf+8]) = v1;
    }
    __syncthreads();
    // ---- S = Q K^T  (4 key sub-tiles of 16)
    f32x4 sacc[4];
#pragma unroll
    for (int kt=0;kt<4;kt++){ sacc[kt][0]=0.f; sacc[kt][1]=0.f; sacc[kt][2]=0.f; sacc[kt][3]=0.f; }
#pragma unroll
    for (int ks=0;ks<2;ks++){
#pragma unroll
      for (int kt=0;kt<4;kt++){
        f16x8 bf = *reinterpret_cast<const f16x8*>(&Ks[kt*16+fr][ks*32+fg*8]);
        sacc[kt] = __builtin_amdgcn_mfma_f32_16x16x32_f16(aq[ks], bf, sacc[kt], 0,0,0);
      }
    }
    // ---- online softmax (rows = fg*4+r, cols = kt*16+fr)
#pragma unroll
    for (int r=0;r<4;r++){
      float sv[4];
      int ia = qt*64 + w*16 + fg*4 + r;
#pragma unroll
      for (int kt=0;kt<4;kt++){
        float s = sacc[kt][r]*scale;
        if (WIN){
          int jg = jt*64 + kt*16 + fr;
          bool valid = (jg > ia) && (jg <= ia+512) && (has_mem || jg >= 512);
          s = valid ? s + tcol[ia+512-jg] : -1e9f;
        }
        sv[kt] = s;
      }
      float tm = fmaxf(fmaxf(sv[0],sv[1]), fmaxf(sv[2],sv[3]));
      tm = fmaxf(tm, __shfl_xor(tm,1));
      tm = fmaxf(tm, __shfl_xor(tm,2));
      tm = fmaxf(tm, __shfl_xor(tm,4));
      tm = fmaxf(tm, __shfl_xor(tm,8));
      float mn = fmaxf(m[r], tm);
      float c = __expf(m[r]-mn);
      m[r] = mn;
      float ps = 0.f;
#pragma unroll
      for (int kt=0;kt<4;kt++){
        float pp = (sv[kt] <= -1e8f) ? 0.f : __expf(sv[kt]-mn);
        ps += pp;
        Pw[w][fg*4+r][kt*16+fr] = f2h(pp);
      }
      ps += __shfl_xor(ps,1);
      ps += __shfl_xor(ps,2);
      ps += __shfl_xor(ps,4);
      ps += __shfl_xor(ps,8);
      lsum[r] = lsum[r]*c + ps;
#pragma unroll
      for (int dt=0;dt<4;dt++) so[dt][r] *= c;
    }
    // ---- O += P V  (A = P from wave-private LDS, B = V^T)
#pragma unroll
    for (int ks=0;ks<2;ks++){
      f16x8 pa = *reinterpret_cast<const f16x8*>(&Pw[w][fr][ks*32+fg*8]);
#pragma unroll
      for (int dt=0;dt<4;dt++){
        f16x8 bv = *reinterpret_cast<const f16x8*>(&Vs[dt*16+fr][ks*32+fg*8]);
        so[dt] = __builtin_amdgcn_mfma_f32_16x16x32_f16(pa, bv, so[dt], 0,0,0);
      }
    }
    __syncthreads();
  }
  // ---- write O (row=(fg*4+r), col=dt*16+fr)
#pragma unroll
  for (int r=0;r<4;r++){
    int row = qt*64 + w*16 + fg*4 + r;
    float inv = 1.f / lsum[r];
    float* op = O + (size_t)b*oB + (size_t)row*512 + h*64;
#pragma unroll
    for (int dt=0;dt<4;dt++)
      op[dt*16+fr] = so[dt][r]*inv;
  }
}

// ---------------- small utility kernels ----------------
__global__ void k_copy(float* __restrict__ dst, const float* __restrict__ src, int n){
  int idx = blockIdx.x*blockDim.x + threadIdx.x;
  if (idx < n) dst[idx] = src[idx];
}
__global__ void k_gather_xb(float* __restrict__ dst, const float* __restrict__ src, int nb){
  int idx = blockIdx.x*blockDim.x + threadIdx.x;
  if (idx >= 1048576) return;
  int b = idx >> 18, rem = idx & 262143;
  dst[idx] = src[(size_t)b*524288 + (size_t)nb*262144 + rem];
}
__global__ void k_xlout(float* __restrict__ dk, float* __restrict__ dv,
                        const float* __restrict__ k, const float* __restrict__ v){
  int idx = blockIdx.x*blockDim.x + threadIdx.x;
  if (idx >= 1048576) return;
  int b = idx >> 18, rem = idx & 262143;
  size_t s = (size_t)b*524288 + 262144 + rem;
  dk[idx] = k[s]; dv[idx] = v[s];
}
__global__ void k_ema(float* __restrict__ st, const float* __restrict__ sp,
                      const float* __restrict__ beta, int n){
  int idx = blockIdx.x*blockDim.x + threadIdx.x;
  if (idx >= n) return;
  int d = idx & 511;
  float dec = 1.f/(1.f+__expf(-beta[d]));
  st[idx] = dec*st[idx] + (1.f-dec)*sp[idx];
}

// ---------------- launcher ----------------
extern "C" void kernel_launch(void* const* d_in, const int* in_sizes, int n_in,
                              void* d_out, int out_size, void* d_ws, size_t ws_size,
                              hipStream_t stream){
  // floats 96,485,376 B + ushorts (38,338,560) 76,677,120 B = 173,162,496 B
  if (ws_size < (size_t)173162496) return;

  const int*   x        = (const int*)  d_in[0];
  const float* tok_emb  = (const float*)d_in[1];
  const float* pw1 = (const float*)d_in[2];
  const float* pb1 = (const float*)d_in[3];
  const float* pw2 = (const float*)d_in[4];
  const float* pb2 = (const float*)d_in[5];
  const float* pw3 = (const float*)d_in[6];
  const float* pb3 = (const float*)d_in[7];
  const float* ln_g = (const float*)d_in[8];
  const float* Wq = (const float*)d_in[9];
  const float* Wk = (const float*)d_in[10];
  const float* Wv = (const float*)d_in[11];
  const float* Wo = (const float*)d_in[12];
  const float* q_scale = (const float*)d_in[13];
  const float* k_scale = (const float*)d_in[14];
  const float* Wo_state = (const float*)d_in[15];
  const float* state_norm_g = (const float*)d_in[16];
  const float* Wq2s = (const float*)d_in[17];
  const float* Ws2q = (const float*)d_in[18];
  const float* Ws2kv = (const float*)d_in[19];
  const float* W_state_out = (const float*)d_in[20];
  const float* ema_beta = (const float*)d_in[21];
  const float* ff_g = (const float*)d_in[22];
  const float* ff_w1 = (const float*)d_in[23];
  const float* ff_b1 = (const float*)d_in[24];
  const float* ff_w2 = (const float*)d_in[25];
  const float* ff_b2 = (const float*)d_in[26];
  const float* final_g = (const float*)d_in[27];
  const float* W_logits = (const float*)d_in[28];
  const float* xl_mem_k = (const float*)d_in[29];
  const float* xl_mem_v = (const float*)d_in[30];
  const float* states_in = (const float*)d_in[31];

  float* out = (float*)d_out;
  float* out_xlk    = out + 81920000;
  float* out_xlv    = out + 84017152;
  float* out_states = out + 86114304;

  float* p = (float*)d_ws;
  float* hstate   = p; p += 2097152;
  float* xn       = p; p += 2097152;
  float* q        = p; p += 2097152;
  float* k        = p; p += 2097152;
  float* v        = p; p += 2097152;
  float* attn_out = p; p += 2097152;
  float* to_state = p; p += 2097152;
  float* ff1      = p; p += 8388608;
  float* states_cur = p; p += 1048576;
  float* table    = p; p += 4096;
  float* sn    = ff1;
  float* skv   = ff1 + 1048576;
  float* xb    = ff1 + 1310720;
  float* q2s   = ff1 + 2359296;
  float* sq    = ff1 + 3407872;
  float* satt  = ff1 + 4456448;
  float* sproj = ff1 + 5505024;

  ushort* us = (ushort*)p;
  ushort* wqh   = us; us += 1572864;
  ushort* wql   = us; us += 1572864;
  ushort* wkh   = us; us += 1572864;
  ushort* wkl   = us; us += 1572864;
  ushort* wvT   = us; us += 1572864;
  ushort* woT   = us; us += 1572864;
  ushort* ffw1T = us; us += 6291456;
  ushort* ffw2T = us; us += 6291456;
  ushort* wostT = us; us += 262144;
  ushort* wstoutT = us; us += 262144;
  ushort* wq2sh = us; us += 262144;
  ushort* wq2sl = us; us += 262144;
  ushort* ws2qh = us; us += 262144;
  ushort* ws2ql = us; us += 262144;
  ushort* ws2kvh = us; us += 65536;
  ushort* ws2kvl = us; us += 65536;
  ushort* wlogT  = us; us += 10289152;
  ushort* vTb   = us; us += 2097152;   // [b][h][64][1024] fp16 of v (per layer)
  ushort* xlvT  = us; us += 2097152;   // [2][b][h][64][512]
  ushort* svT   = us; us += 131072;    // [b][64][512]

  // ---- weight prep ----
  k_prep<1><<<dim3(16,16,6),256,0,stream>>>(Wq, wqh, wql, 512,512,512);
  k_prep<1><<<dim3(16,16,6),256,0,stream>>>(Wk, wkh, wkl, 512,512,512);
  k_prep<0><<<dim3(16,16,6),256,0,stream>>>(Wv, wvT, nullptr, 512,512,512);
  k_prep<0><<<dim3(16,16,6),256,0,stream>>>(Wo, woT, nullptr, 512,512,512);
  k_prep<0><<<dim3(64,16,6),256,0,stream>>>(ff_w1, ffw1T, nullptr, 512,2048,2048);
  k_prep<0><<<dim3(16,64,6),256,0,stream>>>(ff_w2, ffw2T, nullptr, 2048,512,512);
  k_prep<0><<<dim3(16,16,1),256,0,stream>>>(Wo_state, wostT, nullptr, 512,512,512);
  k_prep<0><<<dim3(16,16,1),256,0,stream>>>(W_state_out, wstoutT, nullptr, 512,512,512);
  k_prep<1><<<dim3(16,16,1),256,0,stream>>>(Wq2s, wq2sh, wq2sl, 512,512,512);
  k_prep<1><<<dim3(16,16,1),256,0,stream>>>(Ws2q, ws2qh, ws2ql, 512,512,512);
  k_prep<1><<<dim3(4,16,1),256,0,stream>>>(Ws2kv, ws2kvh, ws2kvl, 512,128,128);
  k_prep<0><<<dim3(628,16,1),256,0,stream>>>(W_logits, wlogT, nullptr, 512,20000,20096);

  // xl memory V transposes (both slots)
  for (int s=0;s<2;s++)
    k_vtrans<<<dim3(8,8,4),256,0,stream>>>(xl_mem_v + (size_t)s*1048576,
                                           xlvT + (size_t)s*1048576,
                                           262144L, 512, 1, 262144L, 32768L, 512);

  k_embed<<<2048, 256, 0, stream>>>(x, tok_emb, hstate, 524288);
  k_postable<<<512, 128, 0, stream>>>(pw1,pb1,pw2,pb2,pw3,pb3, table);
  k_copy<<<4096, 256, 0, stream>>>(states_cur, states_in, 1048576);

  for (int l=0;l<6;l++){
    k_ln<<<4096,256,0,stream>>>(hstate, ln_g + l*512, xn);
    k_gemm_mfma<0,0,1><<<dim3(32,4),256,0,stream>>>(xn, wqh + (size_t)l*262144, wql + (size_t)l*262144, nullptr, q, 4096,512,512);
    k_gemm_mfma<0,0,1><<<dim3(32,4),256,0,stream>>>(xn, wkh + (size_t)l*262144, wkl + (size_t)l*262144, nullptr, k, 4096,512,512);
    k_gemm_mfma<0,0,0><<<dim3(32,4),256,0,stream>>>(xn, wvT + (size_t)l*262144, nullptr, nullptr, v, 4096,512,512);
    float scale = 0.125f;
    if (l>=3){
      k_qkrms<<<4096,512,0,stream>>>(q, k, q_scale + l*64, k_scale + l*64);
      scale = 8.f;
    }
    // v^T for this layer: [b][h][64][1024]
    k_vtrans<<<dim3(16,8,4),256,0,stream>>>(v, vTb, 524288L, 512, 1, 524288L, 65536L, 1024);

    bool isxl = (l==4 || l==5);
    int src = (l==4)? 1 : 0;     // roll(-1)
    for (int nb=0;nb<2;nb++){
      const float* K0; const ushort* VT0;
      long k0B, vt0B, vt0H; int k0R, k0H, vt0D, has_mem;
      if (nb==0 && isxl){
        K0 = xl_mem_k + (size_t)src*1048576; k0B=262144; k0R=512; k0H=1;
        VT0 = xlvT + (size_t)src*1048576; vt0B=262144; vt0H=32768; vt0D=512;
        has_mem = 1;
      } else if (nb==0){
        K0 = k; k0B=524288; k0R=512; k0H=1;           // dummy (masked)
        VT0 = vTb; vt0B=524288; vt0H=65536; vt0D=1024;
        has_mem = 0;
      } else {
        K0 = k; k0B=524288; k0R=512; k0H=1;           // prev block = block 0
        VT0 = vTb; vt0B=524288; vt0H=65536; vt0D=1024;
        has_mem = 1;
      }
      k_attn_mfma<1><<<dim3(8,8,4),256,0,stream>>>(
        q + nb*262144, 524288L,
        K0, k0B, k0R, k0H,
        k + nb*262144, 524288L, 512, 1,
        VT0, vt0B, vt0H, vt0D,
        vTb + nb*512, 524288L, 65536L, 1024,
        512, 512,
        attn_out + nb*262144, 524288L,
        scale, has_mem, table);
    }
    k_gemm_mfma<1,0,0><<<dim3(32,4),256,0,stream>>>(attn_out, woT + (size_t)l*262144, nullptr, nullptr, hstate, 4096,512,512);
    if (l==3){
      for (int nb=0;nb<2;nb++){
        k_ln<<<2048,256,0,stream>>>(states_cur, state_norm_g, sn);
        k_gemm_mfma<0,0,1><<<dim3(16,1),256,0,stream>>>(sn, ws2kvh, ws2kvl, nullptr, skv, 2048,128,512);
        k_vtrans<<<dim3(8,1,4),256,0,stream>>>(skv + 64, svT, 65536L, 128, 0, 32768L, 0L, 512);
        k_gather_xb<<<4096,256,0,stream>>>(xb, xn, nb);
        k_gemm_mfma<0,0,1><<<dim3(16,4),256,0,stream>>>(xb, wq2sh, wq2sl, nullptr, q2s, 2048,512,512);
        // block tokens -> states (512 keys, single-head kv)
        k_attn_mfma<0><<<dim3(8,8,4),256,0,stream>>>(
          q2s, 262144L,
          skv, 65536L, 128, 0,
          skv, 65536L, 128, 0,
          svT, 32768L, 0L, 512,
          svT, 32768L, 0L, 512,
          512, 0,
          to_state + nb*262144, 524288L,
          0.125f, 0, table);
        k_gemm_mfma<0,0,1><<<dim3(16,4),256,0,stream>>>(sn, ws2qh, ws2ql, nullptr, sq, 2048,512,512);
        // states -> [states | block tokens]
        k_attn_mfma<0><<<dim3(8,8,4),256,0,stream>>>(
          sq, 262144L,
          skv, 65536L, 128, 0,
          k + nb*262144, 524288L, 512, 1,
          svT, 32768L, 0L, 512,
          vTb + nb*512, 524288L, 65536L, 1024,
          512, 512,
          satt, 262144L,
          0.125f, 0, table);
        k_gemm_mfma<0,0,0><<<dim3(16,4),256,0,stream>>>(satt, wstoutT, nullptr, nullptr, sproj, 2048,512,512);
        k_ema<<<4096,256,0,stream>>>(states_cur, sproj, ema_beta, 1048576);
      }
      k_gemm_mfma<1,0,0><<<dim3(32,4),256,0,stream>>>(to_state, wostT, nullptr, nullptr, hstate, 4096,512,512);
    }
    if (isxl){
      int xli = l-4;
      k_xlout<<<4096,256,0,stream>>>(out_xlk + (size_t)xli*1048576,
                                     out_xlv + (size_t)xli*1048576, k, v);
    }
    k_ln<<<4096,256,0,stream>>>(hstate, ff_g + l*512, xn);
    k_gemm_mfma<0,1,0><<<dim3(32,16),256,0,stream>>>(xn, ffw1T + (size_t)l*1048576, nullptr, ff_b1 + l*2048, ff1, 4096,2048,512);
    k_gemm_mfma<1,0,0><<<dim3(32,4),256,0,stream>>>(ff1, ffw2T + (size_t)l*1048576, nullptr, ff_b2 + l*512, hstate, 4096,512,2048);
  }
  k_ln<<<4096,256,0,stream>>>(hstate, final_g, xn);
  k_gemm_mfma<0,0,0><<<dim3(32,157),256,0,stream>>>(xn, wlogT, nullptr, nullptr, out, 4096,20000,512);
  k_copy<<<4096, 256, 0, stream>>>(out_states, states_cur, 1048576);
}

// Round 8
// 2432.046 us; speedup vs baseline: 5.1777x; 1.2208x over previous
//
#include <hip/hip_runtime.h>
#include <math.h>

// B=4 N=1024 V=20000 D=512 H=8 DH=64 W=512 NB=2 NS=512 FF=2048

typedef __attribute__((ext_vector_type(8))) __bf16 bf16x8;
typedef __attribute__((ext_vector_type(8))) _Float16 f16x8;
typedef __attribute__((ext_vector_type(4))) float f32x4;

__device__ __forceinline__ ushort f2b(float f){
  uint u = __float_as_uint(f);
  uint r = (u + 0x7FFFu + ((u >> 16) & 1u)) >> 16;
  return (ushort)r;
}
__device__ __forceinline__ ushort f2h(float f){
  _Float16 h = (_Float16)f;
  return *reinterpret_cast<ushort*>(&h);
}
__device__ __forceinline__ uint pkh2(float a, float b){
  return (uint)f2h(a) | ((uint)f2h(b)<<16);
}
__device__ __forceinline__ void split8(const float* f, uint4& hi, uint4& lo){
  ushort h[8], l[8];
#pragma unroll
  for (int i=0;i<8;i++){
    h[i] = f2b(f[i]);
    float fh = __uint_as_float((uint)h[i] << 16);
    l[i] = f2b(f[i] - fh);
  }
  hi = make_uint4((uint)h[0]|((uint)h[1]<<16), (uint)h[2]|((uint)h[3]<<16),
                  (uint)h[4]|((uint)h[5]<<16), (uint)h[6]|((uint)h[7]<<16));
  lo = make_uint4((uint)l[0]|((uint)l[1]<<16), (uint)l[2]|((uint)l[3]<<16),
                  (uint)l[4]|((uint)l[5]<<16), (uint)l[6]|((uint)l[7]<<16));
}

// ---------------- weight prep: [K][N] fp32 -> [Npad][K] fp16 / bf16 hi+lo ----
template<int MODE>
__global__ __launch_bounds__(256)
void k_prep(const float* __restrict__ src, ushort* __restrict__ dh,
            ushort* __restrict__ dl, int K, int N, int Npad, long zStride){
  __shared__ float tile[32][33];
  int z = blockIdx.z;
  src += (size_t)z*K*N;
  dh  += (size_t)z*zStride;
  if (MODE) dl += (size_t)z*zStride;
  int n0 = blockIdx.x*32, k0 = blockIdx.y*32;
  int tx = threadIdx.x&31, ty = threadIdx.x>>5;
#pragma unroll
  for (int i=0;i<4;i++){
    int kk = k0 + ty + i*8, nn = n0 + tx;
    tile[ty+i*8][tx] = (nn < N) ? src[(size_t)kk*N + nn] : 0.f;
  }
  __syncthreads();
#pragma unroll
  for (int i=0;i<4;i++){
    int nn = n0 + ty + i*8, kk = k0 + tx;
    float v = tile[tx][ty+i*8];
    if (MODE==0){
      dh[(size_t)nn*K + kk] = f2h(v);
    } else {
      ushort h = f2b(v);
      dh[(size_t)nn*K + kk] = h;
      float fh = __uint_as_float((uint)h<<16);
      dl[(size_t)nn*K + kk] = f2b(v - fh);
    }
  }
}

// ---------------- V transpose: fp32 [b][key][cols] -> fp16 [b][h][64][NK] ----
__global__ __launch_bounds__(256)
void k_vtrans(const float* __restrict__ src, ushort* __restrict__ dst,
              long sB, int sR, int sMH, long dB, long dH, int NK){
  __shared__ float tile[64][65];
  int kc = blockIdx.x, h = blockIdx.y, b = blockIdx.z;
  int t = threadIdx.x;
  int key = t>>2, doff = (t&3)*16;
  const float* sp = src + (size_t)b*sB + (size_t)(kc*64+key)*sR + (sMH? h*64:0) + doff;
#pragma unroll
  for (int u=0;u<4;u++){
    float4 v = *reinterpret_cast<const float4*>(sp + u*4);
    tile[key][doff+u*4+0]=v.x; tile[key][doff+u*4+1]=v.y;
    tile[key][doff+u*4+2]=v.z; tile[key][doff+u*4+3]=v.w;
  }
  __syncthreads();
  int d = t>>2, kf = (t&3)*16;
  ushort* dp = dst + (size_t)b*dB + (size_t)h*dH + (size_t)d*NK + kc*64 + kf;
  ushort tmp[16];
#pragma unroll
  for (int u=0;u<16;u++) tmp[u] = f2h(tile[kf+u][d]);
  uint4 o0 = make_uint4((uint)tmp[0]|((uint)tmp[1]<<16), (uint)tmp[2]|((uint)tmp[3]<<16),
                        (uint)tmp[4]|((uint)tmp[5]<<16), (uint)tmp[6]|((uint)tmp[7]<<16));
  uint4 o1 = make_uint4((uint)tmp[8]|((uint)tmp[9]<<16), (uint)tmp[10]|((uint)tmp[11]<<16),
                        (uint)tmp[12]|((uint)tmp[13]<<16),(uint)tmp[14]|((uint)tmp[15]<<16));
  *reinterpret_cast<uint4*>(dp)   = o0;
  *reinterpret_cast<uint4*>(dp+8) = o1;
}

// ---------------- embed / postable ----------------
__global__ void k_embed(const int* __restrict__ x, const float* __restrict__ emb,
                        float* __restrict__ h, int total4){
  int idx = blockIdx.x*blockDim.x + threadIdx.x;
  if (idx >= total4) return;
  int row = idx >> 7;
  int c4  = idx & 127;
  int tok = x[row];
  reinterpret_cast<float4*>(h)[idx] =
      reinterpret_cast<const float4*>(emb)[(size_t)tok*128 + c4];
}

__global__ void k_postable(const float* __restrict__ w1, const float* __restrict__ b1,
                           const float* __restrict__ w2, const float* __restrict__ b2,
                           const float* __restrict__ w3, const float* __restrict__ b3,
                           float* __restrict__ table){
  __shared__ float h1[128];
  __shared__ float h2[128];
  int d = blockIdx.x, t = threadIdx.x;
  float a = (float)d * w1[t] + b1[t];
  h1[t] = a / (1.f + __expf(-a));
  __syncthreads();
  float acc = b2[t];
  for (int p=0;p<128;p++) acc += h1[p]*w2[p*128+t];
  h2[t] = acc / (1.f + __expf(-acc));
  __syncthreads();
  if (t < 8){
    float acc2 = b3[t];
    for (int p=0;p<128;p++) acc2 += h2[p]*w3[p*8+t];
    table[d*8+t] = acc2;
  }
}

// ---------------- layernorm: fp32 out + optional fp16 out ----------------
__global__ void k_ln(const float* __restrict__ x, const float* __restrict__ g,
                     float* __restrict__ y, ushort* __restrict__ y16){
  int row = blockIdx.x;
  int t = threadIdx.x;
  float2 v = reinterpret_cast<const float2*>(x + (size_t)row*512)[t];
  float s = v.x+v.y, ss = v.x*v.x+v.y*v.y;
  for (int o=32;o;o>>=1){ s += __shfl_down(s,o); ss += __shfl_down(ss,o); }
  __shared__ float ls[4], lss[4];
  __shared__ float smu, srs;
  int wid = t>>6;
  if ((t&63)==0){ ls[wid]=s; lss[wid]=ss; }
  __syncthreads();
  if (t==0){
    float S=ls[0]+ls[1]+ls[2]+ls[3], SS=lss[0]+lss[1]+lss[2]+lss[3];
    float mu = S*(1.f/512.f);
    float var = SS*(1.f/512.f) - mu*mu;
    smu = mu; srs = rsqrtf(var + 1e-5f);
  }
  __syncthreads();
  float mu=smu, rs=srs;
  float2 gg = reinterpret_cast<const float2*>(g)[t];
  float ya = (v.x-mu)*rs*gg.x, yb = (v.y-mu)*rs*gg.y;
  reinterpret_cast<float2*>(y + (size_t)row*512)[t] = make_float2(ya, yb);
  if (y16)
    *reinterpret_cast<uint*>(&y16[(size_t)row*512 + 2*t]) = pkh2(ya, yb);
}

__global__ void k_qkrms(float* __restrict__ q, float* __restrict__ k,
                        const float* __restrict__ qs, const float* __restrict__ ks){
  int row = blockIdx.x;
  int h = threadIdx.x >> 6, d = threadIdx.x & 63;
  size_t base = (size_t)row*512 + h*64 + d;
  float qv = q[base];
  float s = qv*qv;
  for (int o=32;o;o>>=1) s += __shfl_xor(s,o);
  q[base] = qv*rsqrtf(s+1e-12f)*qs[d];
  float kv = k[base];
  float s2 = kv*kv;
  for (int o=32;o;o>>=1) s2 += __shfl_xor(s2,o);
  k[base] = kv*rsqrtf(s2+1e-12f)*ks[d];
}

__device__ __forceinline__ float geluf(float x){
  float u = 1.5957691216f*(x + 0.044715f*x*x*x);   // 2*sqrt(2/pi)*(...)
  return x / (1.f + __expf(-u));                   // == 0.5x(1+tanh(u/2))
}

// ---------------- fp16 MFMA GEMM: C[M,N] (+)= A@Bt^T ----------------
// A [M][K] fp16; Bt [Npad][K] fp16. 128x128 tile, BK=64, 4 waves 2x2.
// OUT16: write fp16 C16 instead of fp32 C. Requires M%128==0, K%64==0.
template<int ACC, int EPI, int OUT16>
__global__ __launch_bounds__(256)
void k_gemmh(const ushort* __restrict__ A, const ushort* __restrict__ Bt,
             const float* __restrict__ bias, float* __restrict__ C,
             ushort* __restrict__ C16, int M, int N, int K){
  __shared__ ushort As[128][68];
  __shared__ ushort Bs[128][68];
  const int t = threadIdx.x;
  const int m0 = blockIdx.x*128, n0 = blockIdx.y*128;
  const int w = t>>6, lane = t&63;
  const int wm = (w>>1)*64, wn = (w&1)*64;
  const int fr = lane&15, fg = lane>>4;
  const int srow = t>>1, sko = (t&1)*32;

  f32x4 acc[4][4];
#pragma unroll
  for (int i=0;i<4;i++)
#pragma unroll
    for (int j=0;j<4;j++){ acc[i][j][0]=0.f; acc[i][j][1]=0.f; acc[i][j][2]=0.f; acc[i][j][3]=0.f; }

  const ushort* ap = A  + (size_t)(m0+srow)*K + sko;
  const ushort* bp = Bt + (size_t)(n0+srow)*K + sko;

  for (int k0=0; k0<K; k0+=64){
    uint4 av[4], bv[4];
#pragma unroll
    for (int u=0;u<4;u++){
      av[u] = *reinterpret_cast<const uint4*>(ap + k0 + u*8);
      bv[u] = *reinterpret_cast<const uint4*>(bp + k0 + u*8);
    }
#pragma unroll
    for (int u=0;u<4;u++){
      *reinterpret_cast<uint4*>(&As[srow][sko+u*8]) = av[u];
      *reinterpret_cast<uint4*>(&Bs[srow][sko+u*8]) = bv[u];
    }
    __syncthreads();
#pragma unroll
    for (int kk=0;kk<2;kk++){
      f16x8 af[4], bf[4];
#pragma unroll
      for (int mi=0;mi<4;mi++)
        af[mi] = *reinterpret_cast<const f16x8*>(&As[wm+mi*16+fr][kk*32+fg*8]);
#pragma unroll
      for (int nj=0;nj<4;nj++)
        bf[nj] = *reinterpret_cast<const f16x8*>(&Bs[wn+nj*16+fr][kk*32+fg*8]);
#pragma unroll
      for (int mi=0;mi<4;mi++)
#pragma unroll
        for (int nj=0;nj<4;nj++)
          acc[mi][nj] = __builtin_amdgcn_mfma_f32_16x16x32_f16(af[mi], bf[nj], acc[mi][nj], 0,0,0);
    }
    __syncthreads();
  }
#pragma unroll
  for (int mi=0;mi<4;mi++){
#pragma unroll
    for (int r=0;r<4;r++){
      int row = m0 + wm + mi*16 + fg*4 + r;
#pragma unroll
      for (int nj=0;nj<4;nj++){
        int col = n0 + wn + nj*16 + fr;
        if (col < N){
          float val = acc[mi][nj][r];
          if (bias) val += bias[col];
          if (EPI==1) val = geluf(val);
          if (OUT16){
            C16[(size_t)row*N + col] = f2h(val);
          } else {
            if (ACC) C[(size_t)row*N + col] += val; else C[(size_t)row*N + col] = val;
          }
        }
      }
    }
  }
}

// ---------------- split-bf16 (hi/lo) MFMA GEMM for q/k-path ----------------
// A fp32 [M][K]; Bh/Bl [Npad][K] bf16. BK=32. Split epilogue: col<N1 -> C1,
// else C2[col-N1]. Effective-fp32 inputs via 3-product Dekker.
__global__ __launch_bounds__(256)
void k_gemm_sp(const float* __restrict__ A, const ushort* __restrict__ Bh,
               const ushort* __restrict__ Bl,
               float* __restrict__ C1, int ld1, int N1,
               float* __restrict__ C2, int ld2,
               int M, int N, int K){
  __shared__ ushort As[2][128][36];
  __shared__ ushort Bs[2][128][36];
  const int t = threadIdx.x;
  const int m0 = blockIdx.x*128, n0 = blockIdx.y*128;
  const int w = t>>6, lane = t&63;
  const int wm = (w>>1)*64, wn = (w&1)*64;
  const int fr = lane&15, fg = lane>>4;
  const int srow = t>>1, sko = (t&1)*16;

  f32x4 acc[4][4];
#pragma unroll
  for (int i=0;i<4;i++)
#pragma unroll
    for (int j=0;j<4;j++){ acc[i][j][0]=0.f; acc[i][j][1]=0.f; acc[i][j][2]=0.f; acc[i][j][3]=0.f; }

  const float*  ap  = A  + (size_t)(m0+srow)*K + sko;
  const ushort* bph = Bh + (size_t)(n0+srow)*K + sko;
  const ushort* bpl = Bl + (size_t)(n0+srow)*K + sko;

  for (int k0=0; k0<K; k0+=32){
    uint4 b0 = *reinterpret_cast<const uint4*>(bph + k0);
    uint4 b1 = *reinterpret_cast<const uint4*>(bph + k0 + 8);
    uint4 bl0 = *reinterpret_cast<const uint4*>(bpl + k0);
    uint4 bl1 = *reinterpret_cast<const uint4*>(bpl + k0 + 8);
    float4 a0 = *reinterpret_cast<const float4*>(ap + k0);
    float4 a1 = *reinterpret_cast<const float4*>(ap + k0 + 4);
    float4 a2 = *reinterpret_cast<const float4*>(ap + k0 + 8);
    float4 a3 = *reinterpret_cast<const float4*>(ap + k0 + 12);
    float fa[16] = {a0.x,a0.y,a0.z,a0.w, a1.x,a1.y,a1.z,a1.w,
                    a2.x,a2.y,a2.z,a2.w, a3.x,a3.y,a3.z,a3.w};
    uint4 hi, lo;
    split8(fa,   hi, lo);
    *reinterpret_cast<uint4*>(&As[0][srow][sko])   = hi;
    *reinterpret_cast<uint4*>(&As[1][srow][sko])   = lo;
    split8(fa+8, hi, lo);
    *reinterpret_cast<uint4*>(&As[0][srow][sko+8]) = hi;
    *reinterpret_cast<uint4*>(&As[1][srow][sko+8]) = lo;
    *reinterpret_cast<uint4*>(&Bs[0][srow][sko])   = b0;
    *reinterpret_cast<uint4*>(&Bs[0][srow][sko+8]) = b1;
    *reinterpret_cast<uint4*>(&Bs[1][srow][sko])   = bl0;
    *reinterpret_cast<uint4*>(&Bs[1][srow][sko+8]) = bl1;
    __syncthreads();

    bf16x8 ah[4], al[4], bh[4], bl[4];
#pragma unroll
    for (int mi=0;mi<4;mi++){
      ah[mi] = *reinterpret_cast<const bf16x8*>(&As[0][wm+mi*16+fr][fg*8]);
      al[mi] = *reinterpret_cast<const bf16x8*>(&As[1][wm+mi*16+fr][fg*8]);
    }
#pragma unroll
    for (int nj=0;nj<4;nj++){
      bh[nj] = *reinterpret_cast<const bf16x8*>(&Bs[0][wn+nj*16+fr][fg*8]);
      bl[nj] = *reinterpret_cast<const bf16x8*>(&Bs[1][wn+nj*16+fr][fg*8]);
    }
#pragma unroll
    for (int mi=0;mi<4;mi++)
#pragma unroll
      for (int nj=0;nj<4;nj++){
        acc[mi][nj] = __builtin_amdgcn_mfma_f32_16x16x32_bf16(ah[mi], bh[nj], acc[mi][nj], 0,0,0);
        acc[mi][nj] = __builtin_amdgcn_mfma_f32_16x16x32_bf16(al[mi], bh[nj], acc[mi][nj], 0,0,0);
        acc[mi][nj] = __builtin_amdgcn_mfma_f32_16x16x32_bf16(ah[mi], bl[nj], acc[mi][nj], 0,0,0);
      }
    __syncthreads();
  }
#pragma unroll
  for (int mi=0;mi<4;mi++){
#pragma unroll
    for (int r=0;r<4;r++){
      int row = m0 + wm + mi*16 + fg*4 + r;
#pragma unroll
      for (int nj=0;nj<4;nj++){
        int col = n0 + wn + nj*16 + fr;
        if (col < N1)      C1[(size_t)row*ld1 + col] = acc[mi][nj][r];
        else if (col < N)  C2[(size_t)row*ld2 + (col-N1)] = acc[mi][nj][r];
      }
    }
  }
}

// ---------------- MFMA flash attention (fp16 output) ----------------
template<int WIN>
__global__ __launch_bounds__(256)
void k_attn_mfma(const float* __restrict__ Q, long qB,
                 const float* __restrict__ K0, long k0B, int k0R, int k0H,
                 const float* __restrict__ K1, long k1B, int k1R, int k1H,
                 const ushort* __restrict__ VT0, long vt0B, long vt0H, int vt0D,
                 const ushort* __restrict__ VT1, long vt1B, long vt1H, int vt1D,
                 int n0, int n1,
                 ushort* __restrict__ O, long oB,
                 float scale, int has_mem, const float* __restrict__ table){
  __shared__ ushort Qs[64][72];
  __shared__ ushort Ks[64][72];
  __shared__ ushort Vs[64][72];
  __shared__ ushort Pw[4][16][72];
  __shared__ float tcol[512];
  const int b = blockIdx.z, h = blockIdx.y, qt = blockIdx.x;
  const int t = threadIdx.x, w = t>>6, lane = t&63;
  const int fr = lane&15, fg = lane>>4;
  if (WIN){
    tcol[t]     = table[t*8 + h];
    tcol[t+256] = table[(t+256)*8 + h];
  }
  {
    int qrow = t>>2, doff = (t&3)*16;
    const float* qp = Q + (size_t)b*qB + (size_t)(qt*64+qrow)*512 + h*64 + doff;
    float4 q0 = *reinterpret_cast<const float4*>(qp);
    float4 q1 = *reinterpret_cast<const float4*>(qp+4);
    float4 q2 = *reinterpret_cast<const float4*>(qp+8);
    float4 q3 = *reinterpret_cast<const float4*>(qp+12);
    uint4 w0 = make_uint4(pkh2(q0.x,q0.y),pkh2(q0.z,q0.w),pkh2(q1.x,q1.y),pkh2(q1.z,q1.w));
    uint4 w1 = make_uint4(pkh2(q2.x,q2.y),pkh2(q2.z,q2.w),pkh2(q3.x,q3.y),pkh2(q3.z,q3.w));
    *reinterpret_cast<uint4*>(&Qs[qrow][doff])   = w0;
    *reinterpret_cast<uint4*>(&Qs[qrow][doff+8]) = w1;
  }
  __syncthreads();
  f16x8 aq[2];
  aq[0] = *reinterpret_cast<const f16x8*>(&Qs[w*16+fr][fg*8]);
  aq[1] = *reinterpret_cast<const f16x8*>(&Qs[w*16+fr][32+fg*8]);

  f32x4 so[4];
#pragma unroll
  for (int dt=0;dt<4;dt++){ so[dt][0]=0.f; so[dt][1]=0.f; so[dt][2]=0.f; so[dt][3]=0.f; }
  float m[4] = {-1e30f,-1e30f,-1e30f,-1e30f};
  float lsum[4] = {0.f,0.f,0.f,0.f};

  const int nt = (n0+n1)>>6;
  const int srow = t>>2, sdo = (t&3)*16;
  const int vd = t>>2,   vkf = (t&3)*16;

  for (int jt=0; jt<nt; jt++){
    {
      int key = jt*64 + srow;
      const float* kp;
      if (key < n0) kp = K0 + (size_t)b*k0B + (size_t)key*k0R + (k0H? h*64:0) + sdo;
      else          kp = K1 + (size_t)b*k1B + (size_t)(key-n0)*k1R + (k1H? h*64:0) + sdo;
      float4 c0 = *reinterpret_cast<const float4*>(kp);
      float4 c1 = *reinterpret_cast<const float4*>(kp+4);
      float4 c2 = *reinterpret_cast<const float4*>(kp+8);
      float4 c3 = *reinterpret_cast<const float4*>(kp+12);
      uint4 w0 = make_uint4(pkh2(c0.x,c0.y),pkh2(c0.z,c0.w),pkh2(c1.x,c1.y),pkh2(c1.z,c1.w));
      uint4 w1 = make_uint4(pkh2(c2.x,c2.y),pkh2(c2.z,c2.w),pkh2(c3.x,c3.y),pkh2(c3.z,c3.w));
      *reinterpret_cast<uint4*>(&Ks[srow][sdo])   = w0;
      *reinterpret_cast<uint4*>(&Ks[srow][sdo+8]) = w1;
    }
    {
      const ushort* vp;
      if (jt*64 < n0) vp = VT0 + (size_t)b*vt0B + (size_t)h*vt0H + (size_t)vd*vt0D + jt*64 + vkf;
      else            vp = VT1 + (size_t)b*vt1B + (size_t)h*vt1H + (size_t)vd*vt1D + (jt*64-n0) + vkf;
      uint4 v0 = *reinterpret_cast<const uint4*>(vp);
      uint4 v1 = *reinterpret_cast<const uint4*>(vp+8);
      *reinterpret_cast<uint4*>(&Vs[vd][vkf])   = v0;
      *reinterpret_cast<uint4*>(&Vs[vd][vkf+8]) = v1;
    }
    __syncthreads();
    f32x4 sacc[4];
#pragma unroll
    for (int kt=0;kt<4;kt++){ sacc[kt][0]=0.f; sacc[kt][1]=0.f; sacc[kt][2]=0.f; sacc[kt][3]=0.f; }
#pragma unroll
    for (int ks=0;ks<2;ks++){
#pragma unroll
      for (int kt=0;kt<4;kt++){
        f16x8 bf = *reinterpret_cast<const f16x8*>(&Ks[kt*16+fr][ks*32+fg*8]);
        sacc[kt] = __builtin_amdgcn_mfma_f32_16x16x32_f16(aq[ks], bf, sacc[kt], 0,0,0);
      }
    }
#pragma unroll
    for (int r=0;r<4;r++){
      float sv[4];
      int ia = qt*64 + w*16 + fg*4 + r;
#pragma unroll
      for (int kt=0;kt<4;kt++){
        float s = sacc[kt][r]*scale;
        if (WIN){
          int jg = jt*64 + kt*16 + fr;
          bool valid = (jg > ia) && (jg <= ia+512) && (has_mem || jg >= 512);
          s = valid ? s + tcol[ia+512-jg] : -1e9f;
        }
        sv[kt] = s;
      }
      float tm = fmaxf(fmaxf(sv[0],sv[1]), fmaxf(sv[2],sv[3]));
      tm = fmaxf(tm, __shfl_xor(tm,1));
      tm = fmaxf(tm, __shfl_xor(tm,2));
      tm = fmaxf(tm, __shfl_xor(tm,4));
      tm = fmaxf(tm, __shfl_xor(tm,8));
      float mn = fmaxf(m[r], tm);
      float c = __expf(m[r]-mn);
      m[r] = mn;
      float ps = 0.f;
#pragma unroll
      for (int kt=0;kt<4;kt++){
        float pp = (sv[kt] <= -1e8f) ? 0.f : __expf(sv[kt]-mn);
        ps += pp;
        Pw[w][fg*4+r][kt*16+fr] = f2h(pp);
      }
      ps += __shfl_xor(ps,1);
      ps += __shfl_xor(ps,2);
      ps += __shfl_xor(ps,4);
      ps += __shfl_xor(ps,8);
      lsum[r] = lsum[r]*c + ps;
#pragma unroll
      for (int dt=0;dt<4;dt++) so[dt][r] *= c;
    }
#pragma unroll
    for (int ks=0;ks<2;ks++){
      f16x8 pa = *reinterpret_cast<const f16x8*>(&Pw[w][fr][ks*32+fg*8]);
#pragma unroll
      for (int dt=0;dt<4;dt++){
        f16x8 bv = *reinterpret_cast<const f16x8*>(&Vs[dt*16+fr][ks*32+fg*8]);
        so[dt] = __builtin_amdgcn_mfma_f32_16x16x32_f16(pa, bv, so[dt], 0,0,0);
      }
    }
    __syncthreads();
  }
#pragma unroll
  for (int r=0;r<4;r++){
    int row = qt*64 + w*16 + fg*4 + r;
    float inv = 1.f / lsum[r];
    ushort* op = O + (size_t)b*oB + (size_t)row*512 + h*64;
#pragma unroll
    for (int dt=0;dt<4;dt++)
      op[dt*16+fr] = f2h(so[dt][r]*inv);
  }
}

// ---------------- small utility kernels ----------------
__global__ void k_copy(float* __restrict__ dst, const float* __restrict__ src, int n){
  int idx = blockIdx.x*blockDim.x + threadIdx.x;
  if (idx < n) dst[idx] = src[idx];
}
__global__ void k_gather_xb(float* __restrict__ dst, const float* __restrict__ src, int nb){
  int idx = blockIdx.x*blockDim.x + threadIdx.x;
  if (idx >= 1048576) return;
  int b = idx >> 18, rem = idx & 262143;
  dst[idx] = src[(size_t)b*524288 + (size_t)nb*262144 + rem];
}
__global__ void k_xlout(float* __restrict__ dk, float* __restrict__ dv,
                        const float* __restrict__ k, const float* __restrict__ v){
  int idx = blockIdx.x*blockDim.x + threadIdx.x;
  if (idx >= 1048576) return;
  int b = idx >> 18, rem = idx & 262143;
  size_t s = (size_t)b*524288 + 262144 + rem;
  dk[idx] = k[s]; dv[idx] = v[s];
}
__global__ void k_ema(float* __restrict__ st, const float* __restrict__ sp,
                      const float* __restrict__ beta, int n){
  int idx = blockIdx.x*blockDim.x + threadIdx.x;
  if (idx >= n) return;
  int d = idx & 511;
  float dec = 1.f/(1.f+__expf(-beta[d]));
  st[idx] = dec*st[idx] + (1.f-dec)*sp[idx];
}

// ---------------- launcher ----------------
extern "C" void kernel_launch(void* const* d_in, const int* in_sizes, int n_in,
                              void* d_out, int out_size, void* d_ws, size_t ws_size,
                              hipStream_t stream){
  // floats 68,173,824 B + ushorts 101,842,944 B = 170,016,768 B
  if (ws_size < (size_t)170016768) return;

  const int*   x        = (const int*)  d_in[0];
  const float* tok_emb  = (const float*)d_in[1];
  const float* pw1 = (const float*)d_in[2];
  const float* pb1 = (const float*)d_in[3];
  const float* pw2 = (const float*)d_in[4];
  const float* pb2 = (const float*)d_in[5];
  const float* pw3 = (const float*)d_in[6];
  const float* pb3 = (const float*)d_in[7];
  const float* ln_g = (const float*)d_in[8];
  const float* Wq = (const float*)d_in[9];
  const float* Wk = (const float*)d_in[10];
  const float* Wv = (const float*)d_in[11];
  const float* Wo = (const float*)d_in[12];
  const float* q_scale = (const float*)d_in[13];
  const float* k_scale = (const float*)d_in[14];
  const float* Wo_state = (const float*)d_in[15];
  const float* state_norm_g = (const float*)d_in[16];
  const float* Wq2s = (const float*)d_in[17];
  const float* Ws2q = (const float*)d_in[18];
  const float* Ws2kv = (const float*)d_in[19];
  const float* W_state_out = (const float*)d_in[20];
  const float* ema_beta = (const float*)d_in[21];
  const float* ff_g = (const float*)d_in[22];
  const float* ff_w1 = (const float*)d_in[23];
  const float* ff_b1 = (const float*)d_in[24];
  const float* ff_w2 = (const float*)d_in[25];
  const float* ff_b2 = (const float*)d_in[26];
  const float* final_g = (const float*)d_in[27];
  const float* W_logits = (const float*)d_in[28];
  const float* xl_mem_k = (const float*)d_in[29];
  const float* xl_mem_v = (const float*)d_in[30];
  const float* states_in = (const float*)d_in[31];

  float* out = (float*)d_out;
  float* out_xlk    = out + 81920000;
  float* out_xlv    = out + 84017152;
  float* out_states = out + 86114304;

  float* p = (float*)d_ws;
  float* hstate   = p; p += 2097152;
  float* xn       = p; p += 2097152;
  float* q        = p; p += 2097152;
  float* k        = p; p += 2097152;
  float* v        = p; p += 2097152;
  float* states_cur = p; p += 1048576;
  float* sn       = p; p += 1048576;
  float* q2s      = p; p += 1048576;
  float* sq       = p; p += 1048576;
  float* sproj    = p; p += 1048576;
  float* xb       = p; p += 1048576;
  float* skv      = p; p += 262144;
  float* table    = p; p += 4096;

  ushort* us = (ushort*)p;
  ushort* wqkh  = us; us += 3145728;   // [6][1024][512]: rows 0-511 q, 512-1023 k
  ushort* wqkl  = us; us += 3145728;
  ushort* wvT   = us; us += 1572864;
  ushort* woT   = us; us += 1572864;
  ushort* ffw1T = us; us += 6291456;
  ushort* ffw2T = us; us += 6291456;
  ushort* wostT = us; us += 262144;
  ushort* wstoutT = us; us += 262144;
  ushort* wq2sh = us; us += 262144;
  ushort* wq2sl = us; us += 262144;
  ushort* wsqkvh = us; us += 327680;   // [640][512]: rows 0-511 Ws2q, 512-639 Ws2kv
  ushort* wsqkvl = us; us += 327680;
  ushort* wlogT  = us; us += 10289152; // [20096][512]
  ushort* vTb   = us; us += 2097152;   // [b][h][64][1024]
  ushort* xlvT  = us; us += 2097152;   // [2][b][h][64][512]
  ushort* svT   = us; us += 131072;    // [b][64][512]
  ushort* xn16  = us; us += 2097152;   // [4096][512]
  ushort* ao16  = us; us += 2097152;   // attn_out fp16
  ushort* ff1_16 = us; us += 8388608;  // [4096][2048]; rec aliases below
  ushort* ts16  = ff1_16;              // to_state fp16 [4096][512]
  ushort* sa16  = ff1_16 + 2097152;    // satt fp16 [2048][512]

  // ---- weight prep ----
  k_prep<1><<<dim3(16,16,6),256,0,stream>>>(Wq, wqkh, wqkl, 512,512,512, 524288);
  k_prep<1><<<dim3(16,16,6),256,0,stream>>>(Wk, wqkh+262144, wqkl+262144, 512,512,512, 524288);
  k_prep<0><<<dim3(16,16,6),256,0,stream>>>(Wv, wvT, nullptr, 512,512,512, 262144);
  k_prep<0><<<dim3(16,16,6),256,0,stream>>>(Wo, woT, nullptr, 512,512,512, 262144);
  k_prep<0><<<dim3(64,16,6),256,0,stream>>>(ff_w1, ffw1T, nullptr, 512,2048,2048, 1048576);
  k_prep<0><<<dim3(16,64,6),256,0,stream>>>(ff_w2, ffw2T, nullptr, 2048,512,512, 1048576);
  k_prep<0><<<dim3(16,16,1),256,0,stream>>>(Wo_state, wostT, nullptr, 512,512,512, 262144);
  k_prep<0><<<dim3(16,16,1),256,0,stream>>>(W_state_out, wstoutT, nullptr, 512,512,512, 262144);
  k_prep<1><<<dim3(16,16,1),256,0,stream>>>(Wq2s, wq2sh, wq2sl, 512,512,512, 262144);
  k_prep<1><<<dim3(16,16,1),256,0,stream>>>(Ws2q, wsqkvh, wsqkvl, 512,512,512, 327680);
  k_prep<1><<<dim3(4,16,1),256,0,stream>>>(Ws2kv, wsqkvh+262144, wsqkvl+262144, 512,128,128, 327680);
  k_prep<0><<<dim3(628,16,1),256,0,stream>>>(W_logits, wlogT, nullptr, 512,20000,20096, 10289152);

  for (int s=0;s<2;s++)
    k_vtrans<<<dim3(8,8,4),256,0,stream>>>(xl_mem_v + (size_t)s*1048576,
                                           xlvT + (size_t)s*1048576,
                                           262144L, 512, 1, 262144L, 32768L, 512);

  k_embed<<<2048, 256, 0, stream>>>(x, tok_emb, hstate, 524288);
  k_postable<<<512, 128, 0, stream>>>(pw1,pb1,pw2,pb2,pw3,pb3, table);
  k_copy<<<4096, 256, 0, stream>>>(states_cur, states_in, 1048576);

  for (int l=0;l<6;l++){
    k_ln<<<4096,256,0,stream>>>(hstate, ln_g + l*512, xn, xn16);
    // merged q|k split-precision GEMM (N=1024)
    k_gemm_sp<<<dim3(32,8),256,0,stream>>>(xn, wqkh + (size_t)l*524288, wqkl + (size_t)l*524288,
                                           q, 512, 512, k, 512, 4096, 1024, 512);
    k_gemmh<0,0,0><<<dim3(32,4),256,0,stream>>>(xn16, wvT + (size_t)l*262144, nullptr, v, nullptr, 4096,512,512);
    float scale = 0.125f;
    if (l>=3){
      k_qkrms<<<4096,512,0,stream>>>(q, k, q_scale + l*64, k_scale + l*64);
      scale = 8.f;
    }
    k_vtrans<<<dim3(16,8,4),256,0,stream>>>(v, vTb, 524288L, 512, 1, 524288L, 65536L, 1024);

    bool isxl = (l==4 || l==5);
    int src = (l==4)? 1 : 0;     // roll(-1)
    for (int nb=0;nb<2;nb++){
      const float* K0; const ushort* VT0;
      long k0B, vt0B, vt0H; int k0R, k0H, vt0D, has_mem;
      if (nb==0 && isxl){
        K0 = xl_mem_k + (size_t)src*1048576; k0B=262144; k0R=512; k0H=1;
        VT0 = xlvT + (size_t)src*1048576; vt0B=262144; vt0H=32768; vt0D=512;
        has_mem = 1;
      } else if (nb==0){
        K0 = k; k0B=524288; k0R=512; k0H=1;
        VT0 = vTb; vt0B=524288; vt0H=65536; vt0D=1024;
        has_mem = 0;
      } else {
        K0 = k; k0B=524288; k0R=512; k0H=1;
        VT0 = vTb; vt0B=524288; vt0H=65536; vt0D=1024;
        has_mem = 1;
      }
      k_attn_mfma<1><<<dim3(8,8,4),256,0,stream>>>(
        q + nb*262144, 524288L,
        K0, k0B, k0R, k0H,
        k + nb*262144, 524288L, 512, 1,
        VT0, vt0B, vt0H, vt0D,
        vTb + nb*512, 524288L, 65536L, 1024,
        512, 512,
        ao16 + nb*262144, 524288L,
        scale, has_mem, table);
    }
    k_gemmh<1,0,0><<<dim3(32,4),256,0,stream>>>(ao16, woT + (size_t)l*262144, nullptr, hstate, nullptr, 4096,512,512);
    if (l==3){
      for (int nb=0;nb<2;nb++){
        k_ln<<<2048,256,0,stream>>>(states_cur, state_norm_g, sn, nullptr);
        // merged Ws2q|Ws2kv GEMM (N=640): sq + skv
        k_gemm_sp<<<dim3(16,5),256,0,stream>>>(sn, wsqkvh, wsqkvl,
                                               sq, 512, 512, skv, 128, 2048, 640, 512);
        k_vtrans<<<dim3(8,1,4),256,0,stream>>>(skv + 64, svT, 65536L, 128, 0, 32768L, 0L, 512);
        k_gather_xb<<<4096,256,0,stream>>>(xb, xn, nb);
        k_gemm_sp<<<dim3(16,4),256,0,stream>>>(xb, wq2sh, wq2sl,
                                               q2s, 512, 512, nullptr, 0, 2048, 512, 512);
        k_attn_mfma<0><<<dim3(8,8,4),256,0,stream>>>(
          q2s, 262144L,
          skv, 65536L, 128, 0,
          skv, 65536L, 128, 0,
          svT, 32768L, 0L, 512,
          svT, 32768L, 0L, 512,
          512, 0,
          ts16 + nb*262144, 524288L,
          0.125f, 0, table);
        k_attn_mfma<0><<<dim3(8,8,4),256,0,stream>>>(
          sq, 262144L,
          skv, 65536L, 128, 0,
          k + nb*262144, 524288L, 512, 1,
          svT, 32768L, 0L, 512,
          vTb + nb*512, 524288L, 65536L, 1024,
          512, 512,
          sa16, 262144L,
          0.125f, 0, table);
        k_gemmh<0,0,0><<<dim3(16,4),256,0,stream>>>(sa16, wstoutT, nullptr, sproj, nullptr, 2048,512,512);
        k_ema<<<4096,256,0,stream>>>(states_cur, sproj, ema_beta, 1048576);
      }
      k_gemmh<1,0,0><<<dim3(32,4),256,0,stream>>>(ts16, wostT, nullptr, hstate, nullptr, 4096,512,512);
    }
    if (isxl){
      int xli = l-4;
      k_xlout<<<4096,256,0,stream>>>(out_xlk + (size_t)xli*1048576,
                                     out_xlv + (size_t)xli*1048576, k, v);
    }
    k_ln<<<4096,256,0,stream>>>(hstate, ff_g + l*512, xn, xn16);
    k_gemmh<0,1,1><<<dim3(32,16),256,0,stream>>>(xn16, ffw1T + (size_t)l*1048576, ff_b1 + l*2048, nullptr, ff1_16, 4096,2048,512);
    k_gemmh<1,0,0><<<dim3(32,4),256,0,stream>>>(ff1_16, ffw2T + (size_t)l*1048576, ff_b2 + l*512, hstate, nullptr, 4096,512,2048);
  }
  k_ln<<<4096,256,0,stream>>>(hstate, final_g, xn, xn16);
  k_gemmh<0,0,0><<<dim3(32,157),256,0,stream>>>(xn16, wlogT, nullptr, out, nullptr, 4096,20000,512);
  k_copy<<<4096, 256, 0, stream>>>(out_states, states_cur, 1048576);
}

// Round 11
// 2128.770 us; speedup vs baseline: 5.9153x; 1.1425x over previous
//
#include <hip/hip_runtime.h>
#include <math.h>

// B=4 N=1024 V=20000 D=512 H=8 DH=64 W=512 NB=2 NS=512 FF=2048

typedef __attribute__((ext_vector_type(8))) __bf16 bf16x8;
typedef __attribute__((ext_vector_type(8))) _Float16 f16x8;
typedef __attribute__((ext_vector_type(4))) float f32x4;

__device__ __forceinline__ ushort f2b(float f){
  uint u = __float_as_uint(f);
  uint r = (u + 0x7FFFu + ((u >> 16) & 1u)) >> 16;
  return (ushort)r;
}
__device__ __forceinline__ ushort f2h(float f){
  _Float16 h = (_Float16)f;
  return *reinterpret_cast<ushort*>(&h);
}
__device__ __forceinline__ uint pkh2(float a, float b){
  return (uint)f2h(a) | ((uint)f2h(b)<<16);
}

// ---------------- weight prep: [K][N] fp32 -> [Npad][K] fp16 / bf16 hi+lo ----
template<int MODE>
__global__ __launch_bounds__(256)
void k_prep(const float* __restrict__ src, ushort* __restrict__ dh,
            ushort* __restrict__ dl, int K, int N, int Npad, long zStride){
  __shared__ float tile[32][33];
  int z = blockIdx.z;
  src += (size_t)z*K*N;
  dh  += (size_t)z*zStride;
  if (MODE) dl += (size_t)z*zStride;
  int n0 = blockIdx.x*32, k0 = blockIdx.y*32;
  int tx = threadIdx.x&31, ty = threadIdx.x>>5;
#pragma unroll
  for (int i=0;i<4;i++){
    int kk = k0 + ty + i*8, nn = n0 + tx;
    tile[ty+i*8][tx] = (nn < N) ? src[(size_t)kk*N + nn] : 0.f;
  }
  __syncthreads();
#pragma unroll
  for (int i=0;i<4;i++){
    int nn = n0 + ty + i*8, kk = k0 + tx;
    float v = tile[tx][ty+i*8];
    if (MODE==0){
      dh[(size_t)nn*K + kk] = f2h(v);
    } else {
      ushort h = f2b(v);
      dh[(size_t)nn*K + kk] = h;
      float fh = __uint_as_float((uint)h<<16);
      dl[(size_t)nn*K + kk] = f2b(v - fh);
    }
  }
}

// ---------------- V transpose: fp32 [b][key][cols] -> fp16 [b][h][64][NK] ----
__global__ __launch_bounds__(256)
void k_vtrans(const float* __restrict__ src, ushort* __restrict__ dst,
              long sB, int sR, int sMH, long dB, long dH, int NK){
  __shared__ float tile[64][65];
  int kc = blockIdx.x, h = blockIdx.y, b = blockIdx.z;
  int t = threadIdx.x;
  int key = t>>2, doff = (t&3)*16;
  const float* sp = src + (size_t)b*sB + (size_t)(kc*64+key)*sR + (sMH? h*64:0) + doff;
#pragma unroll
  for (int u=0;u<4;u++){
    float4 v = *reinterpret_cast<const float4*>(sp + u*4);
    tile[key][doff+u*4+0]=v.x; tile[key][doff+u*4+1]=v.y;
    tile[key][doff+u*4+2]=v.z; tile[key][doff+u*4+3]=v.w;
  }
  __syncthreads();
  int d = t>>2, kf = (t&3)*16;
  ushort* dp = dst + (size_t)b*dB + (size_t)h*dH + (size_t)d*NK + kc*64 + kf;
  ushort tmp[16];
#pragma unroll
  for (int u=0;u<16;u++) tmp[u] = f2h(tile[kf+u][d]);
  uint4 o0 = make_uint4((uint)tmp[0]|((uint)tmp[1]<<16), (uint)tmp[2]|((uint)tmp[3]<<16),
                        (uint)tmp[4]|((uint)tmp[5]<<16), (uint)tmp[6]|((uint)tmp[7]<<16));
  uint4 o1 = make_uint4((uint)tmp[8]|((uint)tmp[9]<<16), (uint)tmp[10]|((uint)tmp[11]<<16),
                        (uint)tmp[12]|((uint)tmp[13]<<16),(uint)tmp[14]|((uint)tmp[15]<<16));
  *reinterpret_cast<uint4*>(dp)   = o0;
  *reinterpret_cast<uint4*>(dp+8) = o1;
}

// fp16 -> fp16 transpose (for skv16 V half)
__global__ __launch_bounds__(256)
void k_vtrans16(const ushort* __restrict__ src, ushort* __restrict__ dst,
                long sB, int sR, long dB, int NK){
  __shared__ ushort tile[64][72];
  int kc = blockIdx.x, b = blockIdx.z;
  int t = threadIdx.x;
  int key = t>>2, doff = (t&3)*16;
  const ushort* sp = src + (size_t)b*sB + (size_t)(kc*64+key)*sR + doff;
  *reinterpret_cast<uint4*>(&tile[key][doff])   = *reinterpret_cast<const uint4*>(sp);
  *reinterpret_cast<uint4*>(&tile[key][doff+8]) = *reinterpret_cast<const uint4*>(sp+8);
  __syncthreads();
  int d = t>>2, kf = (t&3)*16;
  ushort* dp = dst + (size_t)b*dB + (size_t)d*NK + kc*64 + kf;
  ushort tmp[16];
#pragma unroll
  for (int u=0;u<16;u++) tmp[u] = tile[kf+u][d];
  uint4 o0 = make_uint4((uint)tmp[0]|((uint)tmp[1]<<16), (uint)tmp[2]|((uint)tmp[3]<<16),
                        (uint)tmp[4]|((uint)tmp[5]<<16), (uint)tmp[6]|((uint)tmp[7]<<16));
  uint4 o1 = make_uint4((uint)tmp[8]|((uint)tmp[9]<<16), (uint)tmp[10]|((uint)tmp[11]<<16),
                        (uint)tmp[12]|((uint)tmp[13]<<16),(uint)tmp[14]|((uint)tmp[15]<<16));
  *reinterpret_cast<uint4*>(dp)   = o0;
  *reinterpret_cast<uint4*>(dp+8) = o1;
}

// fp32 -> fp16 elementwise (pairs): converts 2*n2 floats total
__global__ void k_cvt(ushort* __restrict__ dst, const float* __restrict__ src, int n2){
  int idx = blockIdx.x*blockDim.x + threadIdx.x;
  if (idx >= n2) return;
  reinterpret_cast<uint*>(dst)[idx] = pkh2(src[2*idx], src[2*idx+1]);
}

// ---------------- embed / postable ----------------
__global__ void k_embed(const int* __restrict__ x, const float* __restrict__ emb,
                        float* __restrict__ h, int total4){
  int idx = blockIdx.x*blockDim.x + threadIdx.x;
  if (idx >= total4) return;
  int row = idx >> 7;
  int c4  = idx & 127;
  int tok = x[row];
  reinterpret_cast<float4*>(h)[idx] =
      reinterpret_cast<const float4*>(emb)[(size_t)tok*128 + c4];
}

__global__ void k_postable(const float* __restrict__ w1, const float* __restrict__ b1,
                           const float* __restrict__ w2, const float* __restrict__ b2,
                           const float* __restrict__ w3, const float* __restrict__ b3,
                           float* __restrict__ table){
  __shared__ float h1[128];
  __shared__ float h2[128];
  int d = blockIdx.x, t = threadIdx.x;
  float a = (float)d * w1[t] + b1[t];
  h1[t] = a / (1.f + __expf(-a));
  __syncthreads();
  float acc = b2[t];
  for (int p=0;p<128;p++) acc += h1[p]*w2[p*128+t];
  h2[t] = acc / (1.f + __expf(-acc));
  __syncthreads();
  if (t < 8){
    float acc2 = b3[t];
    for (int p=0;p<128;p++) acc2 += h2[p]*w3[p*8+t];
    table[d*8+t] = acc2;
  }
}

// ---------------- layernorm: fp16 out and/or bf16 hi/lo out ----------------
__global__ void k_ln(const float* __restrict__ x, const float* __restrict__ g,
                     ushort* __restrict__ y16,
                     ushort* __restrict__ yh, ushort* __restrict__ yl){
  int row = blockIdx.x;
  int t = threadIdx.x;
  float2 v = reinterpret_cast<const float2*>(x + (size_t)row*512)[t];
  float s = v.x+v.y, ss = v.x*v.x+v.y*v.y;
  for (int o=32;o;o>>=1){ s += __shfl_down(s,o); ss += __shfl_down(ss,o); }
  __shared__ float ls[4], lss[4];
  __shared__ float smu, srs;
  int wid = t>>6;
  if ((t&63)==0){ ls[wid]=s; lss[wid]=ss; }
  __syncthreads();
  if (t==0){
    float S=ls[0]+ls[1]+ls[2]+ls[3], SS=lss[0]+lss[1]+lss[2]+lss[3];
    float mu = S*(1.f/512.f);
    float var = SS*(1.f/512.f) - mu*mu;
    smu = mu; srs = rsqrtf(var + 1e-5f);
  }
  __syncthreads();
  float mu=smu, rs=srs;
  float2 gg = reinterpret_cast<const float2*>(g)[t];
  float ya = (v.x-mu)*rs*gg.x, yb = (v.y-mu)*rs*gg.y;
  size_t o2 = (size_t)row*512 + 2*t;
  if (y16)
    *reinterpret_cast<uint*>(&y16[o2]) = pkh2(ya, yb);
  if (yh){
    ushort ha = f2b(ya), hb = f2b(yb);
    *reinterpret_cast<uint*>(&yh[o2]) = (uint)ha | ((uint)hb<<16);
    float fa = __uint_as_float((uint)ha<<16), fb = __uint_as_float((uint)hb<<16);
    *reinterpret_cast<uint*>(&yl[o2]) = (uint)f2b(ya-fa) | ((uint)f2b(yb-fb)<<16);
  }
}

// qk rmsnorm in place (fp32) + fp16 emit
__global__ void k_qkrms16(float* __restrict__ q, float* __restrict__ k,
                          ushort* __restrict__ q16, ushort* __restrict__ k16,
                          const float* __restrict__ qs, const float* __restrict__ ks){
  int row = blockIdx.x;
  int h = threadIdx.x >> 6, d = threadIdx.x & 63;
  size_t base = (size_t)row*512 + h*64 + d;
  float qv = q[base];
  float s = qv*qv;
  for (int o=32;o;o>>=1) s += __shfl_xor(s,o);
  float qn = qv*rsqrtf(s+1e-12f)*qs[d];
  q[base] = qn; q16[base] = f2h(qn);
  float kv = k[base];
  float s2 = kv*kv;
  for (int o=32;o;o>>=1) s2 += __shfl_xor(s2,o);
  float kn = kv*rsqrtf(s2+1e-12f)*ks[d];
  k[base] = kn; k16[base] = f2h(kn);
}

__device__ __forceinline__ float geluf(float x){
  float u = 1.5957691216f*(x + 0.044715f*x*x*x);
  return x / (1.f + __expf(-u));
}

// ---------------- fp16 MFMA GEMM: C[M,N] (+)= A@Bt^T ----------------
template<int ACC, int EPI, int OUT16>
__global__ __launch_bounds__(256)
void k_gemmh(const ushort* __restrict__ A, const ushort* __restrict__ Bt,
             const float* __restrict__ bias, float* __restrict__ C,
             ushort* __restrict__ C16, int M, int N, int K){
  __shared__ ushort As[128][68];
  __shared__ ushort Bs[128][68];
  const int t = threadIdx.x;
  const int m0 = blockIdx.x*128, n0 = blockIdx.y*128;
  const int w = t>>6, lane = t&63;
  const int wm = (w>>1)*64, wn = (w&1)*64;
  const int fr = lane&15, fg = lane>>4;
  const int srow = t>>1, sko = (t&1)*32;

  f32x4 acc[4][4];
#pragma unroll
  for (int i=0;i<4;i++)
#pragma unroll
    for (int j=0;j<4;j++){ acc[i][j][0]=0.f; acc[i][j][1]=0.f; acc[i][j][2]=0.f; acc[i][j][3]=0.f; }

  const ushort* ap = A  + (size_t)(m0+srow)*K + sko;
  const ushort* bp = Bt + (size_t)(n0+srow)*K + sko;

  for (int k0=0; k0<K; k0+=64){
    uint4 av[4], bv[4];
#pragma unroll
    for (int u=0;u<4;u++){
      av[u] = *reinterpret_cast<const uint4*>(ap + k0 + u*8);
      bv[u] = *reinterpret_cast<const uint4*>(bp + k0 + u*8);
    }
#pragma unroll
    for (int u=0;u<4;u++){
      *reinterpret_cast<uint4*>(&As[srow][sko+u*8]) = av[u];
      *reinterpret_cast<uint4*>(&Bs[srow][sko+u*8]) = bv[u];
    }
    __syncthreads();
#pragma unroll
    for (int kk=0;kk<2;kk++){
      f16x8 af[4], bf[4];
#pragma unroll
      for (int mi=0;mi<4;mi++)
        af[mi] = *reinterpret_cast<const f16x8*>(&As[wm+mi*16+fr][kk*32+fg*8]);
#pragma unroll
      for (int nj=0;nj<4;nj++)
        bf[nj] = *reinterpret_cast<const f16x8*>(&Bs[wn+nj*16+fr][kk*32+fg*8]);
#pragma unroll
      for (int mi=0;mi<4;mi++)
#pragma unroll
        for (int nj=0;nj<4;nj++)
          acc[mi][nj] = __builtin_amdgcn_mfma_f32_16x16x32_f16(af[mi], bf[nj], acc[mi][nj], 0,0,0);
    }
    __syncthreads();
  }
#pragma unroll
  for (int mi=0;mi<4;mi++){
#pragma unroll
    for (int r=0;r<4;r++){
      int row = m0 + wm + mi*16 + fg*4 + r;
#pragma unroll
      for (int nj=0;nj<4;nj++){
        int col = n0 + wn + nj*16 + fr;
        if (col < N){
          float val = acc[mi][nj][r];
          if (bias) val += bias[col];
          if (EPI==1) val = geluf(val);
          if (OUT16){
            C16[(size_t)row*N + col] = f2h(val);
          } else {
            if (ACC) C[(size_t)row*N + col] += val; else C[(size_t)row*N + col] = val;
          }
        }
      }
    }
  }
}

// ---------------- split-bf16 MFMA GEMM (pre-split A) ----------------
__global__ __launch_bounds__(256)
void k_gemm_sp(const ushort* __restrict__ Ah, const ushort* __restrict__ Al,
               const ushort* __restrict__ Bh, const ushort* __restrict__ Bl,
               float* __restrict__ C1, ushort* __restrict__ C1h, int ld1, int N1,
               float* __restrict__ C2, ushort* __restrict__ C2h, int ld2,
               int M, int N, int K){
  __shared__ ushort As[2][128][36];
  __shared__ ushort Bs[2][128][36];
  const int t = threadIdx.x;
  const int m0 = blockIdx.x*128, n0 = blockIdx.y*128;
  const int w = t>>6, lane = t&63;
  const int wm = (w>>1)*64, wn = (w&1)*64;
  const int fr = lane&15, fg = lane>>4;
  const int srow = t>>1, sko = (t&1)*16;

  f32x4 acc[4][4];
#pragma unroll
  for (int i=0;i<4;i++)
#pragma unroll
    for (int j=0;j<4;j++){ acc[i][j][0]=0.f; acc[i][j][1]=0.f; acc[i][j][2]=0.f; acc[i][j][3]=0.f; }

  const ushort* aph = Ah + (size_t)(m0+srow)*K + sko;
  const ushort* apl = Al + (size_t)(m0+srow)*K + sko;
  const ushort* bph = Bh + (size_t)(n0+srow)*K + sko;
  const ushort* bpl = Bl + (size_t)(n0+srow)*K + sko;

  for (int k0=0; k0<K; k0+=32){
    uint4 a0 = *reinterpret_cast<const uint4*>(aph + k0);
    uint4 a1 = *reinterpret_cast<const uint4*>(aph + k0 + 8);
    uint4 al0 = *reinterpret_cast<const uint4*>(apl + k0);
    uint4 al1 = *reinterpret_cast<const uint4*>(apl + k0 + 8);
    uint4 b0 = *reinterpret_cast<const uint4*>(bph + k0);
    uint4 b1 = *reinterpret_cast<const uint4*>(bph + k0 + 8);
    uint4 bl0 = *reinterpret_cast<const uint4*>(bpl + k0);
    uint4 bl1 = *reinterpret_cast<const uint4*>(bpl + k0 + 8);
    *reinterpret_cast<uint4*>(&As[0][srow][sko])   = a0;
    *reinterpret_cast<uint4*>(&As[0][srow][sko+8]) = a1;
    *reinterpret_cast<uint4*>(&As[1][srow][sko])   = al0;
    *reinterpret_cast<uint4*>(&As[1][srow][sko+8]) = al1;
    *reinterpret_cast<uint4*>(&Bs[0][srow][sko])   = b0;
    *reinterpret_cast<uint4*>(&Bs[0][srow][sko+8]) = b1;
    *reinterpret_cast<uint4*>(&Bs[1][srow][sko])   = bl0;
    *reinterpret_cast<uint4*>(&Bs[1][srow][sko+8]) = bl1;
    __syncthreads();

    bf16x8 ah[4], al[4], bh[4], bl[4];
#pragma unroll
    for (int mi=0;mi<4;mi++){
      ah[mi] = *reinterpret_cast<const bf16x8*>(&As[0][wm+mi*16+fr][fg*8]);
      al[mi] = *reinterpret_cast<const bf16x8*>(&As[1][wm+mi*16+fr][fg*8]);
    }
#pragma unroll
    for (int nj=0;nj<4;nj++){
      bh[nj] = *reinterpret_cast<const bf16x8*>(&Bs[0][wn+nj*16+fr][fg*8]);
      bl[nj] = *reinterpret_cast<const bf16x8*>(&Bs[1][wn+nj*16+fr][fg*8]);
    }
#pragma unroll
    for (int mi=0;mi<4;mi++)
#pragma unroll
      for (int nj=0;nj<4;nj++){
        acc[mi][nj] = __builtin_amdgcn_mfma_f32_16x16x32_bf16(ah[mi], bh[nj], acc[mi][nj], 0,0,0);
        acc[mi][nj] = __builtin_amdgcn_mfma_f32_16x16x32_bf16(al[mi], bh[nj], acc[mi][nj], 0,0,0);
        acc[mi][nj] = __builtin_amdgcn_mfma_f32_16x16x32_bf16(ah[mi], bl[nj], acc[mi][nj], 0,0,0);
      }
    __syncthreads();
  }
#pragma unroll
  for (int mi=0;mi<4;mi++){
#pragma unroll
    for (int r=0;r<4;r++){
      int row = m0 + wm + mi*16 + fg*4 + r;
#pragma unroll
      for (int nj=0;nj<4;nj++){
        int col = n0 + wn + nj*16 + fr;
        float val = acc[mi][nj][r];
        if (col < N1){
          if (C1)  C1[(size_t)row*ld1 + col] = val;
          if (C1h) C1h[(size_t)row*ld1 + col] = f2h(val);
        } else if (col < N){
          if (C2)  C2[(size_t)row*ld2 + (col-N1)] = val;
          if (C2h) C2h[(size_t)row*ld2 + (col-N1)] = f2h(val);
        }
      }
    }
  }
}

// ---------------- MFMA flash attention (all-fp16 inputs, fp16 output) --------
template<int WIN>
__global__ __launch_bounds__(256)
void k_attn_mfma(const ushort* __restrict__ Q, long qB,
                 const ushort* __restrict__ K0, long k0B, int k0R, int k0H,
                 const ushort* __restrict__ K1, long k1B, int k1R, int k1H,
                 const ushort* __restrict__ VT0, long vt0B, long vt0H, int vt0D,
                 const ushort* __restrict__ VT1, long vt1B, long vt1H, int vt1D,
                 int n0, int n1,
                 ushort* __restrict__ O, long oB,
                 float scale, int has_mem, const float* __restrict__ table){
  __shared__ ushort Qs[64][72];
  __shared__ ushort Ks[64][72];
  __shared__ ushort Vs[64][72];
  __shared__ ushort Pw[4][16][72];
  __shared__ float tcol[512];
  const int b = blockIdx.z, h = blockIdx.y, qt = blockIdx.x;
  const int t = threadIdx.x, w = t>>6, lane = t&63;
  const int fr = lane&15, fg = lane>>4;
  if (WIN){
    tcol[t]     = table[t*8 + h];
    tcol[t+256] = table[(t+256)*8 + h];
  }
  {
    int qrow = t>>2, doff = (t&3)*16;
    const ushort* qp = Q + (size_t)b*qB + (size_t)(qt*64+qrow)*512 + h*64 + doff;
    *reinterpret_cast<uint4*>(&Qs[qrow][doff])   = *reinterpret_cast<const uint4*>(qp);
    *reinterpret_cast<uint4*>(&Qs[qrow][doff+8]) = *reinterpret_cast<const uint4*>(qp+8);
  }
  __syncthreads();
  f16x8 aq[2];
  aq[0] = *reinterpret_cast<const f16x8*>(&Qs[w*16+fr][fg*8]);
  aq[1] = *reinterpret_cast<const f16x8*>(&Qs[w*16+fr][32+fg*8]);

  f32x4 so[4];
#pragma unroll
  for (int dt=0;dt<4;dt++){ so[dt][0]=0.f; so[dt][1]=0.f; so[dt][2]=0.f; so[dt][3]=0.f; }
  float m[4] = {-1e30f,-1e30f,-1e30f,-1e30f};
  float lsum[4] = {0.f,0.f,0.f,0.f};

  const int nt = (n0+n1)>>6;
  const int srow = t>>2, sdo = (t&3)*16;
  const int vd = t>>2,   vkf = (t&3)*16;

  int jt0 = 0, jt1 = nt-1;
  if (WIN){
    jt0 = has_mem ? qt : 8;
    jt1 = qt + 8; if (jt1 > nt-1) jt1 = nt-1;
  }

  for (int jt=jt0; jt<=jt1; jt++){
    {
      int key = jt*64 + srow;
      const ushort* kp;
      if (key < n0) kp = K0 + (size_t)b*k0B + (size_t)key*k0R + (k0H? h*64:0) + sdo;
      else          kp = K1 + (size_t)b*k1B + (size_t)(key-n0)*k1R + (k1H? h*64:0) + sdo;
      *reinterpret_cast<uint4*>(&Ks[srow][sdo])   = *reinterpret_cast<const uint4*>(kp);
      *reinterpret_cast<uint4*>(&Ks[srow][sdo+8]) = *reinterpret_cast<const uint4*>(kp+8);
    }
    {
      const ushort* vp;
      if (jt*64 < n0) vp = VT0 + (size_t)b*vt0B + (size_t)h*vt0H + (size_t)vd*vt0D + jt*64 + vkf;
      else            vp = VT1 + (size_t)b*vt1B + (size_t)h*vt1H + (size_t)vd*vt1D + (jt*64-n0) + vkf;
      *reinterpret_cast<uint4*>(&Vs[vd][vkf])   = *reinterpret_cast<const uint4*>(vp);
      *reinterpret_cast<uint4*>(&Vs[vd][vkf+8]) = *reinterpret_cast<const uint4*>(vp+8);
    }
    __syncthreads();
    f32x4 sacc[4];
#pragma unroll
    for (int kt=0;kt<4;kt++){ sacc[kt][0]=0.f; sacc[kt][1]=0.f; sacc[kt][2]=0.f; sacc[kt][3]=0.f; }
#pragma unroll
    for (int ks=0;ks<2;ks++){
#pragma unroll
      for (int kt=0;kt<4;kt++){
        f16x8 bf = *reinterpret_cast<const f16x8*>(&Ks[kt*16+fr][ks*32+fg*8]);
        sacc[kt] = __builtin_amdgcn_mfma_f32_16x16x32_f16(aq[ks], bf, sacc[kt], 0,0,0);
      }
    }
#pragma unroll
    for (int r=0;r<4;r++){
      float sv[4];
      int ia = qt*64 + w*16 + fg*4 + r;
#pragma unroll
      for (int kt=0;kt<4;kt++){
        float s = sacc[kt][r]*scale;
        if (WIN){
          int jg = jt*64 + kt*16 + fr;
          bool valid = (jg > ia) && (jg <= ia+512) && (has_mem || jg >= 512);
          s = valid ? s + tcol[ia+512-jg] : -1e9f;
        }
        sv[kt] = s;
      }
      float tm = fmaxf(fmaxf(sv[0],sv[1]), fmaxf(sv[2],sv[3]));
      tm = fmaxf(tm, __shfl_xor(tm,1));
      tm = fmaxf(tm, __shfl_xor(tm,2));
      tm = fmaxf(tm, __shfl_xor(tm,4));
      tm = fmaxf(tm, __shfl_xor(tm,8));
      float mn = fmaxf(m[r], tm);
      float c = __expf(m[r]-mn);
      m[r] = mn;
      float ps = 0.f;
#pragma unroll
      for (int kt=0;kt<4;kt++){
        float pp = (sv[kt] <= -1e8f) ? 0.f : __expf(sv[kt]-mn);
        ps += pp;
        Pw[w][fg*4+r][kt*16+fr] = f2h(pp);
      }
      ps += __shfl_xor(ps,1);
      ps += __shfl_xor(ps,2);
      ps += __shfl_xor(ps,4);
      ps += __shfl_xor(ps,8);
      lsum[r] = lsum[r]*c + ps;
#pragma unroll
      for (int dt=0;dt<4;dt++) so[dt][r] *= c;
    }
#pragma unroll
    for (int ks=0;ks<2;ks++){
      f16x8 pa = *reinterpret_cast<const f16x8*>(&Pw[w][fr][ks*32+fg*8]);
#pragma unroll
      for (int dt=0;dt<4;dt++){
        f16x8 bv = *reinterpret_cast<const f16x8*>(&Vs[dt*16+fr][ks*32+fg*8]);
        so[dt] = __builtin_amdgcn_mfma_f32_16x16x32_f16(pa, bv, so[dt], 0,0,0);
      }
    }
    __syncthreads();
  }
#pragma unroll
  for (int r=0;r<4;r++){
    int row = qt*64 + w*16 + fg*4 + r;
    float inv = 1.f / lsum[r];
    ushort* op = O + (size_t)b*oB + (size_t)row*512 + h*64;
#pragma unroll
    for (int dt=0;dt<4;dt++)
      op[dt*16+fr] = f2h(so[dt][r]*inv);
  }
}

// ---------------- small utility kernels ----------------
__global__ void k_copy(float* __restrict__ dst, const float* __restrict__ src, int n){
  int idx = blockIdx.x*blockDim.x + threadIdx.x;
  if (idx < n) dst[idx] = src[idx];
}
__global__ void k_gather16(ushort* __restrict__ dh, ushort* __restrict__ dl,
                           const ushort* __restrict__ sh, const ushort* __restrict__ sl,
                           int nb){
  int idx = blockIdx.x*blockDim.x + threadIdx.x;
  if (idx >= 1048576) return;
  int b = idx >> 18, rem = idx & 262143;
  size_t s = (size_t)b*524288 + (size_t)nb*262144 + rem;
  dh[idx] = sh[s]; dl[idx] = sl[s];
}
__global__ void k_xlout(float* __restrict__ dk, float* __restrict__ dv,
                        const float* __restrict__ k, const float* __restrict__ v){
  int idx = blockIdx.x*blockDim.x + threadIdx.x;
  if (idx >= 1048576) return;
  int b = idx >> 18, rem = idx & 262143;
  size_t s = (size_t)b*524288 + 262144 + rem;
  dk[idx] = k[s]; dv[idx] = v[s];
}
__global__ void k_ema(float* __restrict__ st, const float* __restrict__ sp,
                      const float* __restrict__ beta, int n){
  int idx = blockIdx.x*blockDim.x + threadIdx.x;
  if (idx >= n) return;
  int d = idx & 511;
  float dec = 1.f/(1.f+__expf(-beta[d]));
  st[idx] = dec*st[idx] + (1.f-dec)*sp[idx];
}

// ---------------- launcher ----------------
extern "C" void kernel_launch(void* const* d_in, const int* in_sizes, int n_in,
                              void* d_out, int out_size, void* d_ws, size_t ws_size,
                              hipStream_t stream){
  // floats 41,959,424 B + ushorts 122,814,464 B = 164,773,888 B
  if (ws_size < (size_t)164773888) return;

  const int*   x        = (const int*)  d_in[0];
  const float* tok_emb  = (const float*)d_in[1];
  const float* pw1 = (const float*)d_in[2];
  const float* pb1 = (const float*)d_in[3];
  const float* pw2 = (const float*)d_in[4];
  const float* pb2 = (const float*)d_in[5];
  const float* pw3 = (const float*)d_in[6];
  const float* pb3 = (const float*)d_in[7];
  const float* ln_g = (const float*)d_in[8];
  const float* Wq = (const float*)d_in[9];
  const float* Wk = (const float*)d_in[10];
  const float* Wv = (const float*)d_in[11];
  const float* Wo = (const float*)d_in[12];
  const float* q_scale = (const float*)d_in[13];
  const float* k_scale = (const float*)d_in[14];
  const float* Wo_state = (const float*)d_in[15];
  const float* state_norm_g = (const float*)d_in[16];
  const float* Wq2s = (const float*)d_in[17];
  const float* Ws2q = (const float*)d_in[18];
  const float* Ws2kv = (const float*)d_in[19];
  const float* W_state_out = (const float*)d_in[20];
  const float* ema_beta = (const float*)d_in[21];
  const float* ff_g = (const float*)d_in[22];
  const float* ff_w1 = (const float*)d_in[23];
  const float* ff_b1 = (const float*)d_in[24];
  const float* ff_w2 = (const float*)d_in[25];
  const float* ff_b2 = (const float*)d_in[26];
  const float* final_g = (const float*)d_in[27];
  const float* W_logits = (const float*)d_in[28];
  const float* xl_mem_k = (const float*)d_in[29];
  const float* xl_mem_v = (const float*)d_in[30];
  const float* states_in = (const float*)d_in[31];

  float* out = (float*)d_out;
  float* out_xlk    = out + 81920000;
  float* out_xlv    = out + 84017152;
  float* out_states = out + 86114304;

  float* p = (float*)d_ws;
  float* hstate   = p; p += 2097152;
  float* q        = p; p += 2097152;
  float* k        = p; p += 2097152;
  float* v        = p; p += 2097152;
  float* states_cur = p; p += 1048576;
  float* sproj    = p; p += 1048576;
  float* table    = p; p += 4096;

  ushort* us = (ushort*)p;
  ushort* wqkh  = us; us += 3145728;   // [6][1024][512]: rows 0-511 q, 512-1023 k
  ushort* wqkl  = us; us += 3145728;
  ushort* wvT   = us; us += 1572864;
  ushort* woT   = us; us += 1572864;
  ushort* ffw1T = us; us += 6291456;
  ushort* ffw2T = us; us += 6291456;
  ushort* wostT = us; us += 262144;
  ushort* wstoutT = us; us += 262144;
  ushort* wq2sh = us; us += 262144;
  ushort* wq2sl = us; us += 262144;
  ushort* wsqkvh = us; us += 327680;   // [640][512]: rows 0-511 Ws2q, 512-639 Ws2kv
  ushort* wsqkvl = us; us += 327680;
  ushort* wlogT  = us; us += 10289152; // [20096][512]
  ushort* vTb   = us; us += 2097152;   // [b][h][64][1024]
  ushort* xlvT  = us; us += 2097152;   // [2][b][h][64][512]
  ushort* svT   = us; us += 131072;    // [b][64][512]
  ushort* xn16  = us; us += 2097152;   // fp16 LN out
  ushort* ao16  = us; us += 2097152;   // attn out fp16
  ushort* ff1_16 = us; us += 8388608;  // [4096][2048] + rec aliases
  ushort* xnh   = us; us += 2097152;   // bf16 hi of attn-LN
  ushort* xnl   = us; us += 2097152;
  ushort* q16   = us; us += 2097152;
  ushort* k16   = us; us += 2097152;
  ushort* xlk16 = us; us += 2097152;   // [2][b][512][512] fp16
  // rec aliases inside ff1_16 (dead between FF uses)
  ushort* ts16   = ff1_16;             // [4096][512]
  ushort* sa16   = ff1_16 + 2097152;   // [2048][512]
  ushort* snh    = ff1_16 + 3145728;   // [2048][512]
  ushort* snl    = ff1_16 + 4194304;
  ushort* sq16   = ff1_16 + 5242880;
  ushort* q2s16  = ff1_16 + 6291456;
  ushort* skv16  = ff1_16 + 7340032;   // [2048][128]
  ushort* xbh = snh; ushort* xbl = snl;  // sn dead when xb gathered

  // ---- weight prep ----
  k_prep<1><<<dim3(16,16,6),256,0,stream>>>(Wq, wqkh, wqkl, 512,512,512, 524288);
  k_prep<1><<<dim3(16,16,6),256,0,stream>>>(Wk, wqkh+262144, wqkl+262144, 512,512,512, 524288);
  k_prep<0><<<dim3(16,16,6),256,0,stream>>>(Wv, wvT, nullptr, 512,512,512, 262144);
  k_prep<0><<<dim3(16,16,6),256,0,stream>>>(Wo, woT, nullptr, 512,512,512, 262144);
  k_prep<0><<<dim3(64,16,6),256,0,stream>>>(ff_w1, ffw1T, nullptr, 512,2048,2048, 1048576);
  k_prep<0><<<dim3(16,64,6),256,0,stream>>>(ff_w2, ffw2T, nullptr, 2048,512,512, 1048576);
  k_prep<0><<<dim3(16,16,1),256,0,stream>>>(Wo_state, wostT, nullptr, 512,512,512, 262144);
  k_prep<0><<<dim3(16,16,1),256,0,stream>>>(W_state_out, wstoutT, nullptr, 512,512,512, 262144);
  k_prep<1><<<dim3(16,16,1),256,0,stream>>>(Wq2s, wq2sh, wq2sl, 512,512,512, 262144);
  k_prep<1><<<dim3(16,16,1),256,0,stream>>>(Ws2q, wsqkvh, wsqkvl, 512,512,512, 327680);
  k_prep<1><<<dim3(4,16,1),256,0,stream>>>(Ws2kv, wsqkvh+262144, wsqkvl+262144, 512,128,128, 327680);
  k_prep<0><<<dim3(628,16,1),256,0,stream>>>(W_logits, wlogT, nullptr, 512,20000,20096, 10289152);

  for (int s=0;s<2;s++)
    k_vtrans<<<dim3(8,8,4),256,0,stream>>>(xl_mem_v + (size_t)s*1048576,
                                           xlvT + (size_t)s*1048576,
                                           262144L, 512, 1, 262144L, 32768L, 512);
  // xl_mem_k: 2,097,152 floats total -> 1,048,576 pair-conversions
  k_cvt<<<4096,256,0,stream>>>(xlk16, xl_mem_k, 1048576);

  k_embed<<<2048, 256, 0, stream>>>(x, tok_emb, hstate, 524288);
  k_postable<<<512, 128, 0, stream>>>(pw1,pb1,pw2,pb2,pw3,pb3, table);
  k_copy<<<4096, 256, 0, stream>>>(states_cur, states_in, 1048576);

  for (int l=0;l<6;l++){
    k_ln<<<4096,256,0,stream>>>(hstate, ln_g + l*512, xn16, xnh, xnl);
    float scale = 0.125f;
    if (l>=3){
      // fp32 q,k then rms + fp16 emit
      k_gemm_sp<<<dim3(32,8),256,0,stream>>>(xnh, xnl,
          wqkh + (size_t)l*524288, wqkl + (size_t)l*524288,
          q, nullptr, 512, 512, k, nullptr, 512, 4096, 1024, 512);
      k_qkrms16<<<4096,512,0,stream>>>(q, k, q16, k16, q_scale + l*64, k_scale + l*64);
      scale = 8.f;
    } else {
      // fp16 q,k direct
      k_gemm_sp<<<dim3(32,8),256,0,stream>>>(xnh, xnl,
          wqkh + (size_t)l*524288, wqkl + (size_t)l*524288,
          nullptr, q16, 512, 512, nullptr, k16, 512, 4096, 1024, 512);
    }
    k_gemmh<0,0,0><<<dim3(32,4),256,0,stream>>>(xn16, wvT + (size_t)l*262144, nullptr, v, nullptr, 4096,512,512);
    k_vtrans<<<dim3(16,8,4),256,0,stream>>>(v, vTb, 524288L, 512, 1, 524288L, 65536L, 1024);

    bool isxl = (l==4 || l==5);
    int src = (l==4)? 1 : 0;     // roll(-1)
    for (int nb=0;nb<2;nb++){
      const ushort* K0; const ushort* VT0;
      long k0B, vt0B, vt0H; int k0R, k0H, vt0D, has_mem;
      if (nb==0 && isxl){
        K0 = xlk16 + (size_t)src*1048576; k0B=262144; k0R=512; k0H=1;
        VT0 = xlvT + (size_t)src*1048576; vt0B=262144; vt0H=32768; vt0D=512;
        has_mem = 1;
      } else if (nb==0){
        K0 = k16; k0B=524288; k0R=512; k0H=1;          // dummy (masked, jt0 skips)
        VT0 = vTb; vt0B=524288; vt0H=65536; vt0D=1024;
        has_mem = 0;
      } else {
        K0 = k16; k0B=524288; k0R=512; k0H=1;          // prev block = block 0
        VT0 = vTb; vt0B=524288; vt0H=65536; vt0D=1024;
        has_mem = 1;
      }
      k_attn_mfma<1><<<dim3(8,8,4),256,0,stream>>>(
        q16 + nb*262144, 524288L,
        K0, k0B, k0R, k0H,
        k16 + nb*262144, 524288L, 512, 1,
        VT0, vt0B, vt0H, vt0D,
        vTb + nb*512, 524288L, 65536L, 1024,
        512, 512,
        ao16 + nb*262144, 524288L,
        scale, has_mem, table);
    }
    k_gemmh<1,0,0><<<dim3(32,4),256,0,stream>>>(ao16, woT + (size_t)l*262144, nullptr, hstate, nullptr, 4096,512,512);
    if (l==3){
      for (int nb=0;nb<2;nb++){
        k_ln<<<2048,256,0,stream>>>(states_cur, state_norm_g, nullptr, snh, snl);
        k_gemm_sp<<<dim3(16,5),256,0,stream>>>(snh, snl, wsqkvh, wsqkvl,
            nullptr, sq16, 512, 512, nullptr, skv16, 128, 2048, 640, 512);
        k_vtrans16<<<dim3(8,1,4),256,0,stream>>>(skv16 + 64, svT, 65536L, 128, 32768L, 512);
        k_gather16<<<4096,256,0,stream>>>(xbh, xbl, xnh, xnl, nb);
        k_gemm_sp<<<dim3(16,4),256,0,stream>>>(xbh, xbl, wq2sh, wq2sl,
            nullptr, q2s16, 512, 512, nullptr, nullptr, 0, 2048, 512, 512);
        k_attn_mfma<0><<<dim3(8,8,4),256,0,stream>>>(
          q2s16, 262144L,
          skv16, 65536L, 128, 0,
          skv16, 65536L, 128, 0,
          svT, 32768L, 0L, 512,
          svT, 32768L, 0L, 512,
          512, 0,
          ts16 + nb*262144, 524288L,
          0.125f, 0, table);
        k_attn_mfma<0><<<dim3(8,8,4),256,0,stream>>>(
          sq16, 262144L,
          skv16, 65536L, 128, 0,
          k16 + nb*262144, 524288L, 512, 1,
          svT, 32768L, 0L, 512,
          vTb + nb*512, 524288L, 65536L, 1024,
          512, 512,
          sa16, 262144L,
          0.125f, 0, table);
        k_gemmh<0,0,0><<<dim3(16,4),256,0,stream>>>(sa16, wstoutT, nullptr, sproj, nullptr, 2048,512,512);
        k_ema<<<4096,256,0,stream>>>(states_cur, sproj, ema_beta, 1048576);
      }
      k_gemmh<1,0,0><<<dim3(32,4),256,0,stream>>>(ts16, wostT, nullptr, hstate, nullptr, 4096,512,512);
    }
    if (isxl){
      int xli = l-4;
      k_xlout<<<4096,256,0,stream>>>(out_xlk + (size_t)xli*1048576,
                                     out_xlv + (size_t)xli*1048576, k, v);
    }
    k_ln<<<4096,256,0,stream>>>(hstate, ff_g + l*512, xn16, nullptr, nullptr);
    k_gemmh<0,1,1><<<dim3(32,16),256,0,stream>>>(xn16, ffw1T + (size_t)l*1048576, ff_b1 + l*2048, nullptr, ff1_16, 4096,2048,512);
    k_gemmh<1,0,0><<<dim3(32,4),256,0,stream>>>(ff1_16, ffw2T + (size_t)l*1048576, ff_b2 + l*512, hstate, nullptr, 4096,512,2048);
  }
  k_ln<<<4096,256,0,stream>>>(hstate, final_g, xn16, nullptr, nullptr);
  k_gemmh<0,0,0><<<dim3(32,157),256,0,stream>>>(xn16, wlogT, nullptr, out, nullptr, 4096,20000,512);
  k_copy<<<4096, 256, 0, stream>>>(out_states, states_cur, 1048576);
}

// Round 13
// 1881.944 us; speedup vs baseline: 6.6911x; 1.1312x over previous
//
#include <hip/hip_runtime.h>
#include <math.h>

// B=4 N=1024 V=20000 D=512 H=8 DH=64 W=512 NB=2 NS=512 FF=2048

typedef __attribute__((ext_vector_type(8))) __bf16 bf16x8;
typedef __attribute__((ext_vector_type(8))) _Float16 f16x8;
typedef __attribute__((ext_vector_type(4))) float f32x4;

__device__ __forceinline__ ushort f2b(float f){
  uint u = __float_as_uint(f);
  uint r = (u + 0x7FFFu + ((u >> 16) & 1u)) >> 16;
  return (ushort)r;
}
__device__ __forceinline__ ushort f2h(float f){
  _Float16 h = (_Float16)f;
  return *reinterpret_cast<ushort*>(&h);
}
__device__ __forceinline__ uint pkh2(float a, float b){
  return (uint)f2h(a) | ((uint)f2h(b)<<16);
}

// ---------------- weight prep: [K][N] fp32 -> [Npad][K] fp16 / bf16 hi+lo ----
template<int MODE>
__global__ __launch_bounds__(256)
void k_prep(const float* __restrict__ src, ushort* __restrict__ dh,
            ushort* __restrict__ dl, int K, int N, int Npad, long zStride){
  __shared__ float tile[32][33];
  int z = blockIdx.z;
  src += (size_t)z*K*N;
  dh  += (size_t)z*zStride;
  if (MODE) dl += (size_t)z*zStride;
  int n0 = blockIdx.x*32, k0 = blockIdx.y*32;
  int tx = threadIdx.x&31, ty = threadIdx.x>>5;
#pragma unroll
  for (int i=0;i<4;i++){
    int kk = k0 + ty + i*8, nn = n0 + tx;
    tile[ty+i*8][tx] = (nn < N) ? src[(size_t)kk*N + nn] : 0.f;
  }
  __syncthreads();
#pragma unroll
  for (int i=0;i<4;i++){
    int nn = n0 + ty + i*8, kk = k0 + tx;
    float v = tile[tx][ty+i*8];
    if (MODE==0){
      dh[(size_t)nn*K + kk] = f2h(v);
    } else {
      ushort h = f2b(v);
      dh[(size_t)nn*K + kk] = h;
      float fh = __uint_as_float((uint)h<<16);
      dl[(size_t)nn*K + kk] = f2b(v - fh);
    }
  }
}

// ---------------- V transpose: fp32 [b][key][cols] -> fp16 [b][h][64][NK] ----
__global__ __launch_bounds__(256)
void k_vtrans(const float* __restrict__ src, ushort* __restrict__ dst,
              long sB, int sR, int sMH, long dB, long dH, int NK){
  __shared__ float tile[64][65];
  int kc = blockIdx.x, h = blockIdx.y, b = blockIdx.z;
  int t = threadIdx.x;
  int key = t>>2, doff = (t&3)*16;
  const float* sp = src + (size_t)b*sB + (size_t)(kc*64+key)*sR + (sMH? h*64:0) + doff;
#pragma unroll
  for (int u=0;u<4;u++){
    float4 v = *reinterpret_cast<const float4*>(sp + u*4);
    tile[key][doff+u*4+0]=v.x; tile[key][doff+u*4+1]=v.y;
    tile[key][doff+u*4+2]=v.z; tile[key][doff+u*4+3]=v.w;
  }
  __syncthreads();
  int d = t>>2, kf = (t&3)*16;
  ushort* dp = dst + (size_t)b*dB + (size_t)h*dH + (size_t)d*NK + kc*64 + kf;
  ushort tmp[16];
#pragma unroll
  for (int u=0;u<16;u++) tmp[u] = f2h(tile[kf+u][d]);
  uint4 o0 = make_uint4((uint)tmp[0]|((uint)tmp[1]<<16), (uint)tmp[2]|((uint)tmp[3]<<16),
                        (uint)tmp[4]|((uint)tmp[5]<<16), (uint)tmp[6]|((uint)tmp[7]<<16));
  uint4 o1 = make_uint4((uint)tmp[8]|((uint)tmp[9]<<16), (uint)tmp[10]|((uint)tmp[11]<<16),
                        (uint)tmp[12]|((uint)tmp[13]<<16),(uint)tmp[14]|((uint)tmp[15]<<16));
  *reinterpret_cast<uint4*>(dp)   = o0;
  *reinterpret_cast<uint4*>(dp+8) = o1;
}

// fp16 -> fp16 transpose (for skv16 V half)
__global__ __launch_bounds__(256)
void k_vtrans16(const ushort* __restrict__ src, ushort* __restrict__ dst,
                long sB, int sR, long dB, int NK){
  __shared__ ushort tile[64][72];
  int kc = blockIdx.x, b = blockIdx.z;
  int t = threadIdx.x;
  int key = t>>2, doff = (t&3)*16;
  const ushort* sp = src + (size_t)b*sB + (size_t)(kc*64+key)*sR + doff;
  *reinterpret_cast<uint4*>(&tile[key][doff])   = *reinterpret_cast<const uint4*>(sp);
  *reinterpret_cast<uint4*>(&tile[key][doff+8]) = *reinterpret_cast<const uint4*>(sp+8);
  __syncthreads();
  int d = t>>2, kf = (t&3)*16;
  ushort* dp = dst + (size_t)b*dB + (size_t)d*NK + kc*64 + kf;
  ushort tmp[16];
#pragma unroll
  for (int u=0;u<16;u++) tmp[u] = tile[kf+u][d];
  uint4 o0 = make_uint4((uint)tmp[0]|((uint)tmp[1]<<16), (uint)tmp[2]|((uint)tmp[3]<<16),
                        (uint)tmp[4]|((uint)tmp[5]<<16), (uint)tmp[6]|((uint)tmp[7]<<16));
  uint4 o1 = make_uint4((uint)tmp[8]|((uint)tmp[9]<<16), (uint)tmp[10]|((uint)tmp[11]<<16),
                        (uint)tmp[12]|((uint)tmp[13]<<16),(uint)tmp[14]|((uint)tmp[15]<<16));
  *reinterpret_cast<uint4*>(dp)   = o0;
  *reinterpret_cast<uint4*>(dp+8) = o1;
}

// fp32 -> fp16 elementwise (pairs): converts 2*n2 floats total
__global__ void k_cvt(ushort* __restrict__ dst, const float* __restrict__ src, int n2){
  int idx = blockIdx.x*blockDim.x + threadIdx.x;
  if (idx >= n2) return;
  reinterpret_cast<uint*>(dst)[idx] = pkh2(src[2*idx], src[2*idx+1]);
}

// ---------------- embed / postable ----------------
__global__ void k_embed(const int* __restrict__ x, const float* __restrict__ emb,
                        float* __restrict__ h, int total4){
  int idx = blockIdx.x*blockDim.x + threadIdx.x;
  if (idx >= total4) return;
  int row = idx >> 7;
  int c4  = idx & 127;
  int tok = x[row];
  reinterpret_cast<float4*>(h)[idx] =
      reinterpret_cast<const float4*>(emb)[(size_t)tok*128 + c4];
}

__global__ void k_postable(const float* __restrict__ w1, const float* __restrict__ b1,
                           const float* __restrict__ w2, const float* __restrict__ b2,
                           const float* __restrict__ w3, const float* __restrict__ b3,
                           float* __restrict__ table){
  __shared__ float h1[128];
  __shared__ float h2[128];
  int d = blockIdx.x, t = threadIdx.x;
  float a = (float)d * w1[t] + b1[t];
  h1[t] = a / (1.f + __expf(-a));
  __syncthreads();
  float acc = b2[t];
  for (int p=0;p<128;p++) acc += h1[p]*w2[p*128+t];
  h2[t] = acc / (1.f + __expf(-acc));
  __syncthreads();
  if (t < 8){
    float acc2 = b3[t];
    for (int p=0;p<128;p++) acc2 += h2[p]*w3[p*8+t];
    table[d*8+t] = acc2;
  }
}

// ---------------- layernorm: fp16 out and/or bf16 hi/lo out ----------------
__global__ void k_ln(const float* __restrict__ x, const float* __restrict__ g,
                     ushort* __restrict__ y16,
                     ushort* __restrict__ yh, ushort* __restrict__ yl){
  int row = blockIdx.x;
  int t = threadIdx.x;
  float2 v = reinterpret_cast<const float2*>(x + (size_t)row*512)[t];
  float s = v.x+v.y, ss = v.x*v.x+v.y*v.y;
  for (int o=32;o;o>>=1){ s += __shfl_down(s,o); ss += __shfl_down(ss,o); }
  __shared__ float ls[4], lss[4];
  __shared__ float smu, srs;
  int wid = t>>6;
  if ((t&63)==0){ ls[wid]=s; lss[wid]=ss; }
  __syncthreads();
  if (t==0){
    float S=ls[0]+ls[1]+ls[2]+ls[3], SS=lss[0]+lss[1]+lss[2]+lss[3];
    float mu = S*(1.f/512.f);
    float var = SS*(1.f/512.f) - mu*mu;
    smu = mu; srs = rsqrtf(var + 1e-5f);
  }
  __syncthreads();
  float mu=smu, rs=srs;
  float2 gg = reinterpret_cast<const float2*>(g)[t];
  float ya = (v.x-mu)*rs*gg.x, yb = (v.y-mu)*rs*gg.y;
  size_t o2 = (size_t)row*512 + 2*t;
  if (y16)
    *reinterpret_cast<uint*>(&y16[o2]) = pkh2(ya, yb);
  if (yh){
    ushort ha = f2b(ya), hb = f2b(yb);
    *reinterpret_cast<uint*>(&yh[o2]) = (uint)ha | ((uint)hb<<16);
    float fa = __uint_as_float((uint)ha<<16), fb = __uint_as_float((uint)hb<<16);
    *reinterpret_cast<uint*>(&yl[o2]) = (uint)f2b(ya-fa) | ((uint)f2b(yb-fb)<<16);
  }
}

// qk rmsnorm in place (fp32) + fp16 emit
__global__ void k_qkrms16(float* __restrict__ q, float* __restrict__ k,
                          ushort* __restrict__ q16, ushort* __restrict__ k16,
                          const float* __restrict__ qs, const float* __restrict__ ks){
  int row = blockIdx.x;
  int h = threadIdx.x >> 6, d = threadIdx.x & 63;
  size_t base = (size_t)row*512 + h*64 + d;
  float qv = q[base];
  float s = qv*qv;
  for (int o=32;o;o>>=1) s += __shfl_xor(s,o);
  float qn = qv*rsqrtf(s+1e-12f)*qs[d];
  q[base] = qn; q16[base] = f2h(qn);
  float kv = k[base];
  float s2 = kv*kv;
  for (int o=32;o;o>>=1) s2 += __shfl_xor(s2,o);
  float kn = kv*rsqrtf(s2+1e-12f)*ks[d];
  k[base] = kn; k16[base] = f2h(kn);
}

__device__ __forceinline__ float geluf(float x){
  float u = 1.5957691216f*(x + 0.044715f*x*x*x);
  return x / (1.f + __expf(-u));
}

// ---------------- fp16 MFMA GEMM 128x128: C[M,N] (+)= A@Bt^T ----------------
template<int ACC, int EPI, int OUT16>
__global__ __launch_bounds__(256)
void k_gemmh(const ushort* __restrict__ A, const ushort* __restrict__ Bt,
             const float* __restrict__ bias, float* __restrict__ C,
             ushort* __restrict__ C16, int M, int N, int K){
  __shared__ ushort As[128][68];
  __shared__ ushort Bs[128][68];
  const int t = threadIdx.x;
  const int m0 = blockIdx.x*128, n0 = blockIdx.y*128;
  const int w = t>>6, lane = t&63;
  const int wm = (w>>1)*64, wn = (w&1)*64;
  const int fr = lane&15, fg = lane>>4;
  const int srow = t>>1, sko = (t&1)*32;

  f32x4 acc[4][4];
#pragma unroll
  for (int i=0;i<4;i++)
#pragma unroll
    for (int j=0;j<4;j++){ acc[i][j][0]=0.f; acc[i][j][1]=0.f; acc[i][j][2]=0.f; acc[i][j][3]=0.f; }

  const ushort* ap = A  + (size_t)(m0+srow)*K + sko;
  const ushort* bp = Bt + (size_t)(n0+srow)*K + sko;

  for (int k0=0; k0<K; k0+=64){
    uint4 av[4], bv[4];
#pragma unroll
    for (int u=0;u<4;u++){
      av[u] = *reinterpret_cast<const uint4*>(ap + k0 + u*8);
      bv[u] = *reinterpret_cast<const uint4*>(bp + k0 + u*8);
    }
#pragma unroll
    for (int u=0;u<4;u++){
      *reinterpret_cast<uint4*>(&As[srow][sko+u*8]) = av[u];
      *reinterpret_cast<uint4*>(&Bs[srow][sko+u*8]) = bv[u];
    }
    __syncthreads();
#pragma unroll
    for (int kk=0;kk<2;kk++){
      f16x8 af[4], bf[4];
#pragma unroll
      for (int mi=0;mi<4;mi++)
        af[mi] = *reinterpret_cast<const f16x8*>(&As[wm+mi*16+fr][kk*32+fg*8]);
#pragma unroll
      for (int nj=0;nj<4;nj++)
        bf[nj] = *reinterpret_cast<const f16x8*>(&Bs[wn+nj*16+fr][kk*32+fg*8]);
#pragma unroll
      for (int mi=0;mi<4;mi++)
#pragma unroll
        for (int nj=0;nj<4;nj++)
          acc[mi][nj] = __builtin_amdgcn_mfma_f32_16x16x32_f16(af[mi], bf[nj], acc[mi][nj], 0,0,0);
    }
    __syncthreads();
  }
#pragma unroll
  for (int mi=0;mi<4;mi++){
#pragma unroll
    for (int r=0;r<4;r++){
      int row = m0 + wm + mi*16 + fg*4 + r;
#pragma unroll
      for (int nj=0;nj<4;nj++){
        int col = n0 + wn + nj*16 + fr;
        if (col < N){
          float val = acc[mi][nj][r];
          if (bias) val += bias[col];
          if (EPI==1) val = geluf(val);
          if (OUT16){
            C16[(size_t)row*N + col] = f2h(val);
          } else {
            if (ACC) C[(size_t)row*N + col] += val; else C[(size_t)row*N + col] = val;
          }
        }
      }
    }
  }
}

// ---------------- fp16 MFMA GEMM 64x128 (full-grid variant for N=512) --------
// 4 waves 2x2, each wave 32x64 (2x4 frags). Grid (M/64, ceil(N/128)).
// Same K-summation order as k_gemmh -> bit-identical results.
template<int ACC, int EPI, int OUT16>
__global__ __launch_bounds__(256)
void k_gemmh64(const ushort* __restrict__ A, const ushort* __restrict__ Bt,
               const float* __restrict__ bias, float* __restrict__ C,
               ushort* __restrict__ C16, int M, int N, int K){
  __shared__ ushort As[64][68];
  __shared__ ushort Bs[128][68];
  const int t = threadIdx.x;
  const int m0 = blockIdx.x*64, n0 = blockIdx.y*128;
  const int w = t>>6, lane = t&63;
  const int wm = (w>>1)*32, wn = (w&1)*64;
  const int fr = lane&15, fg = lane>>4;
  const int srowA = t>>2, skoA = (t&3)*16;   // A: 64 rows x 64, 16 ushorts/thread
  const int srowB = t>>1, skoB = (t&1)*32;   // B: 128 rows x 64, 32 ushorts/thread

  f32x4 acc[2][4];
#pragma unroll
  for (int i=0;i<2;i++)
#pragma unroll
    for (int j=0;j<4;j++){ acc[i][j][0]=0.f; acc[i][j][1]=0.f; acc[i][j][2]=0.f; acc[i][j][3]=0.f; }

  const ushort* ap = A  + (size_t)(m0+srowA)*K + skoA;
  const ushort* bp = Bt + (size_t)(n0+srowB)*K + skoB;

  for (int k0=0; k0<K; k0+=64){
    uint4 a0 = *reinterpret_cast<const uint4*>(ap + k0);
    uint4 a1 = *reinterpret_cast<const uint4*>(ap + k0 + 8);
    uint4 b0 = *reinterpret_cast<const uint4*>(bp + k0);
    uint4 b1 = *reinterpret_cast<const uint4*>(bp + k0 + 8);
    uint4 b2 = *reinterpret_cast<const uint4*>(bp + k0 + 16);
    uint4 b3 = *reinterpret_cast<const uint4*>(bp + k0 + 24);
    *reinterpret_cast<uint4*>(&As[srowA][skoA])    = a0;
    *reinterpret_cast<uint4*>(&As[srowA][skoA+8])  = a1;
    *reinterpret_cast<uint4*>(&Bs[srowB][skoB])    = b0;
    *reinterpret_cast<uint4*>(&Bs[srowB][skoB+8])  = b1;
    *reinterpret_cast<uint4*>(&Bs[srowB][skoB+16]) = b2;
    *reinterpret_cast<uint4*>(&Bs[srowB][skoB+24]) = b3;
    __syncthreads();
#pragma unroll
    for (int kk=0;kk<2;kk++){
      f16x8 af[2], bf[4];
#pragma unroll
      for (int mi=0;mi<2;mi++)
        af[mi] = *reinterpret_cast<const f16x8*>(&As[wm+mi*16+fr][kk*32+fg*8]);
#pragma unroll
      for (int nj=0;nj<4;nj++)
        bf[nj] = *reinterpret_cast<const f16x8*>(&Bs[wn+nj*16+fr][kk*32+fg*8]);
#pragma unroll
      for (int mi=0;mi<2;mi++)
#pragma unroll
        for (int nj=0;nj<4;nj++)
          acc[mi][nj] = __builtin_amdgcn_mfma_f32_16x16x32_f16(af[mi], bf[nj], acc[mi][nj], 0,0,0);
    }
    __syncthreads();
  }
#pragma unroll
  for (int mi=0;mi<2;mi++){
#pragma unroll
    for (int r=0;r<4;r++){
      int row = m0 + wm + mi*16 + fg*4 + r;
#pragma unroll
      for (int nj=0;nj<4;nj++){
        int col = n0 + wn + nj*16 + fr;
        if (col < N){
          float val = acc[mi][nj][r];
          if (bias) val += bias[col];
          if (EPI==1) val = geluf(val);
          if (OUT16){
            C16[(size_t)row*N + col] = f2h(val);
          } else {
            if (ACC) C[(size_t)row*N + col] += val; else C[(size_t)row*N + col] = val;
          }
        }
      }
    }
  }
}

// ---------------- split-bf16 MFMA GEMM (pre-split A) ----------------
__global__ __launch_bounds__(256)
void k_gemm_sp(const ushort* __restrict__ Ah, const ushort* __restrict__ Al,
               const ushort* __restrict__ Bh, const ushort* __restrict__ Bl,
               float* __restrict__ C1, ushort* __restrict__ C1h, int ld1, int N1,
               float* __restrict__ C2, ushort* __restrict__ C2h, int ld2,
               int M, int N, int K){
  __shared__ ushort As[2][128][36];
  __shared__ ushort Bs[2][128][36];
  const int t = threadIdx.x;
  const int m0 = blockIdx.x*128, n0 = blockIdx.y*128;
  const int w = t>>6, lane = t&63;
  const int wm = (w>>1)*64, wn = (w&1)*64;
  const int fr = lane&15, fg = lane>>4;
  const int srow = t>>1, sko = (t&1)*16;

  f32x4 acc[4][4];
#pragma unroll
  for (int i=0;i<4;i++)
#pragma unroll
    for (int j=0;j<4;j++){ acc[i][j][0]=0.f; acc[i][j][1]=0.f; acc[i][j][2]=0.f; acc[i][j][3]=0.f; }

  const ushort* aph = Ah + (size_t)(m0+srow)*K + sko;
  const ushort* apl = Al + (size_t)(m0+srow)*K + sko;
  const ushort* bph = Bh + (size_t)(n0+srow)*K + sko;
  const ushort* bpl = Bl + (size_t)(n0+srow)*K + sko;

  for (int k0=0; k0<K; k0+=32){
    uint4 a0 = *reinterpret_cast<const uint4*>(aph + k0);
    uint4 a1 = *reinterpret_cast<const uint4*>(aph + k0 + 8);
    uint4 al0 = *reinterpret_cast<const uint4*>(apl + k0);
    uint4 al1 = *reinterpret_cast<const uint4*>(apl + k0 + 8);
    uint4 b0 = *reinterpret_cast<const uint4*>(bph + k0);
    uint4 b1 = *reinterpret_cast<const uint4*>(bph + k0 + 8);
    uint4 bl0 = *reinterpret_cast<const uint4*>(bpl + k0);
    uint4 bl1 = *reinterpret_cast<const uint4*>(bpl + k0 + 8);
    *reinterpret_cast<uint4*>(&As[0][srow][sko])   = a0;
    *reinterpret_cast<uint4*>(&As[0][srow][sko+8]) = a1;
    *reinterpret_cast<uint4*>(&As[1][srow][sko])   = al0;
    *reinterpret_cast<uint4*>(&As[1][srow][sko+8]) = al1;
    *reinterpret_cast<uint4*>(&Bs[0][srow][sko])   = b0;
    *reinterpret_cast<uint4*>(&Bs[0][srow][sko+8]) = b1;
    *reinterpret_cast<uint4*>(&Bs[1][srow][sko])   = bl0;
    *reinterpret_cast<uint4*>(&Bs[1][srow][sko+8]) = bl1;
    __syncthreads();

    bf16x8 ah[4], al[4], bh[4], bl[4];
#pragma unroll
    for (int mi=0;mi<4;mi++){
      ah[mi] = *reinterpret_cast<const bf16x8*>(&As[0][wm+mi*16+fr][fg*8]);
      al[mi] = *reinterpret_cast<const bf16x8*>(&As[1][wm+mi*16+fr][fg*8]);
    }
#pragma unroll
    for (int nj=0;nj<4;nj++){
      bh[nj] = *reinterpret_cast<const bf16x8*>(&Bs[0][wn+nj*16+fr][fg*8]);
      bl[nj] = *reinterpret_cast<const bf16x8*>(&Bs[1][wn+nj*16+fr][fg*8]);
    }
#pragma unroll
    for (int mi=0;mi<4;mi++)
#pragma unroll
      for (int nj=0;nj<4;nj++){
        acc[mi][nj] = __builtin_amdgcn_mfma_f32_16x16x32_bf16(ah[mi], bh[nj], acc[mi][nj], 0,0,0);
        acc[mi][nj] = __builtin_amdgcn_mfma_f32_16x16x32_bf16(al[mi], bh[nj], acc[mi][nj], 0,0,0);
        acc[mi][nj] = __builtin_amdgcn_mfma_f32_16x16x32_bf16(ah[mi], bl[nj], acc[mi][nj], 0,0,0);
      }
    __syncthreads();
  }
#pragma unroll
  for (int mi=0;mi<4;mi++){
#pragma unroll
    for (int r=0;r<4;r++){
      int row = m0 + wm + mi*16 + fg*4 + r;
#pragma unroll
      for (int nj=0;nj<4;nj++){
        int col = n0 + wn + nj*16 + fr;
        float val = acc[mi][nj][r];
        if (col < N1){
          if (C1)  C1[(size_t)row*ld1 + col] = val;
          if (C1h) C1h[(size_t)row*ld1 + col] = f2h(val);
        } else if (col < N){
          if (C2)  C2[(size_t)row*ld2 + (col-N1)] = val;
          if (C2h) C2h[(size_t)row*ld2 + (col-N1)] = f2h(val);
        }
      }
    }
  }
}

// ---------------- MFMA flash attention (all-fp16 inputs, fp16 output) --------
template<int WIN>
__global__ __launch_bounds__(256)
void k_attn_mfma(const ushort* __restrict__ Q, long qB,
                 const ushort* __restrict__ K0, long k0B, int k0R, int k0H,
                 const ushort* __restrict__ K1, long k1B, int k1R, int k1H,
                 const ushort* __restrict__ VT0, long vt0B, long vt0H, int vt0D,
                 const ushort* __restrict__ VT1, long vt1B, long vt1H, int vt1D,
                 int n0, int n1,
                 ushort* __restrict__ O, long oB,
                 float scale, int has_mem, const float* __restrict__ table){
  __shared__ ushort Qs[64][72];
  __shared__ ushort Ks[64][72];
  __shared__ ushort Vs[64][72];
  __shared__ ushort Pw[4][16][72];
  __shared__ float tcol[512];
  const int b = blockIdx.z, h = blockIdx.y, qt = blockIdx.x;
  const int t = threadIdx.x, w = t>>6, lane = t&63;
  const int fr = lane&15, fg = lane>>4;
  if (WIN){
    tcol[t]     = table[t*8 + h];
    tcol[t+256] = table[(t+256)*8 + h];
  }
  {
    int qrow = t>>2, doff = (t&3)*16;
    const ushort* qp = Q + (size_t)b*qB + (size_t)(qt*64+qrow)*512 + h*64 + doff;
    *reinterpret_cast<uint4*>(&Qs[qrow][doff])   = *reinterpret_cast<const uint4*>(qp);
    *reinterpret_cast<uint4*>(&Qs[qrow][doff+8]) = *reinterpret_cast<const uint4*>(qp+8);
  }
  __syncthreads();
  f16x8 aq[2];
  aq[0] = *reinterpret_cast<const f16x8*>(&Qs[w*16+fr][fg*8]);
  aq[1] = *reinterpret_cast<const f16x8*>(&Qs[w*16+fr][32+fg*8]);

  f32x4 so[4];
#pragma unroll
  for (int dt=0;dt<4;dt++){ so[dt][0]=0.f; so[dt][1]=0.f; so[dt][2]=0.f; so[dt][3]=0.f; }
  float m[4] = {-1e30f,-1e30f,-1e30f,-1e30f};
  float lsum[4] = {0.f,0.f,0.f,0.f};

  const int nt = (n0+n1)>>6;
  const int srow = t>>2, sdo = (t&3)*16;
  const int vd = t>>2,   vkf = (t&3)*16;

  int jt0 = 0, jt1 = nt-1;
  if (WIN){
    jt0 = has_mem ? qt : 8;
    jt1 = qt + 8; if (jt1 > nt-1) jt1 = nt-1;
  }

  for (int jt=jt0; jt<=jt1; jt++){
    {
      int key = jt*64 + srow;
      const ushort* kp;
      if (key < n0) kp = K0 + (size_t)b*k0B + (size_t)key*k0R + (k0H? h*64:0) + sdo;
      else          kp = K1 + (size_t)b*k1B + (size_t)(key-n0)*k1R + (k1H? h*64:0) + sdo;
      *reinterpret_cast<uint4*>(&Ks[srow][sdo])   = *reinterpret_cast<const uint4*>(kp);
      *reinterpret_cast<uint4*>(&Ks[srow][sdo+8]) = *reinterpret_cast<const uint4*>(kp+8);
    }
    {
      const ushort* vp;
      if (jt*64 < n0) vp = VT0 + (size_t)b*vt0B + (size_t)h*vt0H + (size_t)vd*vt0D + jt*64 + vkf;
      else            vp = VT1 + (size_t)b*vt1B + (size_t)h*vt1H + (size_t)vd*vt1D + (jt*64-n0) + vkf;
      *reinterpret_cast<uint4*>(&Vs[vd][vkf])   = *reinterpret_cast<const uint4*>(vp);
      *reinterpret_cast<uint4*>(&Vs[vd][vkf+8]) = *reinterpret_cast<const uint4*>(vp+8);
    }
    __syncthreads();
    f32x4 sacc[4];
#pragma unroll
    for (int kt=0;kt<4;kt++){ sacc[kt][0]=0.f; sacc[kt][1]=0.f; sacc[kt][2]=0.f; sacc[kt][3]=0.f; }
#pragma unroll
    for (int ks=0;ks<2;ks++){
#pragma unroll
      for (int kt=0;kt<4;kt++){
        f16x8 bf = *reinterpret_cast<const f16x8*>(&Ks[kt*16+fr][ks*32+fg*8]);
        sacc[kt] = __builtin_amdgcn_mfma_f32_16x16x32_f16(aq[ks], bf, sacc[kt], 0,0,0);
      }
    }
#pragma unroll
    for (int r=0;r<4;r++){
      float sv[4];
      int ia = qt*64 + w*16 + fg*4 + r;
#pragma unroll
      for (int kt=0;kt<4;kt++){
        float s = sacc[kt][r]*scale;
        if (WIN){
          int jg = jt*64 + kt*16 + fr;
          bool valid = (jg > ia) && (jg <= ia+512) && (has_mem || jg >= 512);
          s = valid ? s + tcol[ia+512-jg] : -1e9f;
        }
        sv[kt] = s;
      }
      float tm = fmaxf(fmaxf(sv[0],sv[1]), fmaxf(sv[2],sv[3]));
      tm = fmaxf(tm, __shfl_xor(tm,1));
      tm = fmaxf(tm, __shfl_xor(tm,2));
      tm = fmaxf(tm, __shfl_xor(tm,4));
      tm = fmaxf(tm, __shfl_xor(tm,8));
      float mn = fmaxf(m[r], tm);
      float c = __expf(m[r]-mn);
      m[r] = mn;
      float ps = 0.f;
#pragma unroll
      for (int kt=0;kt<4;kt++){
        float pp = (sv[kt] <= -1e8f) ? 0.f : __expf(sv[kt]-mn);
        ps += pp;
        Pw[w][fg*4+r][kt*16+fr] = f2h(pp);
      }
      ps += __shfl_xor(ps,1);
      ps += __shfl_xor(ps,2);
      ps += __shfl_xor(ps,4);
      ps += __shfl_xor(ps,8);
      lsum[r] = lsum[r]*c + ps;
#pragma unroll
      for (int dt=0;dt<4;dt++) so[dt][r] *= c;
    }
#pragma unroll
    for (int ks=0;ks<2;ks++){
      f16x8 pa = *reinterpret_cast<const f16x8*>(&Pw[w][fr][ks*32+fg*8]);
#pragma unroll
      for (int dt=0;dt<4;dt++){
        f16x8 bv = *reinterpret_cast<const f16x8*>(&Vs[dt*16+fr][ks*32+fg*8]);
        so[dt] = __builtin_amdgcn_mfma_f32_16x16x32_f16(pa, bv, so[dt], 0,0,0);
      }
    }
    __syncthreads();
  }
#pragma unroll
  for (int r=0;r<4;r++){
    int row = qt*64 + w*16 + fg*4 + r;
    float inv = 1.f / lsum[r];
    ushort* op = O + (size_t)b*oB + (size_t)row*512 + h*64;
#pragma unroll
    for (int dt=0;dt<4;dt++)
      op[dt*16+fr] = f2h(so[dt][r]*inv);
  }
}

// ---------------- small utility kernels ----------------
__global__ void k_copy(float* __restrict__ dst, const float* __restrict__ src, int n){
  int idx = blockIdx.x*blockDim.x + threadIdx.x;
  if (idx < n) dst[idx] = src[idx];
}
__global__ void k_gather16(ushort* __restrict__ dh, ushort* __restrict__ dl,
                           const ushort* __restrict__ sh, const ushort* __restrict__ sl,
                           int nb){
  int idx = blockIdx.x*blockDim.x + threadIdx.x;
  if (idx >= 1048576) return;
  int b = idx >> 18, rem = idx & 262143;
  size_t s = (size_t)b*524288 + (size_t)nb*262144 + rem;
  dh[idx] = sh[s]; dl[idx] = sl[s];
}
__global__ void k_xlout(float* __restrict__ dk, float* __restrict__ dv,
                        const float* __restrict__ k, const float* __restrict__ v){
  int idx = blockIdx.x*blockDim.x + threadIdx.x;
  if (idx >= 1048576) return;
  int b = idx >> 18, rem = idx & 262143;
  size_t s = (size_t)b*524288 + 262144 + rem;
  dk[idx] = k[s]; dv[idx] = v[s];
}
__global__ void k_ema(float* __restrict__ st, const float* __restrict__ sp,
                      const float* __restrict__ beta, int n){
  int idx = blockIdx.x*blockDim.x + threadIdx.x;
  if (idx >= n) return;
  int d = idx & 511;
  float dec = 1.f/(1.f+__expf(-beta[d]));
  st[idx] = dec*st[idx] + (1.f-dec)*sp[idx];
}

// ---------------- launcher ----------------
extern "C" void kernel_launch(void* const* d_in, const int* in_sizes, int n_in,
                              void* d_out, int out_size, void* d_ws, size_t ws_size,
                              hipStream_t stream){
  // floats 41,959,424 B + ushorts 122,814,464 B = 164,773,888 B
  if (ws_size < (size_t)164773888) return;

  const int*   x        = (const int*)  d_in[0];
  const float* tok_emb  = (const float*)d_in[1];
  const float* pw1 = (const float*)d_in[2];
  const float* pb1 = (const float*)d_in[3];
  const float* pw2 = (const float*)d_in[4];
  const float* pb2 = (const float*)d_in[5];
  const float* pw3 = (const float*)d_in[6];
  const float* pb3 = (const float*)d_in[7];
  const float* ln_g = (const float*)d_in[8];
  const float* Wq = (const float*)d_in[9];
  const float* Wk = (const float*)d_in[10];
  const float* Wv = (const float*)d_in[11];
  const float* Wo = (const float*)d_in[12];
  const float* q_scale = (const float*)d_in[13];
  const float* k_scale = (const float*)d_in[14];
  const float* Wo_state = (const float*)d_in[15];
  const float* state_norm_g = (const float*)d_in[16];
  const float* Wq2s = (const float*)d_in[17];
  const float* Ws2q = (const float*)d_in[18];
  const float* Ws2kv = (const float*)d_in[19];
  const float* W_state_out = (const float*)d_in[20];
  const float* ema_beta = (const float*)d_in[21];
  const float* ff_g = (const float*)d_in[22];
  const float* ff_w1 = (const float*)d_in[23];
  const float* ff_b1 = (const float*)d_in[24];
  const float* ff_w2 = (const float*)d_in[25];
  const float* ff_b2 = (const float*)d_in[26];
  const float* final_g = (const float*)d_in[27];
  const float* W_logits = (const float*)d_in[28];
  const float* xl_mem_k = (const float*)d_in[29];
  const float* xl_mem_v = (const float*)d_in[30];
  const float* states_in = (const float*)d_in[31];

  float* out = (float*)d_out;
  float* out_xlk    = out + 81920000;
  float* out_xlv    = out + 84017152;
  float* out_states = out + 86114304;

  float* p = (float*)d_ws;
  float* hstate   = p; p += 2097152;
  float* q        = p; p += 2097152;
  float* k        = p; p += 2097152;
  float* v        = p; p += 2097152;
  float* states_cur = p; p += 1048576;
  float* sproj    = p; p += 1048576;
  float* table    = p; p += 4096;

  ushort* us = (ushort*)p;
  ushort* wqkh  = us; us += 3145728;   // [6][1024][512]: rows 0-511 q, 512-1023 k
  ushort* wqkl  = us; us += 3145728;
  ushort* wvT   = us; us += 1572864;
  ushort* woT   = us; us += 1572864;
  ushort* ffw1T = us; us += 6291456;
  ushort* ffw2T = us; us += 6291456;
  ushort* wostT = us; us += 262144;
  ushort* wstoutT = us; us += 262144;
  ushort* wq2sh = us; us += 262144;
  ushort* wq2sl = us; us += 262144;
  ushort* wsqkvh = us; us += 327680;   // [640][512]: rows 0-511 Ws2q, 512-639 Ws2kv
  ushort* wsqkvl = us; us += 327680;
  ushort* wlogT  = us; us += 10289152; // [20096][512]
  ushort* vTb   = us; us += 2097152;   // [b][h][64][1024]
  ushort* xlvT  = us; us += 2097152;   // [2][b][h][64][512]
  ushort* svT   = us; us += 131072;    // [b][64][512]
  ushort* xn16  = us; us += 2097152;   // fp16 LN out
  ushort* ao16  = us; us += 2097152;   // attn out fp16
  ushort* ff1_16 = us; us += 8388608;  // [4096][2048] + rec aliases
  ushort* xnh   = us; us += 2097152;   // bf16 hi of attn-LN
  ushort* xnl   = us; us += 2097152;
  ushort* q16   = us; us += 2097152;
  ushort* k16   = us; us += 2097152;
  ushort* xlk16 = us; us += 2097152;   // [2][b][512][512] fp16
  // rec aliases inside ff1_16 (dead between FF uses)
  ushort* ts16   = ff1_16;             // [4096][512]
  ushort* sa16   = ff1_16 + 2097152;   // [2048][512]
  ushort* snh    = ff1_16 + 3145728;   // [2048][512]
  ushort* snl    = ff1_16 + 4194304;
  ushort* sq16   = ff1_16 + 5242880;
  ushort* q2s16  = ff1_16 + 6291456;
  ushort* skv16  = ff1_16 + 7340032;   // [2048][128]
  ushort* xbh = snh; ushort* xbl = snl;  // sn dead when xb gathered

  // ---- weight prep ----
  k_prep<1><<<dim3(16,16,6),256,0,stream>>>(Wq, wqkh, wqkl, 512,512,512, 524288);
  k_prep<1><<<dim3(16,16,6),256,0,stream>>>(Wk, wqkh+262144, wqkl+262144, 512,512,512, 524288);
  k_prep<0><<<dim3(16,16,6),256,0,stream>>>(Wv, wvT, nullptr, 512,512,512, 262144);
  k_prep<0><<<dim3(16,16,6),256,0,stream>>>(Wo, woT, nullptr, 512,512,512, 262144);
  k_prep<0><<<dim3(64,16,6),256,0,stream>>>(ff_w1, ffw1T, nullptr, 512,2048,2048, 1048576);
  k_prep<0><<<dim3(16,64,6),256,0,stream>>>(ff_w2, ffw2T, nullptr, 2048,512,512, 1048576);
  k_prep<0><<<dim3(16,16,1),256,0,stream>>>(Wo_state, wostT, nullptr, 512,512,512, 262144);
  k_prep<0><<<dim3(16,16,1),256,0,stream>>>(W_state_out, wstoutT, nullptr, 512,512,512, 262144);
  k_prep<1><<<dim3(16,16,1),256,0,stream>>>(Wq2s, wq2sh, wq2sl, 512,512,512, 262144);
  k_prep<1><<<dim3(16,16,1),256,0,stream>>>(Ws2q, wsqkvh, wsqkvl, 512,512,512, 327680);
  k_prep<1><<<dim3(4,16,1),256,0,stream>>>(Ws2kv, wsqkvh+262144, wsqkvl+262144, 512,128,128, 327680);
  k_prep<0><<<dim3(628,16,1),256,0,stream>>>(W_logits, wlogT, nullptr, 512,20000,20096, 10289152);

  for (int s=0;s<2;s++)
    k_vtrans<<<dim3(8,8,4),256,0,stream>>>(xl_mem_v + (size_t)s*1048576,
                                           xlvT + (size_t)s*1048576,
                                           262144L, 512, 1, 262144L, 32768L, 512);
  // xl_mem_k: 2,097,152 floats total -> 1,048,576 pair-conversions
  k_cvt<<<4096,256,0,stream>>>(xlk16, xl_mem_k, 1048576);

  k_embed<<<2048, 256, 0, stream>>>(x, tok_emb, hstate, 524288);
  k_postable<<<512, 128, 0, stream>>>(pw1,pb1,pw2,pb2,pw3,pb3, table);
  k_copy<<<4096, 256, 0, stream>>>(states_cur, states_in, 1048576);

  for (int l=0;l<6;l++){
    k_ln<<<4096,256,0,stream>>>(hstate, ln_g + l*512, xn16, xnh, xnl);
    float scale = 0.125f;
    if (l>=3){
      // fp32 q,k then rms + fp16 emit
      k_gemm_sp<<<dim3(32,8),256,0,stream>>>(xnh, xnl,
          wqkh + (size_t)l*524288, wqkl + (size_t)l*524288,
          q, nullptr, 512, 512, k, nullptr, 512, 4096, 1024, 512);
      k_qkrms16<<<4096,512,0,stream>>>(q, k, q16, k16, q_scale + l*64, k_scale + l*64);
      scale = 8.f;
    } else {
      // fp16 q,k direct
      k_gemm_sp<<<dim3(32,8),256,0,stream>>>(xnh, xnl,
          wqkh + (size_t)l*524288, wqkl + (size_t)l*524288,
          nullptr, q16, 512, 512, nullptr, k16, 512, 4096, 1024, 512);
    }
    k_gemmh64<0,0,0><<<dim3(64,4),256,0,stream>>>(xn16, wvT + (size_t)l*262144, nullptr, v, nullptr, 4096,512,512);
    k_vtrans<<<dim3(16,8,4),256,0,stream>>>(v, vTb, 524288L, 512, 1, 524288L, 65536L, 1024);

    bool isxl = (l==4 || l==5);
    int src = (l==4)? 1 : 0;     // roll(-1)
    for (int nb=0;nb<2;nb++){
      const ushort* K0; const ushort* VT0;
      long k0B, vt0B, vt0H; int k0R, k0H, vt0D, has_mem;
      if (nb==0 && isxl){
        K0 = xlk16 + (size_t)src*1048576; k0B=262144; k0R=512; k0H=1;
        VT0 = xlvT + (size_t)src*1048576; vt0B=262144; vt0H=32768; vt0D=512;
        has_mem = 1;
      } else if (nb==0){
        K0 = k16; k0B=524288; k0R=512; k0H=1;          // dummy (masked, jt0 skips)
        VT0 = vTb; vt0B=524288; vt0H=65536; vt0D=1024;
        has_mem = 0;
      } else {
        K0 = k16; k0B=524288; k0R=512; k0H=1;          // prev block = block 0
        VT0 = vTb; vt0B=524288; vt0H=65536; vt0D=1024;
        has_mem = 1;
      }
      k_attn_mfma<1><<<dim3(8,8,4),256,0,stream>>>(
        q16 + nb*262144, 524288L,
        K0, k0B, k0R, k0H,
        k16 + nb*262144, 524288L, 512, 1,
        VT0, vt0B, vt0H, vt0D,
        vTb + nb*512, 524288L, 65536L, 1024,
        512, 512,
        ao16 + nb*262144, 524288L,
        scale, has_mem, table);
    }
    k_gemmh64<1,0,0><<<dim3(64,4),256,0,stream>>>(ao16, woT + (size_t)l*262144, nullptr, hstate, nullptr, 4096,512,512);
    if (l==3){
      for (int nb=0;nb<2;nb++){
        k_ln<<<2048,256,0,stream>>>(states_cur, state_norm_g, nullptr, snh, snl);
        k_gemm_sp<<<dim3(16,5),256,0,stream>>>(snh, snl, wsqkvh, wsqkvl,
            nullptr, sq16, 512, 512, nullptr, skv16, 128, 2048, 640, 512);
        k_vtrans16<<<dim3(8,1,4),256,0,stream>>>(skv16 + 64, svT, 65536L, 128, 32768L, 512);
        k_gather16<<<4096,256,0,stream>>>(xbh, xbl, xnh, xnl, nb);
        k_gemm_sp<<<dim3(16,4),256,0,stream>>>(xbh, xbl, wq2sh, wq2sl,
            nullptr, q2s16, 512, 512, nullptr, nullptr, 0, 2048, 512, 512);
        k_attn_mfma<0><<<dim3(8,8,4),256,0,stream>>>(
          q2s16, 262144L,
          skv16, 65536L, 128, 0,
          skv16, 65536L, 128, 0,
          svT, 32768L, 0L, 512,
          svT, 32768L, 0L, 512,
          512, 0,
          ts16 + nb*262144, 524288L,
          0.125f, 0, table);
        k_attn_mfma<0><<<dim3(8,8,4),256,0,stream>>>(
          sq16, 262144L,
          skv16, 65536L, 128, 0,
          k16 + nb*262144, 524288L, 512, 1,
          svT, 32768L, 0L, 512,
          vTb + nb*512, 524288L, 65536L, 1024,
          512, 512,
          sa16, 262144L,
          0.125f, 0, table);
        k_gemmh64<0,0,0><<<dim3(32,4),256,0,stream>>>(sa16, wstoutT, nullptr, sproj, nullptr, 2048,512,512);
        k_ema<<<4096,256,0,stream>>>(states_cur, sproj, ema_beta, 1048576);
      }
      k_gemmh64<1,0,0><<<dim3(64,4),256,0,stream>>>(ts16, wostT, nullptr, hstate, nullptr, 4096,512,512);
    }
    if (isxl){
      int xli = l-4;
      k_xlout<<<4096,256,0,stream>>>(out_xlk + (size_t)xli*1048576,
                                     out_xlv + (size_t)xli*1048576, k, v);
    }
    k_ln<<<4096,256,0,stream>>>(hstate, ff_g + l*512, xn16, nullptr, nullptr);
    k_gemmh<0,1,1><<<dim3(32,16),256,0,stream>>>(xn16, ffw1T + (size_t)l*1048576, ff_b1 + l*2048, nullptr, ff1_16, 4096,2048,512);
    k_gemmh64<1,0,0><<<dim3(64,4),256,0,stream>>>(ff1_16, ffw2T + (size_t)l*1048576, ff_b2 + l*512, hstate, nullptr, 4096,512,2048);
  }
  k_ln<<<4096,256,0,stream>>>(hstate, final_g, xn16, nullptr, nullptr);
  k_gemmh<0,0,0><<<dim3(32,157),256,0,stream>>>(xn16, wlogT, nullptr, out, nullptr, 4096,20000,512);
  k_copy<<<4096, 256, 0, stream>>>(out_states, states_cur, 1048576);
}

// Round 14
// 1728.047 us; speedup vs baseline: 7.2870x; 1.0891x over previous
//
#include <hip/hip_runtime.h>
#include <math.h>

// B=4 N=1024 V=20000 D=512 H=8 DH=64 W=512 NB=2 NS=512 FF=2048

typedef __attribute__((ext_vector_type(8))) __bf16 bf16x8;
typedef __attribute__((ext_vector_type(8))) _Float16 f16x8;
typedef __attribute__((ext_vector_type(4))) float f32x4;

__device__ __forceinline__ ushort f2b(float f){
  uint u = __float_as_uint(f);
  uint r = (u + 0x7FFFu + ((u >> 16) & 1u)) >> 16;
  return (ushort)r;
}
__device__ __forceinline__ ushort f2h(float f){
  _Float16 h = (_Float16)f;
  return *reinterpret_cast<ushort*>(&h);
}
__device__ __forceinline__ uint pkh2(float a, float b){
  return (uint)f2h(a) | ((uint)f2h(b)<<16);
}

// ---------------- weight prep: [K][N] fp32 -> [Npad][K] fp16 / bf16 hi+lo ----
template<int MODE>
__global__ __launch_bounds__(256)
void k_prep(const float* __restrict__ src, ushort* __restrict__ dh,
            ushort* __restrict__ dl, int K, int N, int Npad, long zStride){
  __shared__ float tile[32][33];
  int z = blockIdx.z;
  src += (size_t)z*K*N;
  dh  += (size_t)z*zStride;
  if (MODE) dl += (size_t)z*zStride;
  int n0 = blockIdx.x*32, k0 = blockIdx.y*32;
  int tx = threadIdx.x&31, ty = threadIdx.x>>5;
#pragma unroll
  for (int i=0;i<4;i++){
    int kk = k0 + ty + i*8, nn = n0 + tx;
    tile[ty+i*8][tx] = (nn < N) ? src[(size_t)kk*N + nn] : 0.f;
  }
  __syncthreads();
#pragma unroll
  for (int i=0;i<4;i++){
    int nn = n0 + ty + i*8, kk = k0 + tx;
    float v = tile[tx][ty+i*8];
    if (MODE==0){
      dh[(size_t)nn*K + kk] = f2h(v);
    } else {
      ushort h = f2b(v);
      dh[(size_t)nn*K + kk] = h;
      float fh = __uint_as_float((uint)h<<16);
      dl[(size_t)nn*K + kk] = f2b(v - fh);
    }
  }
}

// ---------------- V transpose: fp32 [b][key][cols] -> fp16 [b][h][64][NK] ----
// (still used for xl memory V at startup)
__global__ __launch_bounds__(256)
void k_vtrans(const float* __restrict__ src, ushort* __restrict__ dst,
              long sB, int sR, int sMH, long dB, long dH, int NK){
  __shared__ float tile[64][65];
  int kc = blockIdx.x, h = blockIdx.y, b = blockIdx.z;
  int t = threadIdx.x;
  int key = t>>2, doff = (t&3)*16;
  const float* sp = src + (size_t)b*sB + (size_t)(kc*64+key)*sR + (sMH? h*64:0) + doff;
#pragma unroll
  for (int u=0;u<4;u++){
    float4 v = *reinterpret_cast<const float4*>(sp + u*4);
    tile[key][doff+u*4+0]=v.x; tile[key][doff+u*4+1]=v.y;
    tile[key][doff+u*4+2]=v.z; tile[key][doff+u*4+3]=v.w;
  }
  __syncthreads();
  int d = t>>2, kf = (t&3)*16;
  ushort* dp = dst + (size_t)b*dB + (size_t)h*dH + (size_t)d*NK + kc*64 + kf;
  ushort tmp[16];
#pragma unroll
  for (int u=0;u<16;u++) tmp[u] = f2h(tile[kf+u][d]);
  uint4 o0 = make_uint4((uint)tmp[0]|((uint)tmp[1]<<16), (uint)tmp[2]|((uint)tmp[3]<<16),
                        (uint)tmp[4]|((uint)tmp[5]<<16), (uint)tmp[6]|((uint)tmp[7]<<16));
  uint4 o1 = make_uint4((uint)tmp[8]|((uint)tmp[9]<<16), (uint)tmp[10]|((uint)tmp[11]<<16),
                        (uint)tmp[12]|((uint)tmp[13]<<16),(uint)tmp[14]|((uint)tmp[15]<<16));
  *reinterpret_cast<uint4*>(dp)   = o0;
  *reinterpret_cast<uint4*>(dp+8) = o1;
}

// fp16 -> fp16 transpose (for skv16 V half)
__global__ __launch_bounds__(256)
void k_vtrans16(const ushort* __restrict__ src, ushort* __restrict__ dst,
                long sB, int sR, long dB, int NK){
  __shared__ ushort tile[64][72];
  int kc = blockIdx.x, b = blockIdx.z;
  int t = threadIdx.x;
  int key = t>>2, doff = (t&3)*16;
  const ushort* sp = src + (size_t)b*sB + (size_t)(kc*64+key)*sR + doff;
  *reinterpret_cast<uint4*>(&tile[key][doff])   = *reinterpret_cast<const uint4*>(sp);
  *reinterpret_cast<uint4*>(&tile[key][doff+8]) = *reinterpret_cast<const uint4*>(sp+8);
  __syncthreads();
  int d = t>>2, kf = (t&3)*16;
  ushort* dp = dst + (size_t)b*dB + (size_t)d*NK + kc*64 + kf;
  ushort tmp[16];
#pragma unroll
  for (int u=0;u<16;u++) tmp[u] = tile[kf+u][d];
  uint4 o0 = make_uint4((uint)tmp[0]|((uint)tmp[1]<<16), (uint)tmp[2]|((uint)tmp[3]<<16),
                        (uint)tmp[4]|((uint)tmp[5]<<16), (uint)tmp[6]|((uint)tmp[7]<<16));
  uint4 o1 = make_uint4((uint)tmp[8]|((uint)tmp[9]<<16), (uint)tmp[10]|((uint)tmp[11]<<16),
                        (uint)tmp[12]|((uint)tmp[13]<<16),(uint)tmp[14]|((uint)tmp[15]<<16));
  *reinterpret_cast<uint4*>(dp)   = o0;
  *reinterpret_cast<uint4*>(dp+8) = o1;
}

// fp32 -> fp16 elementwise (pairs): converts 2*n2 floats total
__global__ void k_cvt(ushort* __restrict__ dst, const float* __restrict__ src, int n2){
  int idx = blockIdx.x*blockDim.x + threadIdx.x;
  if (idx >= n2) return;
  reinterpret_cast<uint*>(dst)[idx] = pkh2(src[2*idx], src[2*idx+1]);
}

// ---------------- embed / postable ----------------
__global__ void k_embed(const int* __restrict__ x, const float* __restrict__ emb,
                        float* __restrict__ h, int total4){
  int idx = blockIdx.x*blockDim.x + threadIdx.x;
  if (idx >= total4) return;
  int row = idx >> 7;
  int c4  = idx & 127;
  int tok = x[row];
  reinterpret_cast<float4*>(h)[idx] =
      reinterpret_cast<const float4*>(emb)[(size_t)tok*128 + c4];
}

__global__ void k_postable(const float* __restrict__ w1, const float* __restrict__ b1,
                           const float* __restrict__ w2, const float* __restrict__ b2,
                           const float* __restrict__ w3, const float* __restrict__ b3,
                           float* __restrict__ table){
  __shared__ float h1[128];
  __shared__ float h2[128];
  int d = blockIdx.x, t = threadIdx.x;
  float a = (float)d * w1[t] + b1[t];
  h1[t] = a / (1.f + __expf(-a));
  __syncthreads();
  float acc = b2[t];
  for (int p=0;p<128;p++) acc += h1[p]*w2[p*128+t];
  h2[t] = acc / (1.f + __expf(-acc));
  __syncthreads();
  if (t < 8){
    float acc2 = b3[t];
    for (int p=0;p<128;p++) acc2 += h2[p]*w3[p*8+t];
    table[d*8+t] = acc2;
  }
}

// ---------------- layernorm: fp16 out and/or bf16 hi/lo out ----------------
__global__ void k_ln(const float* __restrict__ x, const float* __restrict__ g,
                     ushort* __restrict__ y16,
                     ushort* __restrict__ yh, ushort* __restrict__ yl){
  int row = blockIdx.x;
  int t = threadIdx.x;
  float2 v = reinterpret_cast<const float2*>(x + (size_t)row*512)[t];
  float s = v.x+v.y, ss = v.x*v.x+v.y*v.y;
  for (int o=32;o;o>>=1){ s += __shfl_down(s,o); ss += __shfl_down(ss,o); }
  __shared__ float ls[4], lss[4];
  __shared__ float smu, srs;
  int wid = t>>6;
  if ((t&63)==0){ ls[wid]=s; lss[wid]=ss; }
  __syncthreads();
  if (t==0){
    float S=ls[0]+ls[1]+ls[2]+ls[3], SS=lss[0]+lss[1]+lss[2]+lss[3];
    float mu = S*(1.f/512.f);
    float var = SS*(1.f/512.f) - mu*mu;
    smu = mu; srs = rsqrtf(var + 1e-5f);
  }
  __syncthreads();
  float mu=smu, rs=srs;
  float2 gg = reinterpret_cast<const float2*>(g)[t];
  float ya = (v.x-mu)*rs*gg.x, yb = (v.y-mu)*rs*gg.y;
  size_t o2 = (size_t)row*512 + 2*t;
  if (y16)
    *reinterpret_cast<uint*>(&y16[o2]) = pkh2(ya, yb);
  if (yh){
    ushort ha = f2b(ya), hb = f2b(yb);
    *reinterpret_cast<uint*>(&yh[o2]) = (uint)ha | ((uint)hb<<16);
    float fa = __uint_as_float((uint)ha<<16), fb = __uint_as_float((uint)hb<<16);
    *reinterpret_cast<uint*>(&yl[o2]) = (uint)f2b(ya-fa) | ((uint)f2b(yb-fb)<<16);
  }
}

// qk rmsnorm in place (fp32) + fp16 emit
__global__ void k_qkrms16(float* __restrict__ q, float* __restrict__ k,
                          ushort* __restrict__ q16, ushort* __restrict__ k16,
                          const float* __restrict__ qs, const float* __restrict__ ks){
  int row = blockIdx.x;
  int h = threadIdx.x >> 6, d = threadIdx.x & 63;
  size_t base = (size_t)row*512 + h*64 + d;
  float qv = q[base];
  float s = qv*qv;
  for (int o=32;o;o>>=1) s += __shfl_xor(s,o);
  float qn = qv*rsqrtf(s+1e-12f)*qs[d];
  q[base] = qn; q16[base] = f2h(qn);
  float kv = k[base];
  float s2 = kv*kv;
  for (int o=32;o;o>>=1) s2 += __shfl_xor(s2,o);
  float kn = kv*rsqrtf(s2+1e-12f)*ks[d];
  k[base] = kn; k16[base] = f2h(kn);
}

__device__ __forceinline__ float geluf(float x){
  float u = 1.5957691216f*(x + 0.044715f*x*x*x);
  return x / (1.f + __expf(-u));
}

// ---------------- fp16 MFMA GEMM 128x128: C[M,N] (+)= A@Bt^T ----------------
template<int ACC, int EPI, int OUT16>
__global__ __launch_bounds__(256)
void k_gemmh(const ushort* __restrict__ A, const ushort* __restrict__ Bt,
             const float* __restrict__ bias, float* __restrict__ C,
             ushort* __restrict__ C16, int M, int N, int K){
  __shared__ ushort As[128][68];
  __shared__ ushort Bs[128][68];
  const int t = threadIdx.x;
  const int m0 = blockIdx.x*128, n0 = blockIdx.y*128;
  const int w = t>>6, lane = t&63;
  const int wm = (w>>1)*64, wn = (w&1)*64;
  const int fr = lane&15, fg = lane>>4;
  const int srow = t>>1, sko = (t&1)*32;

  f32x4 acc[4][4];
#pragma unroll
  for (int i=0;i<4;i++)
#pragma unroll
    for (int j=0;j<4;j++){ acc[i][j][0]=0.f; acc[i][j][1]=0.f; acc[i][j][2]=0.f; acc[i][j][3]=0.f; }

  const ushort* ap = A  + (size_t)(m0+srow)*K + sko;
  const ushort* bp = Bt + (size_t)(n0+srow)*K + sko;

  for (int k0=0; k0<K; k0+=64){
    uint4 av[4], bv[4];
#pragma unroll
    for (int u=0;u<4;u++){
      av[u] = *reinterpret_cast<const uint4*>(ap + k0 + u*8);
      bv[u] = *reinterpret_cast<const uint4*>(bp + k0 + u*8);
    }
#pragma unroll
    for (int u=0;u<4;u++){
      *reinterpret_cast<uint4*>(&As[srow][sko+u*8]) = av[u];
      *reinterpret_cast<uint4*>(&Bs[srow][sko+u*8]) = bv[u];
    }
    __syncthreads();
#pragma unroll
    for (int kk=0;kk<2;kk++){
      f16x8 af[4], bf[4];
#pragma unroll
      for (int mi=0;mi<4;mi++)
        af[mi] = *reinterpret_cast<const f16x8*>(&As[wm+mi*16+fr][kk*32+fg*8]);
#pragma unroll
      for (int nj=0;nj<4;nj++)
        bf[nj] = *reinterpret_cast<const f16x8*>(&Bs[wn+nj*16+fr][kk*32+fg*8]);
#pragma unroll
      for (int mi=0;mi<4;mi++)
#pragma unroll
        for (int nj=0;nj<4;nj++)
          acc[mi][nj] = __builtin_amdgcn_mfma_f32_16x16x32_f16(af[mi], bf[nj], acc[mi][nj], 0,0,0);
    }
    __syncthreads();
  }
#pragma unroll
  for (int mi=0;mi<4;mi++){
#pragma unroll
    for (int r=0;r<4;r++){
      int row = m0 + wm + mi*16 + fg*4 + r;
#pragma unroll
      for (int nj=0;nj<4;nj++){
        int col = n0 + wn + nj*16 + fr;
        if (col < N){
          float val = acc[mi][nj][r];
          if (bias) val += bias[col];
          if (EPI==1) val = geluf(val);
          if (OUT16){
            C16[(size_t)row*N + col] = f2h(val);
          } else {
            if (ACC) C[(size_t)row*N + col] += val; else C[(size_t)row*N + col] = val;
          }
        }
      }
    }
  }
}

// ---------------- fp16 MFMA GEMM 64x128 (full-grid, N=512 class) ------------
// 4 waves 2x2, each wave 32x64 (2x4 frags). Grid (M/64, ceil(N/128)).
// EPI: 0 none, 1 gelu, 2 ema (bias=beta; C = dec*C + (1-dec)*val).
// VT=1: additionally write fp16 transposed copy to vT [b][h][64][1024]
// (requires M rows = [b][1024] tokens, N=512 = 8 heads x 64).
template<int ACC, int EPI, int OUT16, int VT>
__global__ __launch_bounds__(256)
void k_gemmh64(const ushort* __restrict__ A, const ushort* __restrict__ Bt,
               const float* __restrict__ bias, float* __restrict__ C,
               ushort* __restrict__ C16, ushort* __restrict__ vT,
               int M, int N, int K){
  __shared__ ushort As[64][68];
  __shared__ ushort Bs[128][68];
  const int t = threadIdx.x;
  const int m0 = blockIdx.x*64, n0 = blockIdx.y*128;
  const int w = t>>6, lane = t&63;
  const int wm = (w>>1)*32, wn = (w&1)*64;
  const int fr = lane&15, fg = lane>>4;
  const int srowA = t>>2, skoA = (t&3)*16;
  const int srowB = t>>1, skoB = (t&1)*32;

  f32x4 acc[2][4];
#pragma unroll
  for (int i=0;i<2;i++)
#pragma unroll
    for (int j=0;j<4;j++){ acc[i][j][0]=0.f; acc[i][j][1]=0.f; acc[i][j][2]=0.f; acc[i][j][3]=0.f; }

  const ushort* ap = A  + (size_t)(m0+srowA)*K + skoA;
  const ushort* bp = Bt + (size_t)(n0+srowB)*K + skoB;

  for (int k0=0; k0<K; k0+=64){
    uint4 a0 = *reinterpret_cast<const uint4*>(ap + k0);
    uint4 a1 = *reinterpret_cast<const uint4*>(ap + k0 + 8);
    uint4 b0 = *reinterpret_cast<const uint4*>(bp + k0);
    uint4 b1 = *reinterpret_cast<const uint4*>(bp + k0 + 8);
    uint4 b2 = *reinterpret_cast<const uint4*>(bp + k0 + 16);
    uint4 b3 = *reinterpret_cast<const uint4*>(bp + k0 + 24);
    *reinterpret_cast<uint4*>(&As[srowA][skoA])    = a0;
    *reinterpret_cast<uint4*>(&As[srowA][skoA+8])  = a1;
    *reinterpret_cast<uint4*>(&Bs[srowB][skoB])    = b0;
    *reinterpret_cast<uint4*>(&Bs[srowB][skoB+8])  = b1;
    *reinterpret_cast<uint4*>(&Bs[srowB][skoB+16]) = b2;
    *reinterpret_cast<uint4*>(&Bs[srowB][skoB+24]) = b3;
    __syncthreads();
#pragma unroll
    for (int kk=0;kk<2;kk++){
      f16x8 af[2], bf[4];
#pragma unroll
      for (int mi=0;mi<2;mi++)
        af[mi] = *reinterpret_cast<const f16x8*>(&As[wm+mi*16+fr][kk*32+fg*8]);
#pragma unroll
      for (int nj=0;nj<4;nj++)
        bf[nj] = *reinterpret_cast<const f16x8*>(&Bs[wn+nj*16+fr][kk*32+fg*8]);
#pragma unroll
      for (int mi=0;mi<2;mi++)
#pragma unroll
        for (int nj=0;nj<4;nj++)
          acc[mi][nj] = __builtin_amdgcn_mfma_f32_16x16x32_f16(af[mi], bf[nj], acc[mi][nj], 0,0,0);
    }
    __syncthreads();
  }
#pragma unroll
  for (int mi=0;mi<2;mi++){
#pragma unroll
    for (int r=0;r<4;r++){
      int row = m0 + wm + mi*16 + fg*4 + r;
#pragma unroll
      for (int nj=0;nj<4;nj++){
        int col = n0 + wn + nj*16 + fr;
        if (col < N){
          float val = acc[mi][nj][r];
          if (EPI==2){
            size_t idx = (size_t)row*N + col;
            float old = C[idx];
            float dec = 1.f/(1.f+__expf(-bias[col]));
            C[idx] = dec*old + (1.f-dec)*val;
          } else {
            if (bias) val += bias[col];
            if (EPI==1) val = geluf(val);
            if (OUT16){
              C16[(size_t)row*N + col] = f2h(val);
            } else {
              if (ACC) C[(size_t)row*N + col] += val; else C[(size_t)row*N + col] = val;
            }
          }
        }
      }
    }
  }
  if (VT){
    // transpose 64x128 tile via Bs (done with MFMA reads) -> vT [b][h][64][1024]
#pragma unroll
    for (int mi=0;mi<2;mi++)
#pragma unroll
      for (int r=0;r<4;r++)
#pragma unroll
        for (int nj=0;nj<4;nj++)
          Bs[wn+nj*16+fr][wm+mi*16+fg*4+r] = f2h(acc[mi][nj][r]);
    __syncthreads();
    int c = t>>1, half = t&1;
    int hh = (n0+c)>>6, dd = (n0+c)&63;
    int bb = m0>>10, posb = m0&1023;
    ushort* dp = vT + (size_t)bb*524288 + (size_t)hh*65536 + (size_t)dd*1024 + posb + half*32;
#pragma unroll
    for (int u=0;u<4;u++)
      *reinterpret_cast<uint4*>(dp + u*8) = *reinterpret_cast<const uint4*>(&Bs[c][half*32 + u*8]);
  }
}

// ---------------- split-bf16 MFMA GEMM (pre-split A; optional row remap) ------
template<int REMAP>
__global__ __launch_bounds__(256)
void k_gemm_sp(const ushort* __restrict__ Ah, const ushort* __restrict__ Al,
               const ushort* __restrict__ Bh, const ushort* __restrict__ Bl,
               float* __restrict__ C1, ushort* __restrict__ C1h, int ld1, int N1,
               float* __restrict__ C2, ushort* __restrict__ C2h, int ld2,
               int nb, int M, int N, int K){
  __shared__ ushort As[2][128][36];
  __shared__ ushort Bs[2][128][36];
  const int t = threadIdx.x;
  const int m0 = blockIdx.x*128, n0 = blockIdx.y*128;
  const int w = t>>6, lane = t&63;
  const int wm = (w>>1)*64, wn = (w&1)*64;
  const int fr = lane&15, fg = lane>>4;
  const int srow = t>>1, sko = (t&1)*16;

  f32x4 acc[4][4];
#pragma unroll
  for (int i=0;i<4;i++)
#pragma unroll
    for (int j=0;j<4;j++){ acc[i][j][0]=0.f; acc[i][j][1]=0.f; acc[i][j][2]=0.f; acc[i][j][3]=0.f; }

  int mrow = m0 + srow;
  int arow = REMAP ? ((mrow>>9)*1024 + nb*512 + (mrow&511)) : mrow;
  const ushort* aph = Ah + (size_t)arow*K + sko;
  const ushort* apl = Al + (size_t)arow*K + sko;
  const ushort* bph = Bh + (size_t)(n0+srow)*K + sko;
  const ushort* bpl = Bl + (size_t)(n0+srow)*K + sko;

  for (int k0=0; k0<K; k0+=32){
    uint4 a0 = *reinterpret_cast<const uint4*>(aph + k0);
    uint4 a1 = *reinterpret_cast<const uint4*>(aph + k0 + 8);
    uint4 al0 = *reinterpret_cast<const uint4*>(apl + k0);
    uint4 al1 = *reinterpret_cast<const uint4*>(apl + k0 + 8);
    uint4 b0 = *reinterpret_cast<const uint4*>(bph + k0);
    uint4 b1 = *reinterpret_cast<const uint4*>(bph + k0 + 8);
    uint4 bl0 = *reinterpret_cast<const uint4*>(bpl + k0);
    uint4 bl1 = *reinterpret_cast<const uint4*>(bpl + k0 + 8);
    *reinterpret_cast<uint4*>(&As[0][srow][sko])   = a0;
    *reinterpret_cast<uint4*>(&As[0][srow][sko+8]) = a1;
    *reinterpret_cast<uint4*>(&As[1][srow][sko])   = al0;
    *reinterpret_cast<uint4*>(&As[1][srow][sko+8]) = al1;
    *reinterpret_cast<uint4*>(&Bs[0][srow][sko])   = b0;
    *reinterpret_cast<uint4*>(&Bs[0][srow][sko+8]) = b1;
    *reinterpret_cast<uint4*>(&Bs[1][srow][sko])   = bl0;
    *reinterpret_cast<uint4*>(&Bs[1][srow][sko+8]) = bl1;
    __syncthreads();

    bf16x8 ah[4], al[4], bh[4], bl[4];
#pragma unroll
    for (int mi=0;mi<4;mi++){
      ah[mi] = *reinterpret_cast<const bf16x8*>(&As[0][wm+mi*16+fr][fg*8]);
      al[mi] = *reinterpret_cast<const bf16x8*>(&As[1][wm+mi*16+fr][fg*8]);
    }
#pragma unroll
    for (int nj=0;nj<4;nj++){
      bh[nj] = *reinterpret_cast<const bf16x8*>(&Bs[0][wn+nj*16+fr][fg*8]);
      bl[nj] = *reinterpret_cast<const bf16x8*>(&Bs[1][wn+nj*16+fr][fg*8]);
    }
#pragma unroll
    for (int mi=0;mi<4;mi++)
#pragma unroll
      for (int nj=0;nj<4;nj++){
        acc[mi][nj] = __builtin_amdgcn_mfma_f32_16x16x32_bf16(ah[mi], bh[nj], acc[mi][nj], 0,0,0);
        acc[mi][nj] = __builtin_amdgcn_mfma_f32_16x16x32_bf16(al[mi], bh[nj], acc[mi][nj], 0,0,0);
        acc[mi][nj] = __builtin_amdgcn_mfma_f32_16x16x32_bf16(ah[mi], bl[nj], acc[mi][nj], 0,0,0);
      }
    __syncthreads();
  }
#pragma unroll
  for (int mi=0;mi<4;mi++){
#pragma unroll
    for (int r=0;r<4;r++){
      int row = m0 + wm + mi*16 + fg*4 + r;
#pragma unroll
      for (int nj=0;nj<4;nj++){
        int col = n0 + wn + nj*16 + fr;
        float val = acc[mi][nj][r];
        if (col < N1){
          if (C1)  C1[(size_t)row*ld1 + col] = val;
          if (C1h) C1h[(size_t)row*ld1 + col] = f2h(val);
        } else if (col < N){
          if (C2)  C2[(size_t)row*ld2 + (col-N1)] = val;
          if (C2h) C2h[(size_t)row*ld2 + (col-N1)] = f2h(val);
        }
      }
    }
  }
}

// ---------------- merged windowed MFMA flash attention -----------------------
// grid (16, H, B): blockIdx.x = nb*8 + qt. Covers both token blocks per launch.
__global__ __launch_bounds__(256)
void k_attn_win(const ushort* __restrict__ q16, const ushort* __restrict__ k16,
                const ushort* __restrict__ vTb,
                const ushort* __restrict__ xlK, const ushort* __restrict__ xlVT,
                int isxl, ushort* __restrict__ O, float scale,
                const float* __restrict__ table){
  __shared__ ushort Qs[64][72];
  __shared__ ushort Ks[64][72];
  __shared__ ushort Vs[64][72];
  __shared__ ushort Pw[4][16][72];
  __shared__ float tcol[512];
  const int b = blockIdx.z, h = blockIdx.y;
  const int nb = blockIdx.x>>3, qt = blockIdx.x&7;
  const int t = threadIdx.x, w = t>>6, lane = t&63;
  const int fr = lane&15, fg = lane>>4;
  tcol[t]     = table[t*8 + h];
  tcol[t+256] = table[(t+256)*8 + h];

  const ushort* Q  = q16 + (size_t)nb*262144;
  const ushort* K1 = k16 + (size_t)nb*262144;
  const ushort* V1 = vTb + (size_t)nb*512;       // column offset in [1024]-wide vT
  ushort* Op = O + (size_t)nb*262144;
  const int has_mem = (nb==1) || isxl;
  const ushort* K0; long k0B; const ushort* V0; long vt0B, vt0H; int vt0D;
  if (nb==1){ K0=k16; k0B=524288; V0=vTb; vt0B=524288; vt0H=65536; vt0D=1024; }
  else if (isxl){ K0=xlK; k0B=262144; V0=xlVT; vt0B=262144; vt0H=32768; vt0D=512; }
  else { K0=k16; k0B=524288; V0=vTb; vt0B=524288; vt0H=65536; vt0D=1024; }  // masked

  {
    int qrow = t>>2, doff = (t&3)*16;
    const ushort* qp = Q + (size_t)b*524288 + (size_t)(qt*64+qrow)*512 + h*64 + doff;
    *reinterpret_cast<uint4*>(&Qs[qrow][doff])   = *reinterpret_cast<const uint4*>(qp);
    *reinterpret_cast<uint4*>(&Qs[qrow][doff+8]) = *reinterpret_cast<const uint4*>(qp+8);
  }
  __syncthreads();
  f16x8 aq[2];
  aq[0] = *reinterpret_cast<const f16x8*>(&Qs[w*16+fr][fg*8]);
  aq[1] = *reinterpret_cast<const f16x8*>(&Qs[w*16+fr][32+fg*8]);

  f32x4 so[4];
#pragma unroll
  for (int dt=0;dt<4;dt++){ so[dt][0]=0.f; so[dt][1]=0.f; so[dt][2]=0.f; so[dt][3]=0.f; }
  float m[4] = {-1e30f,-1e30f,-1e30f,-1e30f};
  float lsum[4] = {0.f,0.f,0.f,0.f};

  const int srow = t>>2, sdo = (t&3)*16;
  const int vd = t>>2,   vkf = (t&3)*16;

  int jt0 = has_mem ? qt : 8;
  int jt1 = qt + 8; if (jt1 > 15) jt1 = 15;

  for (int jt=jt0; jt<=jt1; jt++){
    {
      int key = jt*64 + srow;
      const ushort* kp;
      if (key < 512) kp = K0 + (size_t)b*k0B + (size_t)key*512 + h*64 + sdo;
      else           kp = K1 + (size_t)b*524288 + (size_t)(key-512)*512 + h*64 + sdo;
      *reinterpret_cast<uint4*>(&Ks[srow][sdo])   = *reinterpret_cast<const uint4*>(kp);
      *reinterpret_cast<uint4*>(&Ks[srow][sdo+8]) = *reinterpret_cast<const uint4*>(kp+8);
    }
    {
      const ushort* vp;
      if (jt*64 < 512) vp = V0 + (size_t)b*vt0B + (size_t)h*vt0H + (size_t)vd*vt0D + jt*64 + vkf;
      else             vp = V1 + (size_t)b*524288 + (size_t)h*65536 + (size_t)vd*1024 + (jt*64-512) + vkf;
      *reinterpret_cast<uint4*>(&Vs[vd][vkf])   = *reinterpret_cast<const uint4*>(vp);
      *reinterpret_cast<uint4*>(&Vs[vd][vkf+8]) = *reinterpret_cast<const uint4*>(vp+8);
    }
    __syncthreads();
    f32x4 sacc[4];
#pragma unroll
    for (int kt=0;kt<4;kt++){ sacc[kt][0]=0.f; sacc[kt][1]=0.f; sacc[kt][2]=0.f; sacc[kt][3]=0.f; }
#pragma unroll
    for (int ks=0;ks<2;ks++){
#pragma unroll
      for (int kt=0;kt<4;kt++){
        f16x8 bf = *reinterpret_cast<const f16x8*>(&Ks[kt*16+fr][ks*32+fg*8]);
        sacc[kt] = __builtin_amdgcn_mfma_f32_16x16x32_f16(aq[ks], bf, sacc[kt], 0,0,0);
      }
    }
#pragma unroll
    for (int r=0;r<4;r++){
      float sv[4];
      int ia = qt*64 + w*16 + fg*4 + r;
#pragma unroll
      for (int kt=0;kt<4;kt++){
        float s = sacc[kt][r]*scale;
        int jg = jt*64 + kt*16 + fr;
        bool valid = (jg > ia) && (jg <= ia+512) && (has_mem || jg >= 512);
        sv[kt] = valid ? s + tcol[ia+512-jg] : -1e9f;
      }
      float tm = fmaxf(fmaxf(sv[0],sv[1]), fmaxf(sv[2],sv[3]));
      tm = fmaxf(tm, __shfl_xor(tm,1));
      tm = fmaxf(tm, __shfl_xor(tm,2));
      tm = fmaxf(tm, __shfl_xor(tm,4));
      tm = fmaxf(tm, __shfl_xor(tm,8));
      float mn = fmaxf(m[r], tm);
      float c = __expf(m[r]-mn);
      m[r] = mn;
      float ps = 0.f;
#pragma unroll
      for (int kt=0;kt<4;kt++){
        float pp = (sv[kt] <= -1e8f) ? 0.f : __expf(sv[kt]-mn);
        ps += pp;
        Pw[w][fg*4+r][kt*16+fr] = f2h(pp);
      }
      ps += __shfl_xor(ps,1);
      ps += __shfl_xor(ps,2);
      ps += __shfl_xor(ps,4);
      ps += __shfl_xor(ps,8);
      lsum[r] = lsum[r]*c + ps;
#pragma unroll
      for (int dt=0;dt<4;dt++) so[dt][r] *= c;
    }
#pragma unroll
    for (int ks=0;ks<2;ks++){
      f16x8 pa = *reinterpret_cast<const f16x8*>(&Pw[w][fr][ks*32+fg*8]);
#pragma unroll
      for (int dt=0;dt<4;dt++){
        f16x8 bv = *reinterpret_cast<const f16x8*>(&Vs[dt*16+fr][ks*32+fg*8]);
        so[dt] = __builtin_amdgcn_mfma_f32_16x16x32_f16(pa, bv, so[dt], 0,0,0);
      }
    }
    __syncthreads();
  }
#pragma unroll
  for (int r=0;r<4;r++){
    int row = qt*64 + w*16 + fg*4 + r;
    float inv = 1.f / lsum[r];
    ushort* op = Op + (size_t)b*524288 + (size_t)row*512 + h*64;
#pragma unroll
    for (int dt=0;dt<4;dt++)
      op[dt*16+fr] = f2h(so[dt][r]*inv);
  }
}

// ---------------- generic (rec) MFMA flash attention, plain softmax ----------
__global__ __launch_bounds__(256)
void k_attn_plain(const ushort* __restrict__ Q, long qB,
                  const ushort* __restrict__ K0, long k0B, int k0R, int k0H,
                  const ushort* __restrict__ K1, long k1B, int k1R, int k1H,
                  const ushort* __restrict__ VT0, long vt0B, long vt0H, int vt0D,
                  const ushort* __restrict__ VT1, long vt1B, long vt1H, int vt1D,
                  int n0, int n1,
                  ushort* __restrict__ O, long oB, float scale){
  __shared__ ushort Qs[64][72];
  __shared__ ushort Ks[64][72];
  __shared__ ushort Vs[64][72];
  __shared__ ushort Pw[4][16][72];
  const int b = blockIdx.z, h = blockIdx.y, qt = blockIdx.x;
  const int t = threadIdx.x, w = t>>6, lane = t&63;
  const int fr = lane&15, fg = lane>>4;
  {
    int qrow = t>>2, doff = (t&3)*16;
    const ushort* qp = Q + (size_t)b*qB + (size_t)(qt*64+qrow)*512 + h*64 + doff;
    *reinterpret_cast<uint4*>(&Qs[qrow][doff])   = *reinterpret_cast<const uint4*>(qp);
    *reinterpret_cast<uint4*>(&Qs[qrow][doff+8]) = *reinterpret_cast<const uint4*>(qp+8);
  }
  __syncthreads();
  f16x8 aq[2];
  aq[0] = *reinterpret_cast<const f16x8*>(&Qs[w*16+fr][fg*8]);
  aq[1] = *reinterpret_cast<const f16x8*>(&Qs[w*16+fr][32+fg*8]);

  f32x4 so[4];
#pragma unroll
  for (int dt=0;dt<4;dt++){ so[dt][0]=0.f; so[dt][1]=0.f; so[dt][2]=0.f; so[dt][3]=0.f; }
  float m[4] = {-1e30f,-1e30f,-1e30f,-1e30f};
  float lsum[4] = {0.f,0.f,0.f,0.f};

  const int nt = (n0+n1)>>6;
  const int srow = t>>2, sdo = (t&3)*16;
  const int vd = t>>2,   vkf = (t&3)*16;

  for (int jt=0; jt<nt; jt++){
    {
      int key = jt*64 + srow;
      const ushort* kp;
      if (key < n0) kp = K0 + (size_t)b*k0B + (size_t)key*k0R + (k0H? h*64:0) + sdo;
      else          kp = K1 + (size_t)b*k1B + (size_t)(key-n0)*k1R + (k1H? h*64:0) + sdo;
      *reinterpret_cast<uint4*>(&Ks[srow][sdo])   = *reinterpret_cast<const uint4*>(kp);
      *reinterpret_cast<uint4*>(&Ks[srow][sdo+8]) = *reinterpret_cast<const uint4*>(kp+8);
    }
    {
      const ushort* vp;
      if (jt*64 < n0) vp = VT0 + (size_t)b*vt0B + (size_t)h*vt0H + (size_t)vd*vt0D + jt*64 + vkf;
      else            vp = VT1 + (size_t)b*vt1B + (size_t)h*vt1H + (size_t)vd*vt1D + (jt*64-n0) + vkf;
      *reinterpret_cast<uint4*>(&Vs[vd][vkf])   = *reinterpret_cast<const uint4*>(vp);
      *reinterpret_cast<uint4*>(&Vs[vd][vkf+8]) = *reinterpret_cast<const uint4*>(vp+8);
    }
    __syncthreads();
    f32x4 sacc[4];
#pragma unroll
    for (int kt=0;kt<4;kt++){ sacc[kt][0]=0.f; sacc[kt][1]=0.f; sacc[kt][2]=0.f; sacc[kt][3]=0.f; }
#pragma unroll
    for (int ks=0;ks<2;ks++){
#pragma unroll
      for (int kt=0;kt<4;kt++){
        f16x8 bf = *reinterpret_cast<const f16x8*>(&Ks[kt*16+fr][ks*32+fg*8]);
        sacc[kt] = __builtin_amdgcn_mfma_f32_16x16x32_f16(aq[ks], bf, sacc[kt], 0,0,0);
      }
    }
#pragma unroll
    for (int r=0;r<4;r++){
      float sv[4];
#pragma unroll
      for (int kt=0;kt<4;kt++) sv[kt] = sacc[kt][r]*scale;
      float tm = fmaxf(fmaxf(sv[0],sv[1]), fmaxf(sv[2],sv[3]));
      tm = fmaxf(tm, __shfl_xor(tm,1));
      tm = fmaxf(tm, __shfl_xor(tm,2));
      tm = fmaxf(tm, __shfl_xor(tm,4));
      tm = fmaxf(tm, __shfl_xor(tm,8));
      float mn = fmaxf(m[r], tm);
      float c = __expf(m[r]-mn);
      m[r] = mn;
      float ps = 0.f;
#pragma unroll
      for (int kt=0;kt<4;kt++){
        float pp = __expf(sv[kt]-mn);
        ps += pp;
        Pw[w][fg*4+r][kt*16+fr] = f2h(pp);
      }
      ps += __shfl_xor(ps,1);
      ps += __shfl_xor(ps,2);
      ps += __shfl_xor(ps,4);
      ps += __shfl_xor(ps,8);
      lsum[r] = lsum[r]*c + ps;
#pragma unroll
      for (int dt=0;dt<4;dt++) so[dt][r] *= c;
    }
#pragma unroll
    for (int ks=0;ks<2;ks++){
      f16x8 pa = *reinterpret_cast<const f16x8*>(&Pw[w][fr][ks*32+fg*8]);
#pragma unroll
      for (int dt=0;dt<4;dt++){
        f16x8 bv = *reinterpret_cast<const f16x8*>(&Vs[dt*16+fr][ks*32+fg*8]);
        so[dt] = __builtin_amdgcn_mfma_f32_16x16x32_f16(pa, bv, so[dt], 0,0,0);
      }
    }
    __syncthreads();
  }
#pragma unroll
  for (int r=0;r<4;r++){
    int row = qt*64 + w*16 + fg*4 + r;
    float inv = 1.f / lsum[r];
    ushort* op = O + (size_t)b*oB + (size_t)row*512 + h*64;
#pragma unroll
    for (int dt=0;dt<4;dt++)
      op[dt*16+fr] = f2h(so[dt][r]*inv);
  }
}

// ---------------- small utility kernels ----------------
__global__ void k_copy(float* __restrict__ dst, const float* __restrict__ src, int n){
  int idx = blockIdx.x*blockDim.x + threadIdx.x;
  if (idx < n) dst[idx] = src[idx];
}
__global__ void k_xlout(float* __restrict__ dk, float* __restrict__ dv,
                        const float* __restrict__ k, const float* __restrict__ v){
  int idx = blockIdx.x*blockDim.x + threadIdx.x;
  if (idx >= 1048576) return;
  int b = idx >> 18, rem = idx & 262143;
  size_t s = (size_t)b*524288 + 262144 + rem;
  dk[idx] = k[s]; dv[idx] = v[s];
}

// ---------------- launcher ----------------
extern "C" void kernel_launch(void* const* d_in, const int* in_sizes, int n_in,
                              void* d_out, int out_size, void* d_ws, size_t ws_size,
                              hipStream_t stream){
  // floats 37,765,120 B + ushorts 122,814,464 B = 160,579,584 B
  if (ws_size < (size_t)160579584) return;

  const int*   x        = (const int*)  d_in[0];
  const float* tok_emb  = (const float*)d_in[1];
  const float* pw1 = (const float*)d_in[2];
  const float* pb1 = (const float*)d_in[3];
  const float* pw2 = (const float*)d_in[4];
  const float* pb2 = (const float*)d_in[5];
  const float* pw3 = (const float*)d_in[6];
  const float* pb3 = (const float*)d_in[7];
  const float* ln_g = (const float*)d_in[8];
  const float* Wq = (const float*)d_in[9];
  const float* Wk = (const float*)d_in[10];
  const float* Wv = (const float*)d_in[11];
  const float* Wo = (const float*)d_in[12];
  const float* q_scale = (const float*)d_in[13];
  const float* k_scale = (const float*)d_in[14];
  const float* Wo_state = (const float*)d_in[15];
  const float* state_norm_g = (const float*)d_in[16];
  const float* Wq2s = (const float*)d_in[17];
  const float* Ws2q = (const float*)d_in[18];
  const float* Ws2kv = (const float*)d_in[19];
  const float* W_state_out = (const float*)d_in[20];
  const float* ema_beta = (const float*)d_in[21];
  const float* ff_g = (const float*)d_in[22];
  const float* ff_w1 = (const float*)d_in[23];
  const float* ff_b1 = (const float*)d_in[24];
  const float* ff_w2 = (const float*)d_in[25];
  const float* ff_b2 = (const float*)d_in[26];
  const float* final_g = (const float*)d_in[27];
  const float* W_logits = (const float*)d_in[28];
  const float* xl_mem_k = (const float*)d_in[29];
  const float* xl_mem_v = (const float*)d_in[30];
  const float* states_in = (const float*)d_in[31];

  float* out = (float*)d_out;
  float* out_xlk    = out + 81920000;
  float* out_xlv    = out + 84017152;
  float* out_states = out + 86114304;

  float* p = (float*)d_ws;
  float* hstate   = p; p += 2097152;
  float* q        = p; p += 2097152;
  float* k        = p; p += 2097152;
  float* v        = p; p += 2097152;
  float* states_cur = p; p += 1048576;
  float* table    = p; p += 4096;

  ushort* us = (ushort*)p;
  ushort* wqkh  = us; us += 3145728;   // [6][1024][512]: rows 0-511 q, 512-1023 k
  ushort* wqkl  = us; us += 3145728;
  ushort* wvT   = us; us += 1572864;
  ushort* woT   = us; us += 1572864;
  ushort* ffw1T = us; us += 6291456;
  ushort* ffw2T = us; us += 6291456;
  ushort* wostT = us; us += 262144;
  ushort* wstoutT = us; us += 262144;
  ushort* wq2sh = us; us += 262144;
  ushort* wq2sl = us; us += 262144;
  ushort* wsqkvh = us; us += 327680;   // [640][512]: rows 0-511 Ws2q, 512-639 Ws2kv
  ushort* wsqkvl = us; us += 327680;
  ushort* wlogT  = us; us += 10289152; // [20096][512]
  ushort* vTb   = us; us += 2097152;   // [b][h][64][1024]
  ushort* xlvT  = us; us += 2097152;   // [2][b][h][64][512]
  ushort* svT   = us; us += 131072;    // [b][64][512]
  ushort* xn16  = us; us += 2097152;   // fp16 LN out
  ushort* ao16  = us; us += 2097152;   // attn out fp16
  ushort* ff1_16 = us; us += 8388608;  // [4096][2048] + rec aliases
  ushort* xnh   = us; us += 2097152;   // bf16 hi of attn-LN
  ushort* xnl   = us; us += 2097152;
  ushort* q16   = us; us += 2097152;
  ushort* k16   = us; us += 2097152;
  ushort* xlk16 = us; us += 2097152;   // [2][b][512][512] fp16
  // rec aliases inside ff1_16 (dead between FF uses)
  ushort* ts16   = ff1_16;             // [4096][512]
  ushort* sa16   = ff1_16 + 2097152;   // [2048][512]
  ushort* snh    = ff1_16 + 3145728;   // [2048][512]
  ushort* snl    = ff1_16 + 4194304;
  ushort* sq16   = ff1_16 + 5242880;
  ushort* q2s16  = ff1_16 + 6291456;
  ushort* skv16  = ff1_16 + 7340032;   // [2048][128]

  // ---- weight prep ----
  k_prep<1><<<dim3(16,16,6),256,0,stream>>>(Wq, wqkh, wqkl, 512,512,512, 524288);
  k_prep<1><<<dim3(16,16,6),256,0,stream>>>(Wk, wqkh+262144, wqkl+262144, 512,512,512, 524288);
  k_prep<0><<<dim3(16,16,6),256,0,stream>>>(Wv, wvT, nullptr, 512,512,512, 262144);
  k_prep<0><<<dim3(16,16,6),256,0,stream>>>(Wo, woT, nullptr, 512,512,512, 262144);
  k_prep<0><<<dim3(64,16,6),256,0,stream>>>(ff_w1, ffw1T, nullptr, 512,2048,2048, 1048576);
  k_prep<0><<<dim3(16,64,6),256,0,stream>>>(ff_w2, ffw2T, nullptr, 2048,512,512, 1048576);
  k_prep<0><<<dim3(16,16,1),256,0,stream>>>(Wo_state, wostT, nullptr, 512,512,512, 262144);
  k_prep<0><<<dim3(16,16,1),256,0,stream>>>(W_state_out, wstoutT, nullptr, 512,512,512, 262144);
  k_prep<1><<<dim3(16,16,1),256,0,stream>>>(Wq2s, wq2sh, wq2sl, 512,512,512, 262144);
  k_prep<1><<<dim3(16,16,1),256,0,stream>>>(Ws2q, wsqkvh, wsqkvl, 512,512,512, 327680);
  k_prep<1><<<dim3(4,16,1),256,0,stream>>>(Ws2kv, wsqkvh+262144, wsqkvl+262144, 512,128,128, 327680);
  k_prep<0><<<dim3(628,16,1),256,0,stream>>>(W_logits, wlogT, nullptr, 512,20000,20096, 10289152);

  for (int s=0;s<2;s++)
    k_vtrans<<<dim3(8,8,4),256,0,stream>>>(xl_mem_v + (size_t)s*1048576,
                                           xlvT + (size_t)s*1048576,
                                           262144L, 512, 1, 262144L, 32768L, 512);
  k_cvt<<<4096,256,0,stream>>>(xlk16, xl_mem_k, 1048576);

  k_embed<<<2048, 256, 0, stream>>>(x, tok_emb, hstate, 524288);
  k_postable<<<512, 128, 0, stream>>>(pw1,pb1,pw2,pb2,pw3,pb3, table);
  k_copy<<<4096, 256, 0, stream>>>(states_cur, states_in, 1048576);

  for (int l=0;l<6;l++){
    k_ln<<<4096,256,0,stream>>>(hstate, ln_g + l*512, xn16, xnh, xnl);
    float scale = 0.125f;
    if (l>=3){
      k_gemm_sp<0><<<dim3(32,8),256,0,stream>>>(xnh, xnl,
          wqkh + (size_t)l*524288, wqkl + (size_t)l*524288,
          q, nullptr, 512, 512, k, nullptr, 512, 0, 4096, 1024, 512);
      k_qkrms16<<<4096,512,0,stream>>>(q, k, q16, k16, q_scale + l*64, k_scale + l*64);
      scale = 8.f;
    } else {
      k_gemm_sp<0><<<dim3(32,8),256,0,stream>>>(xnh, xnl,
          wqkh + (size_t)l*524288, wqkl + (size_t)l*524288,
          nullptr, q16, 512, 512, nullptr, k16, 512, 0, 4096, 1024, 512);
    }
    // v GEMM + fused V^T emit
    k_gemmh64<0,0,0,1><<<dim3(64,4),256,0,stream>>>(xn16, wvT + (size_t)l*262144, nullptr, v, nullptr, vTb, 4096,512,512);

    bool isxl = (l==4 || l==5);
    int src = (l==4)? 1 : 0;     // roll(-1)
    k_attn_win<<<dim3(16,8,4),256,0,stream>>>(
        q16, k16, vTb,
        isxl ? xlk16 + (size_t)src*1048576 : k16,
        isxl ? xlvT  + (size_t)src*1048576 : vTb,
        isxl ? 1 : 0, ao16, scale, table);

    k_gemmh64<1,0,0,0><<<dim3(64,4),256,0,stream>>>(ao16, woT + (size_t)l*262144, nullptr, hstate, nullptr, nullptr, 4096,512,512);
    if (l==3){
      for (int nb=0;nb<2;nb++){
        k_ln<<<2048,256,0,stream>>>(states_cur, state_norm_g, nullptr, snh, snl);
        k_gemm_sp<0><<<dim3(16,5),256,0,stream>>>(snh, snl, wsqkvh, wsqkvl,
            nullptr, sq16, 512, 512, nullptr, skv16, 128, 0, 2048, 640, 512);
        k_vtrans16<<<dim3(8,1,4),256,0,stream>>>(skv16 + 64, svT, 65536L, 128, 32768L, 512);
        // q2s GEMM reads xnh/xnl directly via row remap (replaces gather)
        k_gemm_sp<1><<<dim3(16,4),256,0,stream>>>(xnh, xnl, wq2sh, wq2sl,
            nullptr, q2s16, 512, 512, nullptr, nullptr, 0, nb, 2048, 512, 512);
        k_attn_plain<<<dim3(8,8,4),256,0,stream>>>(
          q2s16, 262144L,
          skv16, 65536L, 128, 0,
          skv16, 65536L, 128, 0,
          svT, 32768L, 0L, 512,
          svT, 32768L, 0L, 512,
          512, 0,
          ts16 + nb*262144, 524288L, 0.125f);
        k_attn_plain<<<dim3(8,8,4),256,0,stream>>>(
          sq16, 262144L,
          skv16, 65536L, 128, 0,
          k16 + nb*262144, 524288L, 512, 1,
          svT, 32768L, 0L, 512,
          vTb + nb*512, 524288L, 65536L, 1024,
          512, 512,
          sa16, 262144L, 0.125f);
        // W_state_out GEMM with fused EMA update of states_cur
        k_gemmh64<0,2,0,0><<<dim3(32,4),256,0,stream>>>(sa16, wstoutT, ema_beta, states_cur, nullptr, nullptr, 2048,512,512);
      }
      k_gemmh64<1,0,0,0><<<dim3(64,4),256,0,stream>>>(ts16, wostT, nullptr, hstate, nullptr, nullptr, 4096,512,512);
    }
    if (isxl){
      int xli = l-4;
      k_xlout<<<4096,256,0,stream>>>(out_xlk + (size_t)xli*1048576,
                                     out_xlv + (size_t)xli*1048576, k, v);
    }
    k_ln<<<4096,256,0,stream>>>(hstate, ff_g + l*512, xn16, nullptr, nullptr);
    k_gemmh<0,1,1><<<dim3(32,16),256,0,stream>>>(xn16, ffw1T + (size_t)l*1048576, ff_b1 + l*2048, nullptr, ff1_16, 4096,2048,512);
    k_gemmh64<1,0,0,0><<<dim3(64,4),256,0,stream>>>(ff1_16, ffw2T + (size_t)l*1048576, ff_b2 + l*512, hstate, nullptr, nullptr, 4096,512,2048);
  }
  k_ln<<<4096,256,0,stream>>>(hstate, final_g, xn16, nullptr, nullptr);
  k_gemmh<0,0,0><<<dim3(32,157),256,0,stream>>>(xn16, wlogT, nullptr, out, nullptr, 4096,20000,512);
  k_copy<<<4096, 256, 0, stream>>>(out_states, states_cur, 1048576);
}

// Round 15
// 1628.414 us; speedup vs baseline: 7.7329x; 1.0612x over previous
//
#include <hip/hip_runtime.h>
#include <math.h>

// B=4 N=1024 V=20000 D=512 H=8 DH=64 W=512 NB=2 NS=512 FF=2048

typedef __attribute__((ext_vector_type(8))) __bf16 bf16x8;
typedef __attribute__((ext_vector_type(8))) _Float16 f16x8;
typedef __attribute__((ext_vector_type(4))) float f32x4;

__device__ __forceinline__ ushort f2b(float f){
  uint u = __float_as_uint(f);
  uint r = (u + 0x7FFFu + ((u >> 16) & 1u)) >> 16;
  return (ushort)r;
}
__device__ __forceinline__ ushort f2h(float f){
  _Float16 h = (_Float16)f;
  return *reinterpret_cast<ushort*>(&h);
}
__device__ __forceinline__ uint pkh2(float a, float b){
  return (uint)f2h(a) | ((uint)f2h(b)<<16);
}

// ---------------- weight prep: [K][N] fp32 -> [Npad][K] fp16 / bf16 hi+lo ----
template<int MODE>
__global__ __launch_bounds__(256)
void k_prep(const float* __restrict__ src, ushort* __restrict__ dh,
            ushort* __restrict__ dl, int K, int N, int Npad, long zStride){
  __shared__ float tile[32][33];
  int z = blockIdx.z;
  src += (size_t)z*K*N;
  dh  += (size_t)z*zStride;
  if (MODE) dl += (size_t)z*zStride;
  int n0 = blockIdx.x*32, k0 = blockIdx.y*32;
  int tx = threadIdx.x&31, ty = threadIdx.x>>5;
#pragma unroll
  for (int i=0;i<4;i++){
    int kk = k0 + ty + i*8, nn = n0 + tx;
    tile[ty+i*8][tx] = (nn < N) ? src[(size_t)kk*N + nn] : 0.f;
  }
  __syncthreads();
#pragma unroll
  for (int i=0;i<4;i++){
    int nn = n0 + ty + i*8, kk = k0 + tx;
    float v = tile[tx][ty+i*8];
    if (MODE==0){
      dh[(size_t)nn*K + kk] = f2h(v);
    } else {
      ushort h = f2b(v);
      dh[(size_t)nn*K + kk] = h;
      float fh = __uint_as_float((uint)h<<16);
      dl[(size_t)nn*K + kk] = f2b(v - fh);
    }
  }
}

// ---------------- V transpose (startup xl mem only) ----------------
__global__ __launch_bounds__(256)
void k_vtrans(const float* __restrict__ src, ushort* __restrict__ dst,
              long sB, int sR, int sMH, long dB, long dH, int NK){
  __shared__ float tile[64][65];
  int kc = blockIdx.x, h = blockIdx.y, b = blockIdx.z;
  int t = threadIdx.x;
  int key = t>>2, doff = (t&3)*16;
  const float* sp = src + (size_t)b*sB + (size_t)(kc*64+key)*sR + (sMH? h*64:0) + doff;
#pragma unroll
  for (int u=0;u<4;u++){
    float4 v = *reinterpret_cast<const float4*>(sp + u*4);
    tile[key][doff+u*4+0]=v.x; tile[key][doff+u*4+1]=v.y;
    tile[key][doff+u*4+2]=v.z; tile[key][doff+u*4+3]=v.w;
  }
  __syncthreads();
  int d = t>>2, kf = (t&3)*16;
  ushort* dp = dst + (size_t)b*dB + (size_t)h*dH + (size_t)d*NK + kc*64 + kf;
  ushort tmp[16];
#pragma unroll
  for (int u=0;u<16;u++) tmp[u] = f2h(tile[kf+u][d]);
  uint4 o0 = make_uint4((uint)tmp[0]|((uint)tmp[1]<<16), (uint)tmp[2]|((uint)tmp[3]<<16),
                        (uint)tmp[4]|((uint)tmp[5]<<16), (uint)tmp[6]|((uint)tmp[7]<<16));
  uint4 o1 = make_uint4((uint)tmp[8]|((uint)tmp[9]<<16), (uint)tmp[10]|((uint)tmp[11]<<16),
                        (uint)tmp[12]|((uint)tmp[13]<<16),(uint)tmp[14]|((uint)tmp[15]<<16));
  *reinterpret_cast<uint4*>(dp)   = o0;
  *reinterpret_cast<uint4*>(dp+8) = o1;
}

// fp16 -> fp16 transpose (for skv16 V half)
__global__ __launch_bounds__(256)
void k_vtrans16(const ushort* __restrict__ src, ushort* __restrict__ dst,
                long sB, int sR, long dB, int NK){
  __shared__ ushort tile[64][72];
  int kc = blockIdx.x, b = blockIdx.z;
  int t = threadIdx.x;
  int key = t>>2, doff = (t&3)*16;
  const ushort* sp = src + (size_t)b*sB + (size_t)(kc*64+key)*sR + doff;
  *reinterpret_cast<uint4*>(&tile[key][doff])   = *reinterpret_cast<const uint4*>(sp);
  *reinterpret_cast<uint4*>(&tile[key][doff+8]) = *reinterpret_cast<const uint4*>(sp+8);
  __syncthreads();
  int d = t>>2, kf = (t&3)*16;
  ushort* dp = dst + (size_t)b*dB + (size_t)d*NK + kc*64 + kf;
  ushort tmp[16];
#pragma unroll
  for (int u=0;u<16;u++) tmp[u] = tile[kf+u][d];
  uint4 o0 = make_uint4((uint)tmp[0]|((uint)tmp[1]<<16), (uint)tmp[2]|((uint)tmp[3]<<16),
                        (uint)tmp[4]|((uint)tmp[5]<<16), (uint)tmp[6]|((uint)tmp[7]<<16));
  uint4 o1 = make_uint4((uint)tmp[8]|((uint)tmp[9]<<16), (uint)tmp[10]|((uint)tmp[11]<<16),
                        (uint)tmp[12]|((uint)tmp[13]<<16),(uint)tmp[14]|((uint)tmp[15]<<16));
  *reinterpret_cast<uint4*>(dp)   = o0;
  *reinterpret_cast<uint4*>(dp+8) = o1;
}

__global__ void k_cvt(ushort* __restrict__ dst, const float* __restrict__ src, int n2){
  int idx = blockIdx.x*blockDim.x + threadIdx.x;
  if (idx >= n2) return;
  reinterpret_cast<uint*>(dst)[idx] = pkh2(src[2*idx], src[2*idx+1]);
}

// ---------------- embed / postable ----------------
__global__ void k_embed(const int* __restrict__ x, const float* __restrict__ emb,
                        float* __restrict__ h, int total4){
  int idx = blockIdx.x*blockDim.x + threadIdx.x;
  if (idx >= total4) return;
  int row = idx >> 7;
  int c4  = idx & 127;
  int tok = x[row];
  reinterpret_cast<float4*>(h)[idx] =
      reinterpret_cast<const float4*>(emb)[(size_t)tok*128 + c4];
}

__global__ void k_postable(const float* __restrict__ w1, const float* __restrict__ b1,
                           const float* __restrict__ w2, const float* __restrict__ b2,
                           const float* __restrict__ w3, const float* __restrict__ b3,
                           float* __restrict__ table){
  __shared__ float h1[128];
  __shared__ float h2[128];
  int d = blockIdx.x, t = threadIdx.x;
  float a = (float)d * w1[t] + b1[t];
  h1[t] = a / (1.f + __expf(-a));
  __syncthreads();
  float acc = b2[t];
  for (int p=0;p<128;p++) acc += h1[p]*w2[p*128+t];
  h2[t] = acc / (1.f + __expf(-acc));
  __syncthreads();
  if (t < 8){
    float acc2 = b3[t];
    for (int p=0;p<128;p++) acc2 += h2[p]*w3[p*8+t];
    table[d*8+t] = acc2;
  }
}

// ---------------- layernorm: fp16 out and/or bf16 hi/lo out ----------------
__global__ void k_ln(const float* __restrict__ x, const float* __restrict__ g,
                     ushort* __restrict__ y16,
                     ushort* __restrict__ yh, ushort* __restrict__ yl){
  int row = blockIdx.x;
  int t = threadIdx.x;
  float2 v = reinterpret_cast<const float2*>(x + (size_t)row*512)[t];
  float s = v.x+v.y, ss = v.x*v.x+v.y*v.y;
  for (int o=32;o;o>>=1){ s += __shfl_down(s,o); ss += __shfl_down(ss,o); }
  __shared__ float ls[4], lss[4];
  __shared__ float smu, srs;
  int wid = t>>6;
  if ((t&63)==0){ ls[wid]=s; lss[wid]=ss; }
  __syncthreads();
  if (t==0){
    float S=ls[0]+ls[1]+ls[2]+ls[3], SS=lss[0]+lss[1]+lss[2]+lss[3];
    float mu = S*(1.f/512.f);
    float var = SS*(1.f/512.f) - mu*mu;
    smu = mu; srs = rsqrtf(var + 1e-5f);
  }
  __syncthreads();
  float mu=smu, rs=srs;
  float2 gg = reinterpret_cast<const float2*>(g)[t];
  float ya = (v.x-mu)*rs*gg.x, yb = (v.y-mu)*rs*gg.y;
  size_t o2 = (size_t)row*512 + 2*t;
  if (y16)
    *reinterpret_cast<uint*>(&y16[o2]) = pkh2(ya, yb);
  if (yh){
    ushort ha = f2b(ya), hb = f2b(yb);
    *reinterpret_cast<uint*>(&yh[o2]) = (uint)ha | ((uint)hb<<16);
    float fa = __uint_as_float((uint)ha<<16), fb = __uint_as_float((uint)hb<<16);
    *reinterpret_cast<uint*>(&yl[o2]) = (uint)f2b(ya-fa) | ((uint)f2b(yb-fb)<<16);
  }
}

__device__ __forceinline__ float geluf(float x){
  float u = 1.5957691216f*(x + 0.044715f*x*x*x);
  return x / (1.f + __expf(-u));
}

// ---------------- fp16 MFMA GEMM 128x128 (FF1, logits) ----------------
template<int ACC, int EPI, int OUT16>
__global__ __launch_bounds__(256)
void k_gemmh(const ushort* __restrict__ A, const ushort* __restrict__ Bt,
             const float* __restrict__ bias, float* __restrict__ C,
             ushort* __restrict__ C16, int M, int N, int K){
  __shared__ ushort As[128][68];
  __shared__ ushort Bs[128][68];
  const int t = threadIdx.x;
  const int m0 = blockIdx.x*128, n0 = blockIdx.y*128;
  const int w = t>>6, lane = t&63;
  const int wm = (w>>1)*64, wn = (w&1)*64;
  const int fr = lane&15, fg = lane>>4;
  const int srow = t>>1, sko = (t&1)*32;

  f32x4 acc[4][4];
#pragma unroll
  for (int i=0;i<4;i++)
#pragma unroll
    for (int j=0;j<4;j++){ acc[i][j][0]=0.f; acc[i][j][1]=0.f; acc[i][j][2]=0.f; acc[i][j][3]=0.f; }

  const ushort* ap = A  + (size_t)(m0+srow)*K + sko;
  const ushort* bp = Bt + (size_t)(n0+srow)*K + sko;

  for (int k0=0; k0<K; k0+=64){
    uint4 av[4], bv[4];
#pragma unroll
    for (int u=0;u<4;u++){
      av[u] = *reinterpret_cast<const uint4*>(ap + k0 + u*8);
      bv[u] = *reinterpret_cast<const uint4*>(bp + k0 + u*8);
    }
#pragma unroll
    for (int u=0;u<4;u++){
      *reinterpret_cast<uint4*>(&As[srow][sko+u*8]) = av[u];
      *reinterpret_cast<uint4*>(&Bs[srow][sko+u*8]) = bv[u];
    }
    __syncthreads();
#pragma unroll
    for (int kk=0;kk<2;kk++){
      f16x8 af[4], bf[4];
#pragma unroll
      for (int mi=0;mi<4;mi++)
        af[mi] = *reinterpret_cast<const f16x8*>(&As[wm+mi*16+fr][kk*32+fg*8]);
#pragma unroll
      for (int nj=0;nj<4;nj++)
        bf[nj] = *reinterpret_cast<const f16x8*>(&Bs[wn+nj*16+fr][kk*32+fg*8]);
#pragma unroll
      for (int mi=0;mi<4;mi++)
#pragma unroll
        for (int nj=0;nj<4;nj++)
          acc[mi][nj] = __builtin_amdgcn_mfma_f32_16x16x32_f16(af[mi], bf[nj], acc[mi][nj], 0,0,0);
    }
    __syncthreads();
  }
#pragma unroll
  for (int mi=0;mi<4;mi++){
#pragma unroll
    for (int r=0;r<4;r++){
      int row = m0 + wm + mi*16 + fg*4 + r;
#pragma unroll
      for (int nj=0;nj<4;nj++){
        int col = n0 + wn + nj*16 + fr;
        if (col < N){
          float val = acc[mi][nj][r];
          if (bias) val += bias[col];
          if (EPI==1) val = geluf(val);
          if (OUT16){
            C16[(size_t)row*N + col] = f2h(val);
          } else {
            if (ACC) C[(size_t)row*N + col] += val; else C[(size_t)row*N + col] = val;
          }
        }
      }
    }
  }
}

// ---------------- fp16 MFMA GEMM 64x128 (N=512 class) ------------------------
// EPI: 0 none, 1 gelu, 2 ema (bias=beta; C = dec*C + (1-dec)*val).
// VT=1: write fp16 transposed copy to vT [b][h][64][1024]; optional fp32 xlv
// (block-1 rows -> [b][512][512]). C write skipped when C/C16 null.
template<int ACC, int EPI, int OUT16, int VT>
__global__ __launch_bounds__(256)
void k_gemmh64(const ushort* __restrict__ A, const ushort* __restrict__ Bt,
               const float* __restrict__ bias, float* __restrict__ C,
               ushort* __restrict__ C16, ushort* __restrict__ vT,
               float* __restrict__ xlv, int M, int N, int K){
  __shared__ ushort As[64][68];
  __shared__ ushort Bs[128][68];
  const int t = threadIdx.x;
  const int m0 = blockIdx.x*64, n0 = blockIdx.y*128;
  const int w = t>>6, lane = t&63;
  const int wm = (w>>1)*32, wn = (w&1)*64;
  const int fr = lane&15, fg = lane>>4;
  const int srowA = t>>2, skoA = (t&3)*16;
  const int srowB = t>>1, skoB = (t&1)*32;

  f32x4 acc[2][4];
#pragma unroll
  for (int i=0;i<2;i++)
#pragma unroll
    for (int j=0;j<4;j++){ acc[i][j][0]=0.f; acc[i][j][1]=0.f; acc[i][j][2]=0.f; acc[i][j][3]=0.f; }

  const ushort* ap = A  + (size_t)(m0+srowA)*K + skoA;
  const ushort* bp = Bt + (size_t)(n0+srowB)*K + skoB;

  for (int k0=0; k0<K; k0+=64){
    uint4 a0 = *reinterpret_cast<const uint4*>(ap + k0);
    uint4 a1 = *reinterpret_cast<const uint4*>(ap + k0 + 8);
    uint4 b0 = *reinterpret_cast<const uint4*>(bp + k0);
    uint4 b1 = *reinterpret_cast<const uint4*>(bp + k0 + 8);
    uint4 b2 = *reinterpret_cast<const uint4*>(bp + k0 + 16);
    uint4 b3 = *reinterpret_cast<const uint4*>(bp + k0 + 24);
    *reinterpret_cast<uint4*>(&As[srowA][skoA])    = a0;
    *reinterpret_cast<uint4*>(&As[srowA][skoA+8])  = a1;
    *reinterpret_cast<uint4*>(&Bs[srowB][skoB])    = b0;
    *reinterpret_cast<uint4*>(&Bs[srowB][skoB+8])  = b1;
    *reinterpret_cast<uint4*>(&Bs[srowB][skoB+16]) = b2;
    *reinterpret_cast<uint4*>(&Bs[srowB][skoB+24]) = b3;
    __syncthreads();
#pragma unroll
    for (int kk=0;kk<2;kk++){
      f16x8 af[2], bf[4];
#pragma unroll
      for (int mi=0;mi<2;mi++)
        af[mi] = *reinterpret_cast<const f16x8*>(&As[wm+mi*16+fr][kk*32+fg*8]);
#pragma unroll
      for (int nj=0;nj<4;nj++)
        bf[nj] = *reinterpret_cast<const f16x8*>(&Bs[wn+nj*16+fr][kk*32+fg*8]);
#pragma unroll
      for (int mi=0;mi<2;mi++)
#pragma unroll
        for (int nj=0;nj<4;nj++)
          acc[mi][nj] = __builtin_amdgcn_mfma_f32_16x16x32_f16(af[mi], bf[nj], acc[mi][nj], 0,0,0);
    }
    __syncthreads();
  }
#pragma unroll
  for (int mi=0;mi<2;mi++){
#pragma unroll
    for (int r=0;r<4;r++){
      int row = m0 + wm + mi*16 + fg*4 + r;
#pragma unroll
      for (int nj=0;nj<4;nj++){
        int col = n0 + wn + nj*16 + fr;
        if (col < N){
          float val = acc[mi][nj][r];
          if (EPI==2){
            size_t idx = (size_t)row*N + col;
            float old = C[idx];
            float dec = 1.f/(1.f+__expf(-bias[col]));
            C[idx] = dec*old + (1.f-dec)*val;
          } else {
            if (bias) val += bias[col];
            if (EPI==1) val = geluf(val);
            if (OUT16){
              if (C16) C16[(size_t)row*N + col] = f2h(val);
            } else if (C){
              if (ACC) C[(size_t)row*N + col] += val; else C[(size_t)row*N + col] = val;
            }
            if (VT && xlv && (row&1023) >= 512)
              xlv[((size_t)(row>>10)*512 + (row&1023) - 512)*512 + col] = val;
          }
        }
      }
    }
  }
  if (VT){
#pragma unroll
    for (int mi=0;mi<2;mi++)
#pragma unroll
      for (int r=0;r<4;r++)
#pragma unroll
        for (int nj=0;nj<4;nj++)
          Bs[wn+nj*16+fr][wm+mi*16+fg*4+r] = f2h(acc[mi][nj][r]);
    __syncthreads();
    int c = t>>1, half = t&1;
    int hh = (n0+c)>>6, dd = (n0+c)&63;
    int bb = m0>>10, posb = m0&1023;
    ushort* dp = vT + (size_t)bb*524288 + (size_t)hh*65536 + (size_t)dd*1024 + posb + half*32;
#pragma unroll
    for (int u=0;u<4;u++)
      *reinterpret_cast<uint4*>(dp + u*8) = *reinterpret_cast<const uint4*>(&Bs[c][half*32 + u*8]);
  }
}

// ---------------- split-bf16 MFMA GEMM (pre-split A; fused rms + xl-k out) ----
// fp16-only outputs. If qsc != nullptr: per-(row,head) l2norm over 64 cols
// (in-lane nj sum + 16-lane butterfly), scale by qsc/ksc per col<N1.
// If xlk != nullptr: write fp32 normalized k (cols>=N1, block-1 rows).
template<int REMAP>
__global__ __launch_bounds__(256)
void k_gemm_sp(const ushort* __restrict__ Ah, const ushort* __restrict__ Al,
               const ushort* __restrict__ Bh, const ushort* __restrict__ Bl,
               ushort* __restrict__ C1h, int ld1, int N1,
               ushort* __restrict__ C2h, int ld2,
               const float* __restrict__ qsc, const float* __restrict__ ksc,
               float* __restrict__ xlk,
               int nb, int M, int N, int K){
  __shared__ ushort As[2][128][36];
  __shared__ ushort Bs[2][128][36];
  const int t = threadIdx.x;
  const int m0 = blockIdx.x*128, n0 = blockIdx.y*128;
  const int w = t>>6, lane = t&63;
  const int wm = (w>>1)*64, wn = (w&1)*64;
  const int fr = lane&15, fg = lane>>4;
  const int srow = t>>1, sko = (t&1)*16;

  f32x4 acc[4][4];
#pragma unroll
  for (int i=0;i<4;i++)
#pragma unroll
    for (int j=0;j<4;j++){ acc[i][j][0]=0.f; acc[i][j][1]=0.f; acc[i][j][2]=0.f; acc[i][j][3]=0.f; }

  int mrow = m0 + srow;
  int arow = REMAP ? ((mrow>>9)*1024 + nb*512 + (mrow&511)) : mrow;
  const ushort* aph = Ah + (size_t)arow*K + sko;
  const ushort* apl = Al + (size_t)arow*K + sko;
  const ushort* bph = Bh + (size_t)(n0+srow)*K + sko;
  const ushort* bpl = Bl + (size_t)(n0+srow)*K + sko;

  for (int k0=0; k0<K; k0+=32){
    uint4 a0 = *reinterpret_cast<const uint4*>(aph + k0);
    uint4 a1 = *reinterpret_cast<const uint4*>(aph + k0 + 8);
    uint4 al0 = *reinterpret_cast<const uint4*>(apl + k0);
    uint4 al1 = *reinterpret_cast<const uint4*>(apl + k0 + 8);
    uint4 b0 = *reinterpret_cast<const uint4*>(bph + k0);
    uint4 b1 = *reinterpret_cast<const uint4*>(bph + k0 + 8);
    uint4 bl0 = *reinterpret_cast<const uint4*>(bpl + k0);
    uint4 bl1 = *reinterpret_cast<const uint4*>(bpl + k0 + 8);
    *reinterpret_cast<uint4*>(&As[0][srow][sko])   = a0;
    *reinterpret_cast<uint4*>(&As[0][srow][sko+8]) = a1;
    *reinterpret_cast<uint4*>(&As[1][srow][sko])   = al0;
    *reinterpret_cast<uint4*>(&As[1][srow][sko+8]) = al1;
    *reinterpret_cast<uint4*>(&Bs[0][srow][sko])   = b0;
    *reinterpret_cast<uint4*>(&Bs[0][srow][sko+8]) = b1;
    *reinterpret_cast<uint4*>(&Bs[1][srow][sko])   = bl0;
    *reinterpret_cast<uint4*>(&Bs[1][srow][sko+8]) = bl1;
    __syncthreads();

    bf16x8 ah[4], al[4], bh[4], bl[4];
#pragma unroll
    for (int mi=0;mi<4;mi++){
      ah[mi] = *reinterpret_cast<const bf16x8*>(&As[0][wm+mi*16+fr][fg*8]);
      al[mi] = *reinterpret_cast<const bf16x8*>(&As[1][wm+mi*16+fr][fg*8]);
    }
#pragma unroll
    for (int nj=0;nj<4;nj++){
      bh[nj] = *reinterpret_cast<const bf16x8*>(&Bs[0][wn+nj*16+fr][fg*8]);
      bl[nj] = *reinterpret_cast<const bf16x8*>(&Bs[1][wn+nj*16+fr][fg*8]);
    }
#pragma unroll
    for (int mi=0;mi<4;mi++)
#pragma unroll
      for (int nj=0;nj<4;nj++){
        acc[mi][nj] = __builtin_amdgcn_mfma_f32_16x16x32_bf16(ah[mi], bh[nj], acc[mi][nj], 0,0,0);
        acc[mi][nj] = __builtin_amdgcn_mfma_f32_16x16x32_bf16(al[mi], bh[nj], acc[mi][nj], 0,0,0);
        acc[mi][nj] = __builtin_amdgcn_mfma_f32_16x16x32_bf16(ah[mi], bl[nj], acc[mi][nj], 0,0,0);
      }
    __syncthreads();
  }
#pragma unroll
  for (int mi=0;mi<4;mi++){
#pragma unroll
    for (int r=0;r<4;r++){
      int row = m0 + wm + mi*16 + fg*4 + r;
      float vals[4];
#pragma unroll
      for (int nj=0;nj<4;nj++) vals[nj] = acc[mi][nj][r];
      if (qsc){
        float ss = vals[0]*vals[0]+vals[1]*vals[1]+vals[2]*vals[2]+vals[3]*vals[3];
        ss += __shfl_xor(ss,1);
        ss += __shfl_xor(ss,2);
        ss += __shfl_xor(ss,4);
        ss += __shfl_xor(ss,8);
        float rs = rsqrtf(ss + 1e-12f);
        const float* sc = ((n0+wn) < N1) ? qsc : ksc;
#pragma unroll
        for (int nj=0;nj<4;nj++) vals[nj] = vals[nj]*rs*sc[nj*16+fr];
      }
#pragma unroll
      for (int nj=0;nj<4;nj++){
        int col = n0 + wn + nj*16 + fr;
        float val = vals[nj];
        if (col < N1){
          if (C1h) C1h[(size_t)row*ld1 + col] = f2h(val);
        } else if (col < N){
          if (C2h) C2h[(size_t)row*ld2 + (col-N1)] = f2h(val);
          if (xlk && (row&1023) >= 512)
            xlk[((size_t)(row>>10)*512 + (row&1023) - 512)*512 + (col-N1)] = val;
        }
      }
    }
  }
}

// ---------------- merged windowed MFMA flash attention -----------------------
__global__ __launch_bounds__(256)
void k_attn_win(const ushort* __restrict__ q16, const ushort* __restrict__ k16,
                const ushort* __restrict__ vTb,
                const ushort* __restrict__ xlK, const ushort* __restrict__ xlVT,
                int isxl, ushort* __restrict__ O, float scale,
                const float* __restrict__ table){
  __shared__ ushort Qs[64][72];
  __shared__ ushort Ks[64][72];
  __shared__ ushort Vs[64][72];
  __shared__ ushort Pw[4][16][72];
  __shared__ float tcol[512];
  const int b = blockIdx.z, h = blockIdx.y;
  const int nb = blockIdx.x>>3, qt = blockIdx.x&7;
  const int t = threadIdx.x, w = t>>6, lane = t&63;
  const int fr = lane&15, fg = lane>>4;
  tcol[t]     = table[t*8 + h];
  tcol[t+256] = table[(t+256)*8 + h];

  const ushort* Q  = q16 + (size_t)nb*262144;
  const ushort* K1 = k16 + (size_t)nb*262144;
  const ushort* V1 = vTb + (size_t)nb*512;
  ushort* Op = O + (size_t)nb*262144;
  const int has_mem = (nb==1) || isxl;
  const ushort* K0; long k0B; const ushort* V0; long vt0B, vt0H; int vt0D;
  if (nb==1){ K0=k16; k0B=524288; V0=vTb; vt0B=524288; vt0H=65536; vt0D=1024; }
  else if (isxl){ K0=xlK; k0B=262144; V0=xlVT; vt0B=262144; vt0H=32768; vt0D=512; }
  else { K0=k16; k0B=524288; V0=vTb; vt0B=524288; vt0H=65536; vt0D=1024; }

  {
    int qrow = t>>2, doff = (t&3)*16;
    const ushort* qp = Q + (size_t)b*524288 + (size_t)(qt*64+qrow)*512 + h*64 + doff;
    *reinterpret_cast<uint4*>(&Qs[qrow][doff])   = *reinterpret_cast<const uint4*>(qp);
    *reinterpret_cast<uint4*>(&Qs[qrow][doff+8]) = *reinterpret_cast<const uint4*>(qp+8);
  }
  __syncthreads();
  f16x8 aq[2];
  aq[0] = *reinterpret_cast<const f16x8*>(&Qs[w*16+fr][fg*8]);
  aq[1] = *reinterpret_cast<const f16x8*>(&Qs[w*16+fr][32+fg*8]);

  f32x4 so[4];
#pragma unroll
  for (int dt=0;dt<4;dt++){ so[dt][0]=0.f; so[dt][1]=0.f; so[dt][2]=0.f; so[dt][3]=0.f; }
  float m[4] = {-1e30f,-1e30f,-1e30f,-1e30f};
  float lsum[4] = {0.f,0.f,0.f,0.f};

  const int srow = t>>2, sdo = (t&3)*16;
  const int vd = t>>2,   vkf = (t&3)*16;

  int jt0 = has_mem ? qt : 8;
  int jt1 = qt + 8; if (jt1 > 15) jt1 = 15;

  for (int jt=jt0; jt<=jt1; jt++){
    {
      int key = jt*64 + srow;
      const ushort* kp;
      if (key < 512) kp = K0 + (size_t)b*k0B + (size_t)key*512 + h*64 + sdo;
      else           kp = K1 + (size_t)b*524288 + (size_t)(key-512)*512 + h*64 + sdo;
      *reinterpret_cast<uint4*>(&Ks[srow][sdo])   = *reinterpret_cast<const uint4*>(kp);
      *reinterpret_cast<uint4*>(&Ks[srow][sdo+8]) = *reinterpret_cast<const uint4*>(kp+8);
    }
    {
      const ushort* vp;
      if (jt*64 < 512) vp = V0 + (size_t)b*vt0B + (size_t)h*vt0H + (size_t)vd*vt0D + jt*64 + vkf;
      else             vp = V1 + (size_t)b*524288 + (size_t)h*65536 + (size_t)vd*1024 + (jt*64-512) + vkf;
      *reinterpret_cast<uint4*>(&Vs[vd][vkf])   = *reinterpret_cast<const uint4*>(vp);
      *reinterpret_cast<uint4*>(&Vs[vd][vkf+8]) = *reinterpret_cast<const uint4*>(vp+8);
    }
    __syncthreads();
    f32x4 sacc[4];
#pragma unroll
    for (int kt=0;kt<4;kt++){ sacc[kt][0]=0.f; sacc[kt][1]=0.f; sacc[kt][2]=0.f; sacc[kt][3]=0.f; }
#pragma unroll
    for (int ks=0;ks<2;ks++){
#pragma unroll
      for (int kt=0;kt<4;kt++){
        f16x8 bf = *reinterpret_cast<const f16x8*>(&Ks[kt*16+fr][ks*32+fg*8]);
        sacc[kt] = __builtin_amdgcn_mfma_f32_16x16x32_f16(aq[ks], bf, sacc[kt], 0,0,0);
      }
    }
#pragma unroll
    for (int r=0;r<4;r++){
      float sv[4];
      int ia = qt*64 + w*16 + fg*4 + r;
#pragma unroll
      for (int kt=0;kt<4;kt++){
        float s = sacc[kt][r]*scale;
        int jg = jt*64 + kt*16 + fr;
        bool valid = (jg > ia) && (jg <= ia+512) && (has_mem || jg >= 512);
        sv[kt] = valid ? s + tcol[ia+512-jg] : -1e9f;
      }
      float tm = fmaxf(fmaxf(sv[0],sv[1]), fmaxf(sv[2],sv[3]));
      tm = fmaxf(tm, __shfl_xor(tm,1));
      tm = fmaxf(tm, __shfl_xor(tm,2));
      tm = fmaxf(tm, __shfl_xor(tm,4));
      tm = fmaxf(tm, __shfl_xor(tm,8));
      float mn = fmaxf(m[r], tm);
      float c = __expf(m[r]-mn);
      m[r] = mn;
      float ps = 0.f;
#pragma unroll
      for (int kt=0;kt<4;kt++){
        float pp = (sv[kt] <= -1e8f) ? 0.f : __expf(sv[kt]-mn);
        ps += pp;
        Pw[w][fg*4+r][kt*16+fr] = f2h(pp);
      }
      ps += __shfl_xor(ps,1);
      ps += __shfl_xor(ps,2);
      ps += __shfl_xor(ps,4);
      ps += __shfl_xor(ps,8);
      lsum[r] = lsum[r]*c + ps;
#pragma unroll
      for (int dt=0;dt<4;dt++) so[dt][r] *= c;
    }
#pragma unroll
    for (int ks=0;ks<2;ks++){
      f16x8 pa = *reinterpret_cast<const f16x8*>(&Pw[w][fr][ks*32+fg*8]);
#pragma unroll
      for (int dt=0;dt<4;dt++){
        f16x8 bv = *reinterpret_cast<const f16x8*>(&Vs[dt*16+fr][ks*32+fg*8]);
        so[dt] = __builtin_amdgcn_mfma_f32_16x16x32_f16(pa, bv, so[dt], 0,0,0);
      }
    }
    __syncthreads();
  }
#pragma unroll
  for (int r=0;r<4;r++){
    int row = qt*64 + w*16 + fg*4 + r;
    float inv = 1.f / lsum[r];
    ushort* op = Op + (size_t)b*524288 + (size_t)row*512 + h*64;
#pragma unroll
    for (int dt=0;dt<4;dt++)
      op[dt*16+fr] = f2h(so[dt][r]*inv);
  }
}

// ---------------- merged rec-layer attentions (both tasks, one launch) --------
// grid (16, 8, 4): x<8 -> tokens->states (512 keys); x>=8 -> states->[states|tokens].
__global__ __launch_bounds__(256)
void k_attn_rec(const ushort* __restrict__ q2s, const ushort* __restrict__ sq,
                const ushort* __restrict__ skv, const ushort* __restrict__ svT,
                const ushort* __restrict__ kblk, const ushort* __restrict__ vblk,
                ushort* __restrict__ ts, ushort* __restrict__ sa){
  __shared__ ushort Qs[64][72];
  __shared__ ushort Ks[64][72];
  __shared__ ushort Vs[64][72];
  __shared__ ushort Pw[4][16][72];
  const int b = blockIdx.z, h = blockIdx.y;
  const int task = blockIdx.x>>3, qt = blockIdx.x&7;
  const int t = threadIdx.x, w = t>>6, lane = t&63;
  const int fr = lane&15, fg = lane>>4;

  const ushort* Q; const ushort* K1; int k1R, k1H;
  const ushort* VT1; long vt1B, vt1H; int vt1D;
  int nt; ushort* O; long oB;
  if (task==0){
    Q=q2s; K1=skv; k1R=128; k1H=0;
    VT1=svT; vt1B=32768; vt1H=0; vt1D=512;
    nt=8; O=ts; oB=524288;
  } else {
    Q=sq; K1=kblk; k1R=512; k1H=1;
    VT1=vblk; vt1B=524288; vt1H=65536; vt1D=1024;
    nt=16; O=sa; oB=262144;
  }

  {
    int qrow = t>>2, doff = (t&3)*16;
    const ushort* qp = Q + (size_t)b*262144 + (size_t)(qt*64+qrow)*512 + h*64 + doff;
    *reinterpret_cast<uint4*>(&Qs[qrow][doff])   = *reinterpret_cast<const uint4*>(qp);
    *reinterpret_cast<uint4*>(&Qs[qrow][doff+8]) = *reinterpret_cast<const uint4*>(qp+8);
  }
  __syncthreads();
  f16x8 aq[2];
  aq[0] = *reinterpret_cast<const f16x8*>(&Qs[w*16+fr][fg*8]);
  aq[1] = *reinterpret_cast<const f16x8*>(&Qs[w*16+fr][32+fg*8]);

  f32x4 so[4];
#pragma unroll
  for (int dt=0;dt<4;dt++){ so[dt][0]=0.f; so[dt][1]=0.f; so[dt][2]=0.f; so[dt][3]=0.f; }
  float m[4] = {-1e30f,-1e30f,-1e30f,-1e30f};
  float lsum[4] = {0.f,0.f,0.f,0.f};

  const int srow = t>>2, sdo = (t&3)*16;
  const int vd = t>>2,   vkf = (t&3)*16;

  for (int jt=0; jt<nt; jt++){
    {
      int key = jt*64 + srow;
      const ushort* kp;
      if (key < 512) kp = skv + (size_t)b*65536 + (size_t)key*128 + sdo;
      else           kp = K1 + (size_t)b*524288 + (size_t)(key-512)*k1R + (k1H? h*64:0) + sdo;
      *reinterpret_cast<uint4*>(&Ks[srow][sdo])   = *reinterpret_cast<const uint4*>(kp);
      *reinterpret_cast<uint4*>(&Ks[srow][sdo+8]) = *reinterpret_cast<const uint4*>(kp+8);
    }
    {
      const ushort* vp;
      if (jt*64 < 512) vp = svT + (size_t)b*32768 + (size_t)vd*512 + jt*64 + vkf;
      else             vp = VT1 + (size_t)b*vt1B + (size_t)h*vt1H + (size_t)vd*vt1D + (jt*64-512) + vkf;
      *reinterpret_cast<uint4*>(&Vs[vd][vkf])   = *reinterpret_cast<const uint4*>(vp);
      *reinterpret_cast<uint4*>(&Vs[vd][vkf+8]) = *reinterpret_cast<const uint4*>(vp+8);
    }
    __syncthreads();
    f32x4 sacc[4];
#pragma unroll
    for (int kt=0;kt<4;kt++){ sacc[kt][0]=0.f; sacc[kt][1]=0.f; sacc[kt][2]=0.f; sacc[kt][3]=0.f; }
#pragma unroll
    for (int ks=0;ks<2;ks++){
#pragma unroll
      for (int kt=0;kt<4;kt++){
        f16x8 bf = *reinterpret_cast<const f16x8*>(&Ks[kt*16+fr][ks*32+fg*8]);
        sacc[kt] = __builtin_amdgcn_mfma_f32_16x16x32_f16(aq[ks], bf, sacc[kt], 0,0,0);
      }
    }
#pragma unroll
    for (int r=0;r<4;r++){
      float sv[4];
#pragma unroll
      for (int kt=0;kt<4;kt++) sv[kt] = sacc[kt][r]*0.125f;
      float tm = fmaxf(fmaxf(sv[0],sv[1]), fmaxf(sv[2],sv[3]));
      tm = fmaxf(tm, __shfl_xor(tm,1));
      tm = fmaxf(tm, __shfl_xor(tm,2));
      tm = fmaxf(tm, __shfl_xor(tm,4));
      tm = fmaxf(tm, __shfl_xor(tm,8));
      float mn = fmaxf(m[r], tm);
      float c = __expf(m[r]-mn);
      m[r] = mn;
      float ps = 0.f;
#pragma unroll
      for (int kt=0;kt<4;kt++){
        float pp = __expf(sv[kt]-mn);
        ps += pp;
        Pw[w][fg*4+r][kt*16+fr] = f2h(pp);
      }
      ps += __shfl_xor(ps,1);
      ps += __shfl_xor(ps,2);
      ps += __shfl_xor(ps,4);
      ps += __shfl_xor(ps,8);
      lsum[r] = lsum[r]*c + ps;
#pragma unroll
      for (int dt=0;dt<4;dt++) so[dt][r] *= c;
    }
#pragma unroll
    for (int ks=0;ks<2;ks++){
      f16x8 pa = *reinterpret_cast<const f16x8*>(&Pw[w][fr][ks*32+fg*8]);
#pragma unroll
      for (int dt=0;dt<4;dt++){
        f16x8 bv = *reinterpret_cast<const f16x8*>(&Vs[dt*16+fr][ks*32+fg*8]);
        so[dt] = __builtin_amdgcn_mfma_f32_16x16x32_f16(pa, bv, so[dt], 0,0,0);
      }
    }
    __syncthreads();
  }
#pragma unroll
  for (int r=0;r<4;r++){
    int row = qt*64 + w*16 + fg*4 + r;
    float inv = 1.f / lsum[r];
    ushort* op = O + (size_t)b*oB + (size_t)row*512 + h*64;
#pragma unroll
    for (int dt=0;dt<4;dt++)
      op[dt*16+fr] = f2h(so[dt][r]*inv);
  }
}

// ---------------- small utility kernels ----------------
__global__ void k_copy(float* __restrict__ dst, const float* __restrict__ src, int n){
  int idx = blockIdx.x*blockDim.x + threadIdx.x;
  if (idx < n) dst[idx] = src[idx];
}

// ---------------- launcher ----------------
extern "C" void kernel_launch(void* const* d_in, const int* in_sizes, int n_in,
                              void* d_out, int out_size, void* d_ws, size_t ws_size,
                              hipStream_t stream){
  // floats 12,599,296 B + ushorts 122,814,464 B = 135,413,760 B
  if (ws_size < (size_t)135413760) return;

  const int*   x        = (const int*)  d_in[0];
  const float* tok_emb  = (const float*)d_in[1];
  const float* pw1 = (const float*)d_in[2];
  const float* pb1 = (const float*)d_in[3];
  const float* pw2 = (const float*)d_in[4];
  const float* pb2 = (const float*)d_in[5];
  const float* pw3 = (const float*)d_in[6];
  const float* pb3 = (const float*)d_in[7];
  const float* ln_g = (const float*)d_in[8];
  const float* Wq = (const float*)d_in[9];
  const float* Wk = (const float*)d_in[10];
  const float* Wv = (const float*)d_in[11];
  const float* Wo = (const float*)d_in[12];
  const float* q_scale = (const float*)d_in[13];
  const float* k_scale = (const float*)d_in[14];
  const float* Wo_state = (const float*)d_in[15];
  const float* state_norm_g = (const float*)d_in[16];
  const float* Wq2s = (const float*)d_in[17];
  const float* Ws2q = (const float*)d_in[18];
  const float* Ws2kv = (const float*)d_in[19];
  const float* W_state_out = (const float*)d_in[20];
  const float* ema_beta = (const float*)d_in[21];
  const float* ff_g = (const float*)d_in[22];
  const float* ff_w1 = (const float*)d_in[23];
  const float* ff_b1 = (const float*)d_in[24];
  const float* ff_w2 = (const float*)d_in[25];
  const float* ff_b2 = (const float*)d_in[26];
  const float* final_g = (const float*)d_in[27];
  const float* W_logits = (const float*)d_in[28];
  const float* xl_mem_k = (const float*)d_in[29];
  const float* xl_mem_v = (const float*)d_in[30];
  const float* states_in = (const float*)d_in[31];

  float* out = (float*)d_out;
  float* out_xlk    = out + 81920000;
  float* out_xlv    = out + 84017152;
  float* out_states = out + 86114304;

  float* p = (float*)d_ws;
  float* hstate   = p; p += 2097152;
  float* states_cur = p; p += 1048576;
  float* table    = p; p += 4096;

  ushort* us = (ushort*)p;
  ushort* wqkh  = us; us += 3145728;   // [6][1024][512]: rows 0-511 q, 512-1023 k
  ushort* wqkl  = us; us += 3145728;
  ushort* wvT   = us; us += 1572864;
  ushort* woT   = us; us += 1572864;
  ushort* ffw1T = us; us += 6291456;
  ushort* ffw2T = us; us += 6291456;
  ushort* wostT = us; us += 262144;
  ushort* wstoutT = us; us += 262144;
  ushort* wq2sh = us; us += 262144;
  ushort* wq2sl = us; us += 262144;
  ushort* wsqkvh = us; us += 327680;   // [640][512]: rows 0-511 Ws2q, 512-639 Ws2kv
  ushort* wsqkvl = us; us += 327680;
  ushort* wlogT  = us; us += 10289152; // [20096][512]
  ushort* vTb   = us; us += 2097152;   // [b][h][64][1024]
  ushort* xlvT  = us; us += 2097152;   // [2][b][h][64][512]
  ushort* svT   = us; us += 131072;    // [b][64][512]
  ushort* xn16  = us; us += 2097152;
  ushort* ao16  = us; us += 2097152;
  ushort* ff1_16 = us; us += 8388608;  // [4096][2048] + rec aliases
  ushort* xnh   = us; us += 2097152;
  ushort* xnl   = us; us += 2097152;
  ushort* q16   = us; us += 2097152;
  ushort* k16   = us; us += 2097152;
  ushort* xlk16 = us; us += 2097152;   // [2][b][512][512] fp16
  // rec aliases inside ff1_16 (dead between FF uses)
  ushort* ts16   = ff1_16;             // [4096][512]
  ushort* sa16   = ff1_16 + 2097152;   // [2048][512]
  ushort* snh    = ff1_16 + 3145728;
  ushort* snl    = ff1_16 + 4194304;
  ushort* sq16   = ff1_16 + 5242880;
  ushort* q2s16  = ff1_16 + 6291456;
  ushort* skv16  = ff1_16 + 7340032;   // [2048][128]

  // ---- weight prep ----
  k_prep<1><<<dim3(16,16,6),256,0,stream>>>(Wq, wqkh, wqkl, 512,512,512, 524288);
  k_prep<1><<<dim3(16,16,6),256,0,stream>>>(Wk, wqkh+262144, wqkl+262144, 512,512,512, 524288);
  k_prep<0><<<dim3(16,16,6),256,0,stream>>>(Wv, wvT, nullptr, 512,512,512, 262144);
  k_prep<0><<<dim3(16,16,6),256,0,stream>>>(Wo, woT, nullptr, 512,512,512, 262144);
  k_prep<0><<<dim3(64,16,6),256,0,stream>>>(ff_w1, ffw1T, nullptr, 512,2048,2048, 1048576);
  k_prep<0><<<dim3(16,64,6),256,0,stream>>>(ff_w2, ffw2T, nullptr, 2048,512,512, 1048576);
  k_prep<0><<<dim3(16,16,1),256,0,stream>>>(Wo_state, wostT, nullptr, 512,512,512, 262144);
  k_prep<0><<<dim3(16,16,1),256,0,stream>>>(W_state_out, wstoutT, nullptr, 512,512,512, 262144);
  k_prep<1><<<dim3(16,16,1),256,0,stream>>>(Wq2s, wq2sh, wq2sl, 512,512,512, 262144);
  k_prep<1><<<dim3(16,16,1),256,0,stream>>>(Ws2q, wsqkvh, wsqkvl, 512,512,512, 327680);
  k_prep<1><<<dim3(4,16,1),256,0,stream>>>(Ws2kv, wsqkvh+262144, wsqkvl+262144, 512,128,128, 327680);
  k_prep<0><<<dim3(628,16,1),256,0,stream>>>(W_logits, wlogT, nullptr, 512,20000,20096, 10289152);

  for (int s=0;s<2;s++)
    k_vtrans<<<dim3(8,8,4),256,0,stream>>>(xl_mem_v + (size_t)s*1048576,
                                           xlvT + (size_t)s*1048576,
                                           262144L, 512, 1, 262144L, 32768L, 512);
  k_cvt<<<4096,256,0,stream>>>(xlk16, xl_mem_k, 1048576);

  k_embed<<<2048, 256, 0, stream>>>(x, tok_emb, hstate, 524288);
  k_postable<<<512, 128, 0, stream>>>(pw1,pb1,pw2,pb2,pw3,pb3, table);
  k_copy<<<4096, 256, 0, stream>>>(states_cur, states_in, 1048576);

  for (int l=0;l<6;l++){
    bool isxl = (l==4 || l==5);
    int xli = l-4;
    int src = (l==4)? 1 : 0;     // roll(-1)
    k_ln<<<4096,256,0,stream>>>(hstate, ln_g + l*512, xn16, xnh, xnl);
    float scale = 0.125f;
    const float* qsc = nullptr; const float* ksc = nullptr;
    if (l>=3){ qsc = q_scale + l*64; ksc = k_scale + l*64; scale = 8.f; }
    // q|k merged sp-GEMM with fused rmsnorm (l>=3) + xl-k fp32 out (l=4,5)
    k_gemm_sp<0><<<dim3(32,8),256,0,stream>>>(xnh, xnl,
        wqkh + (size_t)l*524288, wqkl + (size_t)l*524288,
        q16, 512, 512, k16, 512, qsc, ksc,
        isxl ? out_xlk + (size_t)xli*1048576 : nullptr,
        0, 4096, 1024, 512);
    // v GEMM: fp16 V^T + (xl) fp32 out_xlv
    k_gemmh64<0,0,0,1><<<dim3(64,4),256,0,stream>>>(xn16, wvT + (size_t)l*262144,
        nullptr, nullptr, nullptr, vTb,
        isxl ? out_xlv + (size_t)xli*1048576 : nullptr, 4096,512,512);

    k_attn_win<<<dim3(16,8,4),256,0,stream>>>(
        q16, k16, vTb,
        isxl ? xlk16 + (size_t)src*1048576 : k16,
        isxl ? xlvT  + (size_t)src*1048576 : vTb,
        isxl ? 1 : 0, ao16, scale, table);

    k_gemmh64<1,0,0,0><<<dim3(64,4),256,0,stream>>>(ao16, woT + (size_t)l*262144,
        nullptr, hstate, nullptr, nullptr, nullptr, 4096,512,512);
    if (l==3){
      for (int nb=0;nb<2;nb++){
        k_ln<<<2048,256,0,stream>>>(states_cur, state_norm_g, nullptr, snh, snl);
        k_gemm_sp<0><<<dim3(16,5),256,0,stream>>>(snh, snl, wsqkvh, wsqkvl,
            sq16, 512, 512, skv16, 128, nullptr, nullptr, nullptr, 0, 2048, 640, 512);
        k_vtrans16<<<dim3(8,1,4),256,0,stream>>>(skv16 + 64, svT, 65536L, 128, 32768L, 512);
        k_gemm_sp<1><<<dim3(16,4),256,0,stream>>>(xnh, xnl, wq2sh, wq2sl,
            q2s16, 512, 512, nullptr, 0, nullptr, nullptr, nullptr, nb, 2048, 512, 512);
        k_attn_rec<<<dim3(16,8,4),256,0,stream>>>(
            q2s16, sq16, skv16, svT,
            k16 + (size_t)nb*262144, vTb + (size_t)nb*512,
            ts16 + (size_t)nb*262144, sa16);
        k_gemmh64<0,2,0,0><<<dim3(32,4),256,0,stream>>>(sa16, wstoutT, ema_beta,
            states_cur, nullptr, nullptr, nullptr, 2048,512,512);
      }
      k_gemmh64<1,0,0,0><<<dim3(64,4),256,0,stream>>>(ts16, wostT, nullptr,
          hstate, nullptr, nullptr, nullptr, 4096,512,512);
    }
    k_ln<<<4096,256,0,stream>>>(hstate, ff_g + l*512, xn16, nullptr, nullptr);
    k_gemmh<0,1,1><<<dim3(32,16),256,0,stream>>>(xn16, ffw1T + (size_t)l*1048576, ff_b1 + l*2048, nullptr, ff1_16, 4096,2048,512);
    k_gemmh64<1,0,0,0><<<dim3(64,4),256,0,stream>>>(ff1_16, ffw2T + (size_t)l*1048576, ff_b2 + l*512, hstate, nullptr, nullptr, nullptr, 4096,512,2048);
  }
  k_ln<<<4096,256,0,stream>>>(hstate, final_g, xn16, nullptr, nullptr);
  k_gemmh<0,0,0><<<dim3(32,157),256,0,stream>>>(xn16, wlogT, nullptr, out, nullptr, 4096,20000,512);
  k_copy<<<4096, 256, 0, stream>>>(out_states, states_cur, 1048576);
}

// Round 16
// 1490.555 us; speedup vs baseline: 8.4481x; 1.0925x over previous
//
#include <hip/hip_runtime.h>
#include <math.h>

// B=4 N=1024 V=20000 D=512 H=8 DH=64 W=512 NB=2 NS=512 FF=2048

typedef __attribute__((ext_vector_type(8))) _Float16 f16x8;
typedef __attribute__((ext_vector_type(4))) float f32x4;

__device__ __forceinline__ ushort f2h(float f){
  _Float16 h = (_Float16)f;
  return *reinterpret_cast<ushort*>(&h);
}
__device__ __forceinline__ uint pkh2(float a, float b){
  return (uint)f2h(a) | ((uint)f2h(b)<<16);
}

// ---------------- weight prep: [K][N] fp32 -> [Npad][K] fp16 ----
__global__ __launch_bounds__(256)
void k_prep(const float* __restrict__ src, ushort* __restrict__ dh,
            int K, int N, int Npad, long zStride){
  __shared__ float tile[32][33];
  int z = blockIdx.z;
  src += (size_t)z*K*N;
  dh  += (size_t)z*zStride;
  int n0 = blockIdx.x*32, k0 = blockIdx.y*32;
  int tx = threadIdx.x&31, ty = threadIdx.x>>5;
#pragma unroll
  for (int i=0;i<4;i++){
    int kk = k0 + ty + i*8, nn = n0 + tx;
    tile[ty+i*8][tx] = (nn < N) ? src[(size_t)kk*N + nn] : 0.f;
  }
  __syncthreads();
#pragma unroll
  for (int i=0;i<4;i++){
    int nn = n0 + ty + i*8, kk = k0 + tx;
    dh[(size_t)nn*K + kk] = f2h(tile[tx][ty+i*8]);
  }
}

// ---------------- V transpose (startup xl mem only) ----------------
__global__ __launch_bounds__(256)
void k_vtrans(const float* __restrict__ src, ushort* __restrict__ dst,
              long sB, int sR, int sMH, long dB, long dH, int NK){
  __shared__ float tile[64][65];
  int kc = blockIdx.x, h = blockIdx.y, b = blockIdx.z;
  int t = threadIdx.x;
  int key = t>>2, doff = (t&3)*16;
  const float* sp = src + (size_t)b*sB + (size_t)(kc*64+key)*sR + (sMH? h*64:0) + doff;
#pragma unroll
  for (int u=0;u<4;u++){
    float4 v = *reinterpret_cast<const float4*>(sp + u*4);
    tile[key][doff+u*4+0]=v.x; tile[key][doff+u*4+1]=v.y;
    tile[key][doff+u*4+2]=v.z; tile[key][doff+u*4+3]=v.w;
  }
  __syncthreads();
  int d = t>>2, kf = (t&3)*16;
  ushort* dp = dst + (size_t)b*dB + (size_t)h*dH + (size_t)d*NK + kc*64 + kf;
  ushort tmp[16];
#pragma unroll
  for (int u=0;u<16;u++) tmp[u] = f2h(tile[kf+u][d]);
  uint4 o0 = make_uint4((uint)tmp[0]|((uint)tmp[1]<<16), (uint)tmp[2]|((uint)tmp[3]<<16),
                        (uint)tmp[4]|((uint)tmp[5]<<16), (uint)tmp[6]|((uint)tmp[7]<<16));
  uint4 o1 = make_uint4((uint)tmp[8]|((uint)tmp[9]<<16), (uint)tmp[10]|((uint)tmp[11]<<16),
                        (uint)tmp[12]|((uint)tmp[13]<<16),(uint)tmp[14]|((uint)tmp[15]<<16));
  *reinterpret_cast<uint4*>(dp)   = o0;
  *reinterpret_cast<uint4*>(dp+8) = o1;
}

// fp16 -> fp16 transpose (for skv16 V half)
__global__ __launch_bounds__(256)
void k_vtrans16(const ushort* __restrict__ src, ushort* __restrict__ dst,
                long sB, int sR, long dB, int NK){
  __shared__ ushort tile[64][72];
  int kc = blockIdx.x, b = blockIdx.z;
  int t = threadIdx.x;
  int key = t>>2, doff = (t&3)*16;
  const ushort* sp = src + (size_t)b*sB + (size_t)(kc*64+key)*sR + doff;
  *reinterpret_cast<uint4*>(&tile[key][doff])   = *reinterpret_cast<const uint4*>(sp);
  *reinterpret_cast<uint4*>(&tile[key][doff+8]) = *reinterpret_cast<const uint4*>(sp+8);
  __syncthreads();
  int d = t>>2, kf = (t&3)*16;
  ushort* dp = dst + (size_t)b*dB + (size_t)d*NK + kc*64 + kf;
  ushort tmp[16];
#pragma unroll
  for (int u=0;u<16;u++) tmp[u] = tile[kf+u][d];
  uint4 o0 = make_uint4((uint)tmp[0]|((uint)tmp[1]<<16), (uint)tmp[2]|((uint)tmp[3]<<16),
                        (uint)tmp[4]|((uint)tmp[5]<<16), (uint)tmp[6]|((uint)tmp[7]<<16));
  uint4 o1 = make_uint4((uint)tmp[8]|((uint)tmp[9]<<16), (uint)tmp[10]|((uint)tmp[11]<<16),
                        (uint)tmp[12]|((uint)tmp[13]<<16),(uint)tmp[14]|((uint)tmp[15]<<16));
  *reinterpret_cast<uint4*>(dp)   = o0;
  *reinterpret_cast<uint4*>(dp+8) = o1;
}

__global__ void k_cvt(ushort* __restrict__ dst, const float* __restrict__ src, int n2){
  int idx = blockIdx.x*blockDim.x + threadIdx.x;
  if (idx >= n2) return;
  reinterpret_cast<uint*>(dst)[idx] = pkh2(src[2*idx], src[2*idx+1]);
}

// ---------------- embed / postable ----------------
__global__ void k_embed(const int* __restrict__ x, const float* __restrict__ emb,
                        float* __restrict__ h, int total4){
  int idx = blockIdx.x*blockDim.x + threadIdx.x;
  if (idx >= total4) return;
  int row = idx >> 7;
  int c4  = idx & 127;
  int tok = x[row];
  reinterpret_cast<float4*>(h)[idx] =
      reinterpret_cast<const float4*>(emb)[(size_t)tok*128 + c4];
}

__global__ void k_postable(const float* __restrict__ w1, const float* __restrict__ b1,
                           const float* __restrict__ w2, const float* __restrict__ b2,
                           const float* __restrict__ w3, const float* __restrict__ b3,
                           float* __restrict__ table){
  __shared__ float h1[128];
  __shared__ float h2[128];
  int d = blockIdx.x, t = threadIdx.x;
  float a = (float)d * w1[t] + b1[t];
  h1[t] = a / (1.f + __expf(-a));
  __syncthreads();
  float acc = b2[t];
  for (int p=0;p<128;p++) acc += h1[p]*w2[p*128+t];
  h2[t] = acc / (1.f + __expf(-acc));
  __syncthreads();
  if (t < 8){
    float acc2 = b3[t];
    for (int p=0;p<128;p++) acc2 += h2[p]*w3[p*8+t];
    table[d*8+t] = acc2;
  }
}

// ---------------- layernorm -> fp16 ----------------
__global__ void k_ln(const float* __restrict__ x, const float* __restrict__ g,
                     ushort* __restrict__ y16){
  int row = blockIdx.x;
  int t = threadIdx.x;
  float2 v = reinterpret_cast<const float2*>(x + (size_t)row*512)[t];
  float s = v.x+v.y, ss = v.x*v.x+v.y*v.y;
  for (int o=32;o;o>>=1){ s += __shfl_down(s,o); ss += __shfl_down(ss,o); }
  __shared__ float ls[4], lss[4];
  __shared__ float smu, srs;
  int wid = t>>6;
  if ((t&63)==0){ ls[wid]=s; lss[wid]=ss; }
  __syncthreads();
  if (t==0){
    float S=ls[0]+ls[1]+ls[2]+ls[3], SS=lss[0]+lss[1]+lss[2]+lss[3];
    float mu = S*(1.f/512.f);
    float var = SS*(1.f/512.f) - mu*mu;
    smu = mu; srs = rsqrtf(var + 1e-5f);
  }
  __syncthreads();
  float mu=smu, rs=srs;
  float2 gg = reinterpret_cast<const float2*>(g)[t];
  float ya = (v.x-mu)*rs*gg.x, yb = (v.y-mu)*rs*gg.y;
  *reinterpret_cast<uint*>(&y16[(size_t)row*512 + 2*t]) = pkh2(ya, yb);
}

__device__ __forceinline__ float geluf(float x){
  float u = 1.5957691216f*(x + 0.044715f*x*x*x);
  return x / (1.f + __expf(-u));
}

// ---------------- fp16 MFMA GEMM 128x128 (FF1, logits) ----------------
template<int ACC, int EPI, int OUT16>
__global__ __launch_bounds__(256)
void k_gemmh(const ushort* __restrict__ A, const ushort* __restrict__ Bt,
             const float* __restrict__ bias, float* __restrict__ C,
             ushort* __restrict__ C16, int M, int N, int K){
  __shared__ ushort As[128][68];
  __shared__ ushort Bs[128][68];
  const int t = threadIdx.x;
  const int m0 = blockIdx.x*128, n0 = blockIdx.y*128;
  const int w = t>>6, lane = t&63;
  const int wm = (w>>1)*64, wn = (w&1)*64;
  const int fr = lane&15, fg = lane>>4;
  const int srow = t>>1, sko = (t&1)*32;

  f32x4 acc[4][4];
#pragma unroll
  for (int i=0;i<4;i++)
#pragma unroll
    for (int j=0;j<4;j++){ acc[i][j][0]=0.f; acc[i][j][1]=0.f; acc[i][j][2]=0.f; acc[i][j][3]=0.f; }

  const ushort* ap = A  + (size_t)(m0+srow)*K + sko;
  const ushort* bp = Bt + (size_t)(n0+srow)*K + sko;

  for (int k0=0; k0<K; k0+=64){
    uint4 av[4], bv[4];
#pragma unroll
    for (int u=0;u<4;u++){
      av[u] = *reinterpret_cast<const uint4*>(ap + k0 + u*8);
      bv[u] = *reinterpret_cast<const uint4*>(bp + k0 + u*8);
    }
#pragma unroll
    for (int u=0;u<4;u++){
      *reinterpret_cast<uint4*>(&As[srow][sko+u*8]) = av[u];
      *reinterpret_cast<uint4*>(&Bs[srow][sko+u*8]) = bv[u];
    }
    __syncthreads();
#pragma unroll
    for (int kk=0;kk<2;kk++){
      f16x8 af[4], bf[4];
#pragma unroll
      for (int mi=0;mi<4;mi++)
        af[mi] = *reinterpret_cast<const f16x8*>(&As[wm+mi*16+fr][kk*32+fg*8]);
#pragma unroll
      for (int nj=0;nj<4;nj++)
        bf[nj] = *reinterpret_cast<const f16x8*>(&Bs[wn+nj*16+fr][kk*32+fg*8]);
#pragma unroll
      for (int mi=0;mi<4;mi++)
#pragma unroll
        for (int nj=0;nj<4;nj++)
          acc[mi][nj] = __builtin_amdgcn_mfma_f32_16x16x32_f16(af[mi], bf[nj], acc[mi][nj], 0,0,0);
    }
    __syncthreads();
  }
#pragma unroll
  for (int mi=0;mi<4;mi++){
#pragma unroll
    for (int r=0;r<4;r++){
      int row = m0 + wm + mi*16 + fg*4 + r;
#pragma unroll
      for (int nj=0;nj<4;nj++){
        int col = n0 + wn + nj*16 + fr;
        if (col < N){
          float val = acc[mi][nj][r];
          if (bias) val += bias[col];
          if (EPI==1) val = geluf(val);
          if (OUT16){
            C16[(size_t)row*N + col] = f2h(val);
          } else {
            if (ACC) C[(size_t)row*N + col] += val; else C[(size_t)row*N + col] = val;
          }
        }
      }
    }
  }
}

// ---------------- fp16 MFMA GEMM 128x128 with split out + rms + remap --------
// C1h cols [0,N1), C2h cols [N1,N). qsc!=null: per-(row,64-col-head) l2norm
// + scale (qsc for cols<N1, ksc else). xlk!=null: fp32 write of cols>=N1,
// token rows >=512 per batch -> [b][512][512]. REMAP: A row remap for rec q2s.
template<int REMAP>
__global__ __launch_bounds__(256)
void k_gemmqk(const ushort* __restrict__ A, const ushort* __restrict__ Bt,
              ushort* __restrict__ C1h, int ld1, int N1,
              ushort* __restrict__ C2h, int ld2,
              const float* __restrict__ qsc, const float* __restrict__ ksc,
              float* __restrict__ xlk,
              int nb, int M, int N, int K){
  __shared__ ushort As[128][68];
  __shared__ ushort Bs[128][68];
  const int t = threadIdx.x;
  const int m0 = blockIdx.x*128, n0 = blockIdx.y*128;
  const int w = t>>6, lane = t&63;
  const int wm = (w>>1)*64, wn = (w&1)*64;
  const int fr = lane&15, fg = lane>>4;
  const int srow = t>>1, sko = (t&1)*32;

  f32x4 acc[4][4];
#pragma unroll
  for (int i=0;i<4;i++)
#pragma unroll
    for (int j=0;j<4;j++){ acc[i][j][0]=0.f; acc[i][j][1]=0.f; acc[i][j][2]=0.f; acc[i][j][3]=0.f; }

  int mrow = m0 + srow;
  int arow = REMAP ? ((mrow>>9)*1024 + nb*512 + (mrow&511)) : mrow;
  const ushort* ap = A  + (size_t)arow*K + sko;
  const ushort* bp = Bt + (size_t)(n0+srow)*K + sko;

  for (int k0=0; k0<K; k0+=64){
    uint4 av[4], bv[4];
#pragma unroll
    for (int u=0;u<4;u++){
      av[u] = *reinterpret_cast<const uint4*>(ap + k0 + u*8);
      bv[u] = *reinterpret_cast<const uint4*>(bp + k0 + u*8);
    }
#pragma unroll
    for (int u=0;u<4;u++){
      *reinterpret_cast<uint4*>(&As[srow][sko+u*8]) = av[u];
      *reinterpret_cast<uint4*>(&Bs[srow][sko+u*8]) = bv[u];
    }
    __syncthreads();
#pragma unroll
    for (int kk=0;kk<2;kk++){
      f16x8 af[4], bf[4];
#pragma unroll
      for (int mi=0;mi<4;mi++)
        af[mi] = *reinterpret_cast<const f16x8*>(&As[wm+mi*16+fr][kk*32+fg*8]);
#pragma unroll
      for (int nj=0;nj<4;nj++)
        bf[nj] = *reinterpret_cast<const f16x8*>(&Bs[wn+nj*16+fr][kk*32+fg*8]);
#pragma unroll
      for (int mi=0;mi<4;mi++)
#pragma unroll
        for (int nj=0;nj<4;nj++)
          acc[mi][nj] = __builtin_amdgcn_mfma_f32_16x16x32_f16(af[mi], bf[nj], acc[mi][nj], 0,0,0);
    }
    __syncthreads();
  }
#pragma unroll
  for (int mi=0;mi<4;mi++){
#pragma unroll
    for (int r=0;r<4;r++){
      int row = m0 + wm + mi*16 + fg*4 + r;
      float vals[4];
#pragma unroll
      for (int nj=0;nj<4;nj++) vals[nj] = acc[mi][nj][r];
      if (qsc){
        float ss = vals[0]*vals[0]+vals[1]*vals[1]+vals[2]*vals[2]+vals[3]*vals[3];
        ss += __shfl_xor(ss,1);
        ss += __shfl_xor(ss,2);
        ss += __shfl_xor(ss,4);
        ss += __shfl_xor(ss,8);
        float rs = rsqrtf(ss + 1e-12f);
        const float* sc = ((n0+wn) < N1) ? qsc : ksc;
#pragma unroll
        for (int nj=0;nj<4;nj++) vals[nj] = vals[nj]*rs*sc[nj*16+fr];
      }
#pragma unroll
      for (int nj=0;nj<4;nj++){
        int col = n0 + wn + nj*16 + fr;
        float val = vals[nj];
        if (col < N1){
          C1h[(size_t)row*ld1 + col] = f2h(val);
        } else if (col < N){
          if (C2h) C2h[(size_t)row*ld2 + (col-N1)] = f2h(val);
          if (xlk && (row&1023) >= 512)
            xlk[((size_t)(row>>10)*512 + (row&1023) - 512)*512 + (col-N1)] = val;
        }
      }
    }
  }
}

// ---------------- fp16 MFMA GEMM 64x128 (N=512 class) ------------------------
// EPI: 0 none, 1 gelu, 2 ema. VT=1: fp16 transposed vT + optional fp32 xlv.
template<int ACC, int EPI, int OUT16, int VT>
__global__ __launch_bounds__(256)
void k_gemmh64(const ushort* __restrict__ A, const ushort* __restrict__ Bt,
               const float* __restrict__ bias, float* __restrict__ C,
               ushort* __restrict__ C16, ushort* __restrict__ vT,
               float* __restrict__ xlv, int M, int N, int K){
  __shared__ ushort As[64][68];
  __shared__ ushort Bs[128][68];
  const int t = threadIdx.x;
  const int m0 = blockIdx.x*64, n0 = blockIdx.y*128;
  const int w = t>>6, lane = t&63;
  const int wm = (w>>1)*32, wn = (w&1)*64;
  const int fr = lane&15, fg = lane>>4;
  const int srowA = t>>2, skoA = (t&3)*16;
  const int srowB = t>>1, skoB = (t&1)*32;

  f32x4 acc[2][4];
#pragma unroll
  for (int i=0;i<2;i++)
#pragma unroll
    for (int j=0;j<4;j++){ acc[i][j][0]=0.f; acc[i][j][1]=0.f; acc[i][j][2]=0.f; acc[i][j][3]=0.f; }

  const ushort* ap = A  + (size_t)(m0+srowA)*K + skoA;
  const ushort* bp = Bt + (size_t)(n0+srowB)*K + skoB;

  for (int k0=0; k0<K; k0+=64){
    uint4 a0 = *reinterpret_cast<const uint4*>(ap + k0);
    uint4 a1 = *reinterpret_cast<const uint4*>(ap + k0 + 8);
    uint4 b0 = *reinterpret_cast<const uint4*>(bp + k0);
    uint4 b1 = *reinterpret_cast<const uint4*>(bp + k0 + 8);
    uint4 b2 = *reinterpret_cast<const uint4*>(bp + k0 + 16);
    uint4 b3 = *reinterpret_cast<const uint4*>(bp + k0 + 24);
    *reinterpret_cast<uint4*>(&As[srowA][skoA])    = a0;
    *reinterpret_cast<uint4*>(&As[srowA][skoA+8])  = a1;
    *reinterpret_cast<uint4*>(&Bs[srowB][skoB])    = b0;
    *reinterpret_cast<uint4*>(&Bs[srowB][skoB+8])  = b1;
    *reinterpret_cast<uint4*>(&Bs[srowB][skoB+16]) = b2;
    *reinterpret_cast<uint4*>(&Bs[srowB][skoB+24]) = b3;
    __syncthreads();
#pragma unroll
    for (int kk=0;kk<2;kk++){
      f16x8 af[2], bf[4];
#pragma unroll
      for (int mi=0;mi<2;mi++)
        af[mi] = *reinterpret_cast<const f16x8*>(&As[wm+mi*16+fr][kk*32+fg*8]);
#pragma unroll
      for (int nj=0;nj<4;nj++)
        bf[nj] = *reinterpret_cast<const f16x8*>(&Bs[wn+nj*16+fr][kk*32+fg*8]);
#pragma unroll
      for (int mi=0;mi<2;mi++)
#pragma unroll
        for (int nj=0;nj<4;nj++)
          acc[mi][nj] = __builtin_amdgcn_mfma_f32_16x16x32_f16(af[mi], bf[nj], acc[mi][nj], 0,0,0);
    }
    __syncthreads();
  }
#pragma unroll
  for (int mi=0;mi<2;mi++){
#pragma unroll
    for (int r=0;r<4;r++){
      int row = m0 + wm + mi*16 + fg*4 + r;
#pragma unroll
      for (int nj=0;nj<4;nj++){
        int col = n0 + wn + nj*16 + fr;
        if (col < N){
          float val = acc[mi][nj][r];
          if (EPI==2){
            size_t idx = (size_t)row*N + col;
            float old = C[idx];
            float dec = 1.f/(1.f+__expf(-bias[col]));
            C[idx] = dec*old + (1.f-dec)*val;
          } else {
            if (bias) val += bias[col];
            if (EPI==1) val = geluf(val);
            if (OUT16){
              if (C16) C16[(size_t)row*N + col] = f2h(val);
            } else if (C){
              if (ACC) C[(size_t)row*N + col] += val; else C[(size_t)row*N + col] = val;
            }
            if (VT && xlv && (row&1023) >= 512)
              xlv[((size_t)(row>>10)*512 + (row&1023) - 512)*512 + col] = val;
          }
        }
      }
    }
  }
  if (VT){
#pragma unroll
    for (int mi=0;mi<2;mi++)
#pragma unroll
      for (int r=0;r<4;r++)
#pragma unroll
        for (int nj=0;nj<4;nj++)
          Bs[wn+nj*16+fr][wm+mi*16+fg*4+r] = f2h(acc[mi][nj][r]);
    __syncthreads();
    int c = t>>1, half = t&1;
    int hh = (n0+c)>>6, dd = (n0+c)&63;
    int bb = m0>>10, posb = m0&1023;
    ushort* dp = vT + (size_t)bb*524288 + (size_t)hh*65536 + (size_t)dd*1024 + posb + half*32;
#pragma unroll
    for (int u=0;u<4;u++)
      *reinterpret_cast<uint4*>(dp + u*8) = *reinterpret_cast<const uint4*>(&Bs[c][half*32 + u*8]);
  }
}

// ---------------- merged windowed MFMA flash attention -----------------------
__global__ __launch_bounds__(256)
void k_attn_win(const ushort* __restrict__ q16, const ushort* __restrict__ k16,
                const ushort* __restrict__ vTb,
                const ushort* __restrict__ xlK, const ushort* __restrict__ xlVT,
                int isxl, ushort* __restrict__ O, float scale,
                const float* __restrict__ table){
  __shared__ ushort Qs[64][72];
  __shared__ ushort Ks[64][72];
  __shared__ ushort Vs[64][72];
  __shared__ ushort Pw[4][16][72];
  __shared__ float tcol[512];
  const int b = blockIdx.z, h = blockIdx.y;
  const int nb = blockIdx.x>>3, qt = blockIdx.x&7;
  const int t = threadIdx.x, w = t>>6, lane = t&63;
  const int fr = lane&15, fg = lane>>4;
  tcol[t]     = table[t*8 + h];
  tcol[t+256] = table[(t+256)*8 + h];

  const ushort* Q  = q16 + (size_t)nb*262144;
  const ushort* K1 = k16 + (size_t)nb*262144;
  const ushort* V1 = vTb + (size_t)nb*512;
  ushort* Op = O + (size_t)nb*262144;
  const int has_mem = (nb==1) || isxl;
  const ushort* K0; long k0B; const ushort* V0; long vt0B, vt0H; int vt0D;
  if (nb==1){ K0=k16; k0B=524288; V0=vTb; vt0B=524288; vt0H=65536; vt0D=1024; }
  else if (isxl){ K0=xlK; k0B=262144; V0=xlVT; vt0B=262144; vt0H=32768; vt0D=512; }
  else { K0=k16; k0B=524288; V0=vTb; vt0B=524288; vt0H=65536; vt0D=1024; }

  {
    int qrow = t>>2, doff = (t&3)*16;
    const ushort* qp = Q + (size_t)b*524288 + (size_t)(qt*64+qrow)*512 + h*64 + doff;
    *reinterpret_cast<uint4*>(&Qs[qrow][doff])   = *reinterpret_cast<const uint4*>(qp);
    *reinterpret_cast<uint4*>(&Qs[qrow][doff+8]) = *reinterpret_cast<const uint4*>(qp+8);
  }
  __syncthreads();
  f16x8 aq[2];
  aq[0] = *reinterpret_cast<const f16x8*>(&Qs[w*16+fr][fg*8]);
  aq[1] = *reinterpret_cast<const f16x8*>(&Qs[w*16+fr][32+fg*8]);

  f32x4 so[4];
#pragma unroll
  for (int dt=0;dt<4;dt++){ so[dt][0]=0.f; so[dt][1]=0.f; so[dt][2]=0.f; so[dt][3]=0.f; }
  float m[4] = {-1e30f,-1e30f,-1e30f,-1e30f};
  float lsum[4] = {0.f,0.f,0.f,0.f};

  const int srow = t>>2, sdo = (t&3)*16;
  const int vd = t>>2,   vkf = (t&3)*16;

  int jt0 = has_mem ? qt : 8;
  int jt1 = qt + 8; if (jt1 > 15) jt1 = 15;

  for (int jt=jt0; jt<=jt1; jt++){
    {
      int key = jt*64 + srow;
      const ushort* kp;
      if (key < 512) kp = K0 + (size_t)b*k0B + (size_t)key*512 + h*64 + sdo;
      else           kp = K1 + (size_t)b*524288 + (size_t)(key-512)*512 + h*64 + sdo;
      *reinterpret_cast<uint4*>(&Ks[srow][sdo])   = *reinterpret_cast<const uint4*>(kp);
      *reinterpret_cast<uint4*>(&Ks[srow][sdo+8]) = *reinterpret_cast<const uint4*>(kp+8);
    }
    {
      const ushort* vp;
      if (jt*64 < 512) vp = V0 + (size_t)b*vt0B + (size_t)h*vt0H + (size_t)vd*vt0D + jt*64 + vkf;
      else             vp = V1 + (size_t)b*524288 + (size_t)h*65536 + (size_t)vd*1024 + (jt*64-512) + vkf;
      *reinterpret_cast<uint4*>(&Vs[vd][vkf])   = *reinterpret_cast<const uint4*>(vp);
      *reinterpret_cast<uint4*>(&Vs[vd][vkf+8]) = *reinterpret_cast<const uint4*>(vp+8);
    }
    __syncthreads();
    f32x4 sacc[4];
#pragma unroll
    for (int kt=0;kt<4;kt++){ sacc[kt][0]=0.f; sacc[kt][1]=0.f; sacc[kt][2]=0.f; sacc[kt][3]=0.f; }
#pragma unroll
    for (int ks=0;ks<2;ks++){
#pragma unroll
      for (int kt=0;kt<4;kt++){
        f16x8 bf = *reinterpret_cast<const f16x8*>(&Ks[kt*16+fr][ks*32+fg*8]);
        sacc[kt] = __builtin_amdgcn_mfma_f32_16x16x32_f16(aq[ks], bf, sacc[kt], 0,0,0);
      }
    }
#pragma unroll
    for (int r=0;r<4;r++){
      float sv[4];
      int ia = qt*64 + w*16 + fg*4 + r;
#pragma unroll
      for (int kt=0;kt<4;kt++){
        float s = sacc[kt][r]*scale;
        int jg = jt*64 + kt*16 + fr;
        bool valid = (jg > ia) && (jg <= ia+512) && (has_mem || jg >= 512);
        sv[kt] = valid ? s + tcol[ia+512-jg] : -1e9f;
      }
      float tm = fmaxf(fmaxf(sv[0],sv[1]), fmaxf(sv[2],sv[3]));
      tm = fmaxf(tm, __shfl_xor(tm,1));
      tm = fmaxf(tm, __shfl_xor(tm,2));
      tm = fmaxf(tm, __shfl_xor(tm,4));
      tm = fmaxf(tm, __shfl_xor(tm,8));
      float mn = fmaxf(m[r], tm);
      float c = __expf(m[r]-mn);
      m[r] = mn;
      float ps = 0.f;
#pragma unroll
      for (int kt=0;kt<4;kt++){
        float pp = (sv[kt] <= -1e8f) ? 0.f : __expf(sv[kt]-mn);
        ps += pp;
        Pw[w][fg*4+r][kt*16+fr] = f2h(pp);
      }
      ps += __shfl_xor(ps,1);
      ps += __shfl_xor(ps,2);
      ps += __shfl_xor(ps,4);
      ps += __shfl_xor(ps,8);
      lsum[r] = lsum[r]*c + ps;
#pragma unroll
      for (int dt=0;dt<4;dt++) so[dt][r] *= c;
    }
#pragma unroll
    for (int ks=0;ks<2;ks++){
      f16x8 pa = *reinterpret_cast<const f16x8*>(&Pw[w][fr][ks*32+fg*8]);
#pragma unroll
      for (int dt=0;dt<4;dt++){
        f16x8 bv = *reinterpret_cast<const f16x8*>(&Vs[dt*16+fr][ks*32+fg*8]);
        so[dt] = __builtin_amdgcn_mfma_f32_16x16x32_f16(pa, bv, so[dt], 0,0,0);
      }
    }
    __syncthreads();
  }
#pragma unroll
  for (int r=0;r<4;r++){
    int row = qt*64 + w*16 + fg*4 + r;
    float inv = 1.f / lsum[r];
    ushort* op = Op + (size_t)b*524288 + (size_t)row*512 + h*64;
#pragma unroll
    for (int dt=0;dt<4;dt++)
      op[dt*16+fr] = f2h(so[dt][r]*inv);
  }
}

// ---------------- merged rec-layer attentions ----------------
__global__ __launch_bounds__(256)
void k_attn_rec(const ushort* __restrict__ q2s, const ushort* __restrict__ sq,
                const ushort* __restrict__ skv, const ushort* __restrict__ svT,
                const ushort* __restrict__ kblk, const ushort* __restrict__ vblk,
                ushort* __restrict__ ts, ushort* __restrict__ sa){
  __shared__ ushort Qs[64][72];
  __shared__ ushort Ks[64][72];
  __shared__ ushort Vs[64][72];
  __shared__ ushort Pw[4][16][72];
  const int b = blockIdx.z, h = blockIdx.y;
  const int task = blockIdx.x>>3, qt = blockIdx.x&7;
  const int t = threadIdx.x, w = t>>6, lane = t&63;
  const int fr = lane&15, fg = lane>>4;

  const ushort* Q; const ushort* K1; int k1R, k1H;
  const ushort* VT1; long vt1B, vt1H; int vt1D;
  int nt; ushort* O; long oB;
  if (task==0){
    Q=q2s; K1=skv; k1R=128; k1H=0;
    VT1=svT; vt1B=32768; vt1H=0; vt1D=512;
    nt=8; O=ts; oB=524288;
  } else {
    Q=sq; K1=kblk; k1R=512; k1H=1;
    VT1=vblk; vt1B=524288; vt1H=65536; vt1D=1024;
    nt=16; O=sa; oB=262144;
  }

  {
    int qrow = t>>2, doff = (t&3)*16;
    const ushort* qp = Q + (size_t)b*262144 + (size_t)(qt*64+qrow)*512 + h*64 + doff;
    *reinterpret_cast<uint4*>(&Qs[qrow][doff])   = *reinterpret_cast<const uint4*>(qp);
    *reinterpret_cast<uint4*>(&Qs[qrow][doff+8]) = *reinterpret_cast<const uint4*>(qp+8);
  }
  __syncthreads();
  f16x8 aq[2];
  aq[0] = *reinterpret_cast<const f16x8*>(&Qs[w*16+fr][fg*8]);
  aq[1] = *reinterpret_cast<const f16x8*>(&Qs[w*16+fr][32+fg*8]);

  f32x4 so[4];
#pragma unroll
  for (int dt=0;dt<4;dt++){ so[dt][0]=0.f; so[dt][1]=0.f; so[dt][2]=0.f; so[dt][3]=0.f; }
  float m[4] = {-1e30f,-1e30f,-1e30f,-1e30f};
  float lsum[4] = {0.f,0.f,0.f,0.f};

  const int srow = t>>2, sdo = (t&3)*16;
  const int vd = t>>2,   vkf = (t&3)*16;

  for (int jt=0; jt<nt; jt++){
    {
      int key = jt*64 + srow;
      const ushort* kp;
      if (key < 512) kp = skv + (size_t)b*65536 + (size_t)key*128 + sdo;
      else           kp = K1 + (size_t)b*524288 + (size_t)(key-512)*k1R + (k1H? h*64:0) + sdo;
      *reinterpret_cast<uint4*>(&Ks[srow][sdo])   = *reinterpret_cast<const uint4*>(kp);
      *reinterpret_cast<uint4*>(&Ks[srow][sdo+8]) = *reinterpret_cast<const uint4*>(kp+8);
    }
    {
      const ushort* vp;
      if (jt*64 < 512) vp = svT + (size_t)b*32768 + (size_t)vd*512 + jt*64 + vkf;
      else             vp = VT1 + (size_t)b*vt1B + (size_t)h*vt1H + (size_t)vd*vt1D + (jt*64-512) + vkf;
      *reinterpret_cast<uint4*>(&Vs[vd][vkf])   = *reinterpret_cast<const uint4*>(vp);
      *reinterpret_cast<uint4*>(&Vs[vd][vkf+8]) = *reinterpret_cast<const uint4*>(vp+8);
    }
    __syncthreads();
    f32x4 sacc[4];
#pragma unroll
    for (int kt=0;kt<4;kt++){ sacc[kt][0]=0.f; sacc[kt][1]=0.f; sacc[kt][2]=0.f; sacc[kt][3]=0.f; }
#pragma unroll
    for (int ks=0;ks<2;ks++){
#pragma unroll
      for (int kt=0;kt<4;kt++){
        f16x8 bf = *reinterpret_cast<const f16x8*>(&Ks[kt*16+fr][ks*32+fg*8]);
        sacc[kt] = __builtin_amdgcn_mfma_f32_16x16x32_f16(aq[ks], bf, sacc[kt], 0,0,0);
      }
    }
#pragma unroll
    for (int r=0;r<4;r++){
      float sv[4];
#pragma unroll
      for (int kt=0;kt<4;kt++) sv[kt] = sacc[kt][r]*0.125f;
      float tm = fmaxf(fmaxf(sv[0],sv[1]), fmaxf(sv[2],sv[3]));
      tm = fmaxf(tm, __shfl_xor(tm,1));
      tm = fmaxf(tm, __shfl_xor(tm,2));
      tm = fmaxf(tm, __shfl_xor(tm,4));
      tm = fmaxf(tm, __shfl_xor(tm,8));
      float mn = fmaxf(m[r], tm);
      float c = __expf(m[r]-mn);
      m[r] = mn;
      float ps = 0.f;
#pragma unroll
      for (int kt=0;kt<4;kt++){
        float pp = __expf(sv[kt]-mn);
        ps += pp;
        Pw[w][fg*4+r][kt*16+fr] = f2h(pp);
      }
      ps += __shfl_xor(ps,1);
      ps += __shfl_xor(ps,2);
      ps += __shfl_xor(ps,4);
      ps += __shfl_xor(ps,8);
      lsum[r] = lsum[r]*c + ps;
#pragma unroll
      for (int dt=0;dt<4;dt++) so[dt][r] *= c;
    }
#pragma unroll
    for (int ks=0;ks<2;ks++){
      f16x8 pa = *reinterpret_cast<const f16x8*>(&Pw[w][fr][ks*32+fg*8]);
#pragma unroll
      for (int dt=0;dt<4;dt++){
        f16x8 bv = *reinterpret_cast<const f16x8*>(&Vs[dt*16+fr][ks*32+fg*8]);
        so[dt] = __builtin_amdgcn_mfma_f32_16x16x32_f16(pa, bv, so[dt], 0,0,0);
      }
    }
    __syncthreads();
  }
#pragma unroll
  for (int r=0;r<4;r++){
    int row = qt*64 + w*16 + fg*4 + r;
    float inv = 1.f / lsum[r];
    ushort* op = O + (size_t)b*oB + (size_t)row*512 + h*64;
#pragma unroll
    for (int dt=0;dt<4;dt++)
      op[dt*16+fr] = f2h(so[dt][r]*inv);
  }
}

// ---------------- small utility kernels ----------------
__global__ void k_copy(float* __restrict__ dst, const float* __restrict__ src, int n){
  int idx = blockIdx.x*blockDim.x + threadIdx.x;
  if (idx < n) dst[idx] = src[idx];
}

// ---------------- launcher ----------------
extern "C" void kernel_launch(void* const* d_in, const int* in_sizes, int n_in,
                              void* d_out, int out_size, void* d_ws, size_t ws_size,
                              hipStream_t stream){
  // floats 12,599,296 B + ushorts 106,954,752 B = 119,554,048 B
  if (ws_size < (size_t)119554048) return;

  const int*   x        = (const int*)  d_in[0];
  const float* tok_emb  = (const float*)d_in[1];
  const float* pw1 = (const float*)d_in[2];
  const float* pb1 = (const float*)d_in[3];
  const float* pw2 = (const float*)d_in[4];
  const float* pb2 = (const float*)d_in[5];
  const float* pw3 = (const float*)d_in[6];
  const float* pb3 = (const float*)d_in[7];
  const float* ln_g = (const float*)d_in[8];
  const float* Wq = (const float*)d_in[9];
  const float* Wk = (const float*)d_in[10];
  const float* Wv = (const float*)d_in[11];
  const float* Wo = (const float*)d_in[12];
  const float* q_scale = (const float*)d_in[13];
  const float* k_scale = (const float*)d_in[14];
  const float* Wo_state = (const float*)d_in[15];
  const float* state_norm_g = (const float*)d_in[16];
  const float* Wq2s = (const float*)d_in[17];
  const float* Ws2q = (const float*)d_in[18];
  const float* Ws2kv = (const float*)d_in[19];
  const float* W_state_out = (const float*)d_in[20];
  const float* ema_beta = (const float*)d_in[21];
  const float* ff_g = (const float*)d_in[22];
  const float* ff_w1 = (const float*)d_in[23];
  const float* ff_b1 = (const float*)d_in[24];
  const float* ff_w2 = (const float*)d_in[25];
  const float* ff_b2 = (const float*)d_in[26];
  const float* final_g = (const float*)d_in[27];
  const float* W_logits = (const float*)d_in[28];
  const float* xl_mem_k = (const float*)d_in[29];
  const float* xl_mem_v = (const float*)d_in[30];
  const float* states_in = (const float*)d_in[31];

  float* out = (float*)d_out;
  float* out_xlk    = out + 81920000;
  float* out_xlv    = out + 84017152;
  float* out_states = out + 86114304;

  float* p = (float*)d_ws;
  float* hstate   = p; p += 2097152;
  float* states_cur = p; p += 1048576;
  float* table    = p; p += 4096;

  ushort* us = (ushort*)p;
  ushort* wqkh  = us; us += 3145728;   // [6][1024][512]: rows 0-511 q, 512-1023 k
  ushort* wvT   = us; us += 1572864;
  ushort* woT   = us; us += 1572864;
  ushort* ffw1T = us; us += 6291456;
  ushort* ffw2T = us; us += 6291456;
  ushort* wostT = us; us += 262144;
  ushort* wstoutT = us; us += 262144;
  ushort* wq2sh = us; us += 262144;
  ushort* wsqkvh = us; us += 327680;   // [640][512]: rows 0-511 Ws2q, 512-639 Ws2kv
  ushort* wlogT  = us; us += 10289152; // [20096][512]
  ushort* vTb   = us; us += 2097152;   // [b][h][64][1024]
  ushort* xlvT  = us; us += 2097152;   // [2][b][h][64][512]
  ushort* svT   = us; us += 131072;    // [b][64][512]
  ushort* xn16  = us; us += 2097152;
  ushort* ao16  = us; us += 2097152;
  ushort* ff1_16 = us; us += 8388608;  // [4096][2048] + rec aliases
  ushort* q16   = us; us += 2097152;
  ushort* k16   = us; us += 2097152;
  ushort* xlk16 = us; us += 2097152;   // [2][b][512][512] fp16
  // rec aliases inside ff1_16 (dead between FF uses)
  ushort* ts16   = ff1_16;             // [4096][512]
  ushort* sa16   = ff1_16 + 2097152;   // [2048][512]
  ushort* sn16   = ff1_16 + 3145728;   // [2048][512]
  ushort* sq16   = ff1_16 + 4194304;   // [2048][512]
  ushort* q2s16  = ff1_16 + 5242880;   // [2048][512]
  ushort* skv16  = ff1_16 + 6291456;   // [2048][128]

  // ---- weight prep ----
  k_prep<<<dim3(16,16,6),256,0,stream>>>(Wq, wqkh, 512,512,512, 524288);
  k_prep<<<dim3(16,16,6),256,0,stream>>>(Wk, wqkh+262144, 512,512,512, 524288);
  k_prep<<<dim3(16,16,6),256,0,stream>>>(Wv, wvT, 512,512,512, 262144);
  k_prep<<<dim3(16,16,6),256,0,stream>>>(Wo, woT, 512,512,512, 262144);
  k_prep<<<dim3(64,16,6),256,0,stream>>>(ff_w1, ffw1T, 512,2048,2048, 1048576);
  k_prep<<<dim3(16,64,6),256,0,stream>>>(ff_w2, ffw2T, 2048,512,512, 1048576);
  k_prep<<<dim3(16,16,1),256,0,stream>>>(Wo_state, wostT, 512,512,512, 262144);
  k_prep<<<dim3(16,16,1),256,0,stream>>>(W_state_out, wstoutT, 512,512,512, 262144);
  k_prep<<<dim3(16,16,1),256,0,stream>>>(Wq2s, wq2sh, 512,512,512, 262144);
  k_prep<<<dim3(16,16,1),256,0,stream>>>(Ws2q, wsqkvh, 512,512,512, 327680);
  k_prep<<<dim3(4,16,1),256,0,stream>>>(Ws2kv, wsqkvh+262144, 512,128,128, 327680);
  k_prep<<<dim3(628,16,1),256,0,stream>>>(W_logits, wlogT, 512,20000,20096, 10289152);

  for (int s=0;s<2;s++)
    k_vtrans<<<dim3(8,8,4),256,0,stream>>>(xl_mem_v + (size_t)s*1048576,
                                           xlvT + (size_t)s*1048576,
                                           262144L, 512, 1, 262144L, 32768L, 512);
  k_cvt<<<4096,256,0,stream>>>(xlk16, xl_mem_k, 1048576);

  k_embed<<<2048, 256, 0, stream>>>(x, tok_emb, hstate, 524288);
  k_postable<<<512, 128, 0, stream>>>(pw1,pb1,pw2,pb2,pw3,pb3, table);
  k_copy<<<4096, 256, 0, stream>>>(states_cur, states_in, 1048576);

  for (int l=0;l<6;l++){
    bool isxl = (l==4 || l==5);
    int xli = l-4;
    int src = (l==4)? 1 : 0;     // roll(-1)
    k_ln<<<4096,256,0,stream>>>(hstate, ln_g + l*512, xn16);
    float scale = 0.125f;
    const float* qsc = nullptr; const float* ksc = nullptr;
    if (l>=3){ qsc = q_scale + l*64; ksc = k_scale + l*64; scale = 8.f; }
    // q|k merged fp16 GEMM with fused rmsnorm (l>=3) + xl-k fp32 out (l=4,5)
    k_gemmqk<0><<<dim3(32,8),256,0,stream>>>(xn16,
        wqkh + (size_t)l*524288,
        q16, 512, 512, k16, 512, qsc, ksc,
        isxl ? out_xlk + (size_t)xli*1048576 : nullptr,
        0, 4096, 1024, 512);
    // v GEMM: fp16 V^T + (xl) fp32 out_xlv
    k_gemmh64<0,0,0,1><<<dim3(64,4),256,0,stream>>>(xn16, wvT + (size_t)l*262144,
        nullptr, nullptr, nullptr, vTb,
        isxl ? out_xlv + (size_t)xli*1048576 : nullptr, 4096,512,512);

    k_attn_win<<<dim3(16,8,4),256,0,stream>>>(
        q16, k16, vTb,
        isxl ? xlk16 + (size_t)src*1048576 : k16,
        isxl ? xlvT  + (size_t)src*1048576 : vTb,
        isxl ? 1 : 0, ao16, scale, table);

    k_gemmh64<1,0,0,0><<<dim3(64,4),256,0,stream>>>(ao16, woT + (size_t)l*262144,
        nullptr, hstate, nullptr, nullptr, nullptr, 4096,512,512);
    if (l==3){
      for (int nb=0;nb<2;nb++){
        k_ln<<<2048,256,0,stream>>>(states_cur, state_norm_g, sn16);
        k_gemmqk<0><<<dim3(16,5),256,0,stream>>>(sn16, wsqkvh,
            sq16, 512, 512, skv16, 128, nullptr, nullptr, nullptr, 0, 2048, 640, 512);
        k_vtrans16<<<dim3(8,1,4),256,0,stream>>>(skv16 + 64, svT, 65536L, 128, 32768L, 512);
        k_gemmqk<1><<<dim3(16,4),256,0,stream>>>(xn16, wq2sh,
            q2s16, 512, 512, nullptr, 0, nullptr, nullptr, nullptr, nb, 2048, 512, 512);
        k_attn_rec<<<dim3(16,8,4),256,0,stream>>>(
            q2s16, sq16, skv16, svT,
            k16 + (size_t)nb*262144, vTb + (size_t)nb*512,
            ts16 + (size_t)nb*262144, sa16);
        k_gemmh64<0,2,0,0><<<dim3(32,4),256,0,stream>>>(sa16, wstoutT, ema_beta,
            states_cur, nullptr, nullptr, nullptr, 2048,512,512);
      }
      k_gemmh64<1,0,0,0><<<dim3(64,4),256,0,stream>>>(ts16, wostT, nullptr,
          hstate, nullptr, nullptr, nullptr, 4096,512,512);
    }
    k_ln<<<4096,256,0,stream>>>(hstate, ff_g + l*512, xn16);
    k_gemmh<0,1,1><<<dim3(32,16),256,0,stream>>>(xn16, ffw1T + (size_t)l*1048576, ff_b1 + l*2048, nullptr, ff1_16, 4096,2048,512);
    k_gemmh64<1,0,0,0><<<dim3(64,4),256,0,stream>>>(ff1_16, ffw2T + (size_t)l*1048576, ff_b2 + l*512, hstate, nullptr, nullptr, nullptr, 4096,512,2048);
  }
  k_ln<<<4096,256,0,stream>>>(hstate, final_g, xn16);
  k_gemmh<0,0,0><<<dim3(32,157),256,0,stream>>>(xn16, wlogT, nullptr, out, nullptr, 4096,20000,512);
  k_copy<<<4096, 256, 0, stream>>>(out_states, states_cur, 1048576);
}